// Round 5
// baseline (675.708 us; speedup 1.0000x reference)
//
#include <hip/hip_runtime.h>
#include <math.h>

#define NN   50000
#define NE   800000
#define FEATD 128
#define SED  16
#define HD   64
#define NCLS 10
#define NLAY 3
#define NG   500

#define SBLK 256
#define SNB  ((NN + SBLK - 1) / SBLK)   // 196 blocks

#define BSH  3                           // bucket = dst >> 3 (8 nodes/bucket)
#define NBUK (NN >> BSH)                 // 6250 (50000 divisible by 8)
#define WNODE 128                        // scatter window: nodes per block
#define NWIN ((NN + WNODE - 1) / WNODE)  // 391

// ---- bf16 helpers (round-to-nearest-even pack; unpack via shift) ----------
__device__ inline unsigned short f2bf(float f){
    unsigned int u = __float_as_uint(f);
    u += 0x7fffu + ((u >> 16) & 1u);
    return (unsigned short)(u >> 16);
}
__device__ inline float bf_lo(unsigned int p){ return __uint_as_float(p << 16); }
__device__ inline float bf_hi(unsigned int p){ return __uint_as_float(p & 0xffff0000u); }

// ---------------- utility zero kernels ------------------------------------
__global__ void zero_i32(int* __restrict__ p, int n){
    int i = blockIdx.x*blockDim.x + threadIdx.x;
    if (i < n) p[i] = 0;
}
__global__ void zero_f32(float* __restrict__ p, int n){
    int i = blockIdx.x*blockDim.x + threadIdx.x;
    if (i < n) p[i] = 0.f;
}

// ---------------- CSR build ------------------------------------------------
// harness delivers integer inputs as int32 (const int*), NOT int64.
__global__ void count_deg(const int* __restrict__ dst, int* __restrict__ cnt, int e){
    int i = blockIdx.x*blockDim.x + threadIdx.x;
    if (i < e) atomicAdd(&cnt[dst[i]], 1);
}

__global__ __launch_bounds__(SBLK) void scan_local(
        const int* __restrict__ cnt, int* __restrict__ off, int* __restrict__ bsum, int n){
    __shared__ int sh[SBLK];
    int t = threadIdx.x;
    int i = blockIdx.x * SBLK + t;
    int v = (i < n) ? cnt[i] : 0;
    sh[t] = v;
    __syncthreads();
#pragma unroll
    for (int d = 1; d < SBLK; d <<= 1){
        int u = (t >= d) ? sh[t-d] : 0;
        __syncthreads();
        sh[t] += u;
        __syncthreads();
    }
    if (i < n) off[i] = sh[t] - v;
    if (t == SBLK-1) bsum[blockIdx.x] = sh[t];
}

__global__ __launch_bounds__(SBLK) void scan_bsum(int* __restrict__ bsum, int nb){
    __shared__ int sh[SBLK];
    int t = threadIdx.x;
    int v = (t < nb) ? bsum[t] : 0;
    sh[t] = v;
    __syncthreads();
#pragma unroll
    for (int d = 1; d < SBLK; d <<= 1){
        int u = (t >= d) ? sh[t-d] : 0;
        __syncthreads();
        sh[t] += u;
        __syncthreads();
    }
    if (t < nb) bsum[t] = sh[t] - v;
}

// finalize off/cur/dinv, and bucket cursors bcur[b] = off[b<<BSH]
__global__ __launch_bounds__(SBLK) void scan_finish(
        int* __restrict__ off, int* __restrict__ cur, const int* __restrict__ cnt,
        const int* __restrict__ bsum, float* __restrict__ dinv,
        int* __restrict__ bcur, int n, int etot){
    int i = blockIdx.x * SBLK + threadIdx.x;
    if (i < n){
        int o = off[i] + bsum[blockIdx.x];
        off[i] = o; cur[i] = o;
        dinv[i] = rsqrtf((float)cnt[i] + 1.0f);
        if ((i & ((1 << BSH) - 1)) == 0) bcur[i >> BSH] = o;
    }
    if (i == 0) off[n] = etot;
}

// phase 1: bin edges into per-bucket streams (sequential appends -> dense lines)
__global__ void bin_edges(const int* __restrict__ src, const int* __restrict__ dst,
        int* __restrict__ bcur, unsigned int* __restrict__ ebuf, int e){
    int i = blockIdx.x*blockDim.x + threadIdx.x;
    if (i < e){
        int d = dst[i];
        int p = atomicAdd(&bcur[d >> BSH], 1);
        ebuf[p] = (unsigned int)src[i] | ((unsigned int)d << 16);
    }
}

// phase 2: per-window sequential read of ebuf, scatter within ~8KB csr window
__global__ __launch_bounds__(SBLK) void scatter_bucket(
        const unsigned int* __restrict__ ebuf, const int* __restrict__ off,
        int* __restrict__ cur, int* __restrict__ csr, int n){
    int w  = blockIdx.x;
    int n0 = w * WNODE;
    int n1 = n0 + WNODE; if (n1 > n) n1 = n;
    int lo = off[n0], hi = off[n1];
    for (int j = lo + threadIdx.x; j < hi; j += SBLK){
        unsigned int u = ebuf[j];
        int s = (int)(u & 0xffffu);
        int d = (int)(u >> 16);
        int p = atomicAdd(&cur[d], 1);
        csr[p] = s;
    }
}

// ---------------- fp32 tall-skinny linear: out[n,64] = A[n,K]@W[K,64] -----
// wave: lane=row, wave-uniform 16-col group. Optional bf16 shadow output.
template<int K>
__global__ __launch_bounds__(256) void linear64(
        const float* __restrict__ A, int lda,
        const float* __restrict__ W,
        const float* __restrict__ bias,
        float* __restrict__ out, int ldo,
        unsigned short* __restrict__ outb, int ldob,
        int n, int act)
{
    int lane = threadIdx.x & 63;
    int c0 = __builtin_amdgcn_readfirstlane((threadIdx.x >> 6) << 4);
    int row = blockIdx.x * 64 + lane;
    if (row >= n) return;
    float acc[16];
#pragma unroll
    for (int j = 0; j < 16; j++) acc[j] = 0.f;
    const float* a  = A + (size_t)row * lda;
    const float* wp = W + c0;
    for (int k = 0; k < K; k += 4){
        float4 av = *(const float4*)(a + k);
        float aa[4] = {av.x, av.y, av.z, av.w};
#pragma unroll
        for (int kk = 0; kk < 4; kk++){
            const float* wr = wp + (k + kk) * 64;
#pragma unroll
            for (int j = 0; j < 16; j++)
                acc[j] = fmaf(aa[kk], wr[j], acc[j]);
        }
    }
    if (bias){
#pragma unroll
        for (int j = 0; j < 16; j++) acc[j] += bias[c0 + j];
    }
    if (act == 1){
#pragma unroll
        for (int j = 0; j < 16; j++) acc[j] = fmaxf(acc[j], 0.f);
    }
    float* o = out + (size_t)row * ldo + c0;
#pragma unroll
    for (int q = 0; q < 4; q++){
        float4 v;
        v.x = acc[q*4+0]; v.y = acc[q*4+1]; v.z = acc[q*4+2]; v.w = acc[q*4+3];
        *(float4*)(o + q*4) = v;
    }
    if (outb){
        unsigned int pk[8];
#pragma unroll
        for (int j = 0; j < 8; j++)
            pk[j] = (unsigned int)f2bf(acc[2*j]) | ((unsigned int)f2bf(acc[2*j+1]) << 16);
        unsigned short* ob = outb + (size_t)row * ldob + c0;
        uint4 u0; u0.x = pk[0]; u0.y = pk[1]; u0.z = pk[2]; u0.w = pk[3];
        uint4 u1; u1.x = pk[4]; u1.y = pk[5]; u1.z = pk[6]; u1.w = pk[7];
        *(uint4*)(ob)     = u0;
        *(uint4*)(ob + 8) = u1;
    }
}

// ---------------- GIN aggregation (bf16 gather table) ----------------------
__global__ __launch_bounds__(256) void gin_agg(
        const float* __restrict__ xc, const unsigned int* __restrict__ xcb,
        const int* __restrict__ off, const int* __restrict__ csr,
        float* __restrict__ hpre, int n)
{
    int node = __builtin_amdgcn_readfirstlane(blockIdx.x * 4 + (threadIdx.x >> 6));
    int lane = threadIdx.x & 63;
    if (node >= n) return;
    int beg = off[node], end = off[node+1];
    float2 self = *(const float2*)(xc + (size_t)node*128 + 2*lane);
    float a0 = self.x, a1 = self.y;
    int e = beg;
    for (; e + 4 <= end; e += 4){
        int s0 = csr[e], s1 = csr[e+1], s2 = csr[e+2], s3 = csr[e+3];
        unsigned int p0 = xcb[(size_t)s0*64 + lane];
        unsigned int p1 = xcb[(size_t)s1*64 + lane];
        unsigned int p2 = xcb[(size_t)s2*64 + lane];
        unsigned int p3 = xcb[(size_t)s3*64 + lane];
        a0 += (bf_lo(p0) + bf_lo(p1)) + (bf_lo(p2) + bf_lo(p3));
        a1 += (bf_hi(p0) + bf_hi(p1)) + (bf_hi(p2) + bf_hi(p3));
    }
    for (; e < end; e++){
        unsigned int p0 = xcb[(size_t)csr[e]*64 + lane];
        a0 += bf_lo(p0);
        a1 += bf_hi(p0);
    }
    float2 r; r.x = a0; r.y = a1;
    *(float2*)(hpre + (size_t)node*128 + 2*lane) = r;
}

// ---------------- GCN aggregation (bf16 gather) + self + tanh --------------
__global__ __launch_bounds__(256) void gcn_agg(
        const float* __restrict__ hs, const unsigned short* __restrict__ hsb,
        const float* __restrict__ dinv,
        const int* __restrict__ off, const int* __restrict__ csr,
        const float* __restrict__ bias, float* __restrict__ xc,
        unsigned short* __restrict__ xcb, int n)
{
    int node = __builtin_amdgcn_readfirstlane(blockIdx.x * 4 + (threadIdx.x >> 6));
    int lane = threadIdx.x & 63;
    if (node >= n) return;
    int beg = off[node], end = off[node+1];
    float acc = 0.f;
    int e = beg;
    for (; e + 4 <= end; e += 4){
        int s0 = csr[e], s1 = csr[e+1], s2 = csr[e+2], s3 = csr[e+3];
        float v0 = dinv[s0] * __uint_as_float((unsigned int)hsb[(size_t)s0*64 + lane] << 16);
        float v1 = dinv[s1] * __uint_as_float((unsigned int)hsb[(size_t)s1*64 + lane] << 16);
        float v2 = dinv[s2] * __uint_as_float((unsigned int)hsb[(size_t)s2*64 + lane] << 16);
        float v3 = dinv[s3] * __uint_as_float((unsigned int)hsb[(size_t)s3*64 + lane] << 16);
        acc += (v0 + v1) + (v2 + v3);
    }
    for (; e < end; e++){
        int s0 = csr[e];
        acc += dinv[s0] * __uint_as_float((unsigned int)hsb[(size_t)s0*64 + lane] << 16);
    }
    float di   = dinv[node];
    float self = hs[(size_t)node*64 + lane];
    float v = tanhf(di*acc + self*di*di + bias[lane]);
    xc [(size_t)node*128 + 64 + lane] = v;
    xcb[(size_t)node*128 + 64 + lane] = f2bf(v);
}

// ---------------- global_add_pool (batch sorted, int32) -------------------
__global__ __launch_bounds__(64) void pool_kernel(
        const float* __restrict__ xw, const int* __restrict__ batch,
        float* __restrict__ g, int n)
{
    int lane = threadIdx.x;
    int r0 = blockIdx.x * 128;
    if (r0 >= n) return;
    int r1 = r0 + 128; if (r1 > n) r1 = n;
    float acc = 0.f;
    int cb = batch[r0];
    for (int r = r0; r < r1; r++){
        int b = batch[r];
        if (b != cb){
            atomicAdd(&g[(size_t)cb*64 + lane], acc);
            acc = 0.f; cb = b;
        }
        acc += xw[(size_t)r*64 + lane];
    }
    atomicAdd(&g[(size_t)cb*64 + lane], acc);
}

// ---------------- head ----------------------------------------------------
__global__ __launch_bounds__(256) void head_kernel(
        const float* __restrict__ g, const float* __restrict__ postW,
        const float* __restrict__ postb, const float* __restrict__ roW,
        const float* __restrict__ rob, float* __restrict__ out, int ngraph)
{
    int gr = __builtin_amdgcn_readfirstlane(blockIdx.x * 4 + (threadIdx.x >> 6));
    int lane = threadIdx.x & 63;
    if (gr >= ngraph) return;
    float gv = g[(size_t)gr*64 + lane];
    float t = postb[lane];
    for (int k = 0; k < 64; k++){
        float a = __shfl(gv, k);
        t = fmaf(a, postW[k*64 + lane], t);
    }
    t = fmaxf(t, 0.f);
    float lg = (lane < NCLS) ? rob[lane] : 0.f;
    for (int k = 0; k < 64; k++){
        float a = __shfl(t, k);
        float w = (lane < NCLS) ? roW[k*NCLS + lane] : 0.f;
        lg = fmaf(a, w, lg);
    }
    float m = (lane < NCLS) ? lg : -INFINITY;
#pragma unroll
    for (int d = 1; d < 16; d <<= 1) m = fmaxf(m, __shfl_xor(m, d, 16));
    float ex = (lane < NCLS) ? expf(lg - m) : 0.f;
    float ssum = ex;
#pragma unroll
    for (int d = 1; d < 16; d <<= 1) ssum += __shfl_xor(ssum, d, 16);
    if (lane < NCLS) out[(size_t)gr*NCLS + lane] = lg - m - logf(ssum);
}

// ---------------- launch --------------------------------------------------
extern "C" void kernel_launch(void* const* d_in, const int* in_sizes, int n_in,
                              void* d_out, int out_size, void* d_ws, size_t ws_size,
                              hipStream_t stream) {
    const float* x      = (const float*)d_in[0];
    const float* s      = (const float*)d_in[1];
    const int*   ei     = (const int*)d_in[2];    // int32
    const int*   batch  = (const int*)d_in[3];    // int32
    const float* pre_W  = (const float*)d_in[4];
    const float* pre_b  = (const float*)d_in[5];
    const float* emb_W  = (const float*)d_in[6];
    const float* emb_b  = (const float*)d_in[7];
    const float* gin_W1 = (const float*)d_in[8];
    const float* gin_b1 = (const float*)d_in[9];
    const float* gin_W2 = (const float*)d_in[10];
    const float* gin_b2 = (const float*)d_in[11];
    const float* gcn_W  = (const float*)d_in[12];
    const float* gcn_b  = (const float*)d_in[13];
    const float* whp_W  = (const float*)d_in[14];
    const float* whp_b  = (const float*)d_in[15];
    const float* post_W = (const float*)d_in[16];
    const float* post_b = (const float*)d_in[17];
    const float* ro_W   = (const float*)d_in[18];
    const float* ro_b   = (const float*)d_in[19];
    float* out = (float*)d_out;

    char* w = (char*)d_ws;
    auto alloc = [&](size_t bytes) -> void* {
        void* p = (void*)w;
        w += (bytes + 255) & ~(size_t)255;
        return p;
    };
    int*   cnt  = (int*)  alloc((size_t)NN * 4);
    int*   off  = (int*)  alloc((size_t)(NN+1) * 4);
    int*   cur  = (int*)  alloc((size_t)NN * 4);
    int*   csr  = (int*)  alloc((size_t)NE * 4);
    int*   bsum = (int*)  alloc((size_t)SNB * 4);
    int*   bcur = (int*)  alloc((size_t)NBUK * 4);
    unsigned int* ebuf = (unsigned int*)alloc((size_t)NE * 4);
    float* dinv = (float*)alloc((size_t)NN * 4);
    float* xc   = (float*)alloc((size_t)NN * 128 * 4);
    unsigned short* xcb = (unsigned short*)alloc((size_t)NN * 128 * 2);  // bf16 shadow of xc
    float* hpre = (float*)alloc((size_t)NN * 128 * 4);   // aliased as hs in GCN phase
    unsigned short* hsb = (unsigned short*)alloc((size_t)NN * 64 * 2);   // bf16 shadow of hs
    float* h1   = (float*)alloc((size_t)NN * 64 * 4);    // aliased as xw after layers
    float* gbuf = (float*)alloc((size_t)NG * 64 * 4);
    float* hs = hpre;
    float* xw = h1;

    const int B = 256;
    // CSR build: count -> scan -> bin (dense appends) -> windowed scatter
    zero_i32<<<(NN + B-1)/B, B, 0, stream>>>(cnt, NN);
    count_deg<<<(NE + B-1)/B, B, 0, stream>>>(ei + NE, cnt, NE);
    scan_local <<<SNB, SBLK, 0, stream>>>(cnt, off, bsum, NN);
    scan_bsum  <<<1,   SBLK, 0, stream>>>(bsum, SNB);
    scan_finish<<<SNB, SBLK, 0, stream>>>(off, cur, cnt, bsum, dinv, bcur, NN, NE);
    bin_edges<<<(NE + B-1)/B, B, 0, stream>>>(ei, ei + NE, bcur, ebuf, NE);
    scatter_bucket<<<NWIN, SBLK, 0, stream>>>(ebuf, off, cur, csr, NN);

    const int GL = (NN + 63) / 64;   // linear64 grid
    const int GA = (NN + 3) / 4;     // agg grid

    // pre / emb -> xc = [x | s], with bf16 shadow
    linear64<FEATD><<<GL, B, 0, stream>>>(x, FEATD, pre_W, pre_b, xc,      128, xcb,      128, NN, 0);
    linear64<SED>  <<<GL, B, 0, stream>>>(s, SED,   emb_W, emb_b, xc + 64, 128, xcb + 64, 128, NN, 0);

    for (int i = 0; i < NLAY; i++){
        gin_agg<<<GA, B, 0, stream>>>(xc, (const unsigned int*)xcb, off, csr, hpre, NN);
        linear64<128><<<GL, B, 0, stream>>>(hpre, 128, gin_W1 + (size_t)i*128*64,
                                            gin_b1 + i*64, h1, 64, nullptr, 0, NN, 1);
        linear64<64> <<<GL, B, 0, stream>>>(h1, 64, gin_W2 + (size_t)i*64*64,
                                            gin_b2 + i*64, xc, 128, xcb, 128, NN, 1);
        linear64<64> <<<GL, B, 0, stream>>>(xc + 64, 128, gcn_W + (size_t)i*64*64,
                                            nullptr, hs, 64, hsb, 64, NN, 0);
        gcn_agg<<<GA, B, 0, stream>>>(hs, hsb, dinv, off, csr, gcn_b + i*64, xc, xcb, NN);
    }

    // whp -> xw
    linear64<128><<<GL, B, 0, stream>>>(xc, 128, whp_W, whp_b, xw, 64, nullptr, 0, NN, 0);

    // pool
    zero_f32<<<(NG*64 + B-1)/B, B, 0, stream>>>(gbuf, NG*64);
    pool_kernel<<<(NN + 127)/128, 64, 0, stream>>>(xw, batch, gbuf, NN);

    // head
    head_kernel<<<(NG + 3)/4, B, 0, stream>>>(gbuf, post_W, post_b, ro_W, ro_b, out, NG);
}

// Round 6
// 653.869 us; speedup vs baseline: 1.0334x; 1.0334x over previous
//
#include <hip/hip_runtime.h>
#include <math.h>

#define NN   50000
#define NE   800000
#define FEATD 128
#define SED  16
#define HD   64
#define NCLS 10
#define NLAY 3
#define NG   500

#define SBLK 256
#define SNB  ((NN + SBLK - 1) / SBLK)   // 196 blocks

// two-level counting sort params
#define CHUNK 8192                        // edges per bin block
#define NCH   ((NE + CHUNK - 1) / CHUNK)  // 98 chunks
#define CBSH  9                           // coarse bucket = dst >> 9 (512 nodes)
#define CB    ((NN + (1 << CBSH) - 1) >> CBSH)  // 98 coarse buckets

// ---- bf16 helpers ---------------------------------------------------------
__device__ inline unsigned short f2bf(float f){
    unsigned int u = __float_as_uint(f);
    u += 0x7fffu + ((u >> 16) & 1u);
    return (unsigned short)(u >> 16);
}
__device__ inline float bf_lo(unsigned int p){ return __uint_as_float(p << 16); }
__device__ inline float bf_hi(unsigned int p){ return __uint_as_float(p & 0xffff0000u); }

// ---------------- utility zero kernels ------------------------------------
__global__ void zero_i32(int* __restrict__ p, int n){
    int i = blockIdx.x*blockDim.x + threadIdx.x;
    if (i < n) p[i] = 0;
}
__global__ void zero_f32(float* __restrict__ p, int n){
    int i = blockIdx.x*blockDim.x + threadIdx.x;
    if (i < n) p[i] = 0.f;
}

// ---------------- degree count ---------------------------------------------
// harness delivers integer inputs as int32 (const int*), NOT int64.
__global__ void count_deg(const int* __restrict__ dst, int* __restrict__ cnt, int e){
    int i = blockIdx.x*blockDim.x + threadIdx.x;
    if (i < e) atomicAdd(&cnt[dst[i]], 1);
}

// ---------------- node-degree scan (off, dinv) -----------------------------
__global__ __launch_bounds__(SBLK) void scan_local(
        const int* __restrict__ cnt, int* __restrict__ off, int* __restrict__ bsum, int n){
    __shared__ int sh[SBLK];
    int t = threadIdx.x;
    int i = blockIdx.x * SBLK + t;
    int v = (i < n) ? cnt[i] : 0;
    sh[t] = v;
    __syncthreads();
#pragma unroll
    for (int d = 1; d < SBLK; d <<= 1){
        int u = (t >= d) ? sh[t-d] : 0;
        __syncthreads();
        sh[t] += u;
        __syncthreads();
    }
    if (i < n) off[i] = sh[t] - v;
    if (t == SBLK-1) bsum[blockIdx.x] = sh[t];
}

__global__ __launch_bounds__(SBLK) void scan_bsum(int* __restrict__ bsum, int nb){
    __shared__ int sh[SBLK];
    int t = threadIdx.x;
    int v = (t < nb) ? bsum[t] : 0;
    sh[t] = v;
    __syncthreads();
#pragma unroll
    for (int d = 1; d < SBLK; d <<= 1){
        int u = (t >= d) ? sh[t-d] : 0;
        __syncthreads();
        sh[t] += u;
        __syncthreads();
    }
    if (t < nb) bsum[t] = sh[t] - v;
}

__global__ __launch_bounds__(SBLK) void scan_finish(
        int* __restrict__ off, const int* __restrict__ cnt,
        const int* __restrict__ bsum, float* __restrict__ dinv, int n, int etot){
    int i = blockIdx.x * SBLK + threadIdx.x;
    if (i < n){
        off[i] = off[i] + bsum[blockIdx.x];
        dinv[i] = rsqrtf((float)cnt[i] + 1.0f);
    }
    if (i == 0) off[n] = etot;
}

// ---------------- two-level counting sort of edges by dst ------------------
// A: per-chunk coarse histogram (LDS) -> ghist[c*CB+b]
__global__ __launch_bounds__(256) void coarse_hist(
        const int* __restrict__ dst, int* __restrict__ ghist){
    __shared__ int h[CB];
    for (int i = threadIdx.x; i < CB; i += 256) h[i] = 0;
    __syncthreads();
    int base = blockIdx.x * CHUNK;
    int end  = base + CHUNK; if (end > NE) end = NE;
    for (int i = base + threadIdx.x; i < end; i += 256)
        atomicAdd(&h[dst[i] >> CBSH], 1);
    __syncthreads();
    for (int i = threadIdx.x; i < CB; i += 256)
        ghist[(size_t)blockIdx.x * CB + i] = h[i];
}

// B: ghist[c][b] -> global base offset for chunk c's bucket-b segment
__global__ __launch_bounds__(256) void coarse_scan(int* __restrict__ ghist){
    __shared__ int sh[256];
    int t = threadIdx.x;
    int run = 0;
    if (t < CB){
        for (int c = 0; c < NCH; c++){
            int v = ghist[(size_t)c*CB + t];
            ghist[(size_t)c*CB + t] = run;
            run += v;
        }
    }
    sh[t] = (t < CB) ? run : 0;
    __syncthreads();
    for (int d = 1; d < 256; d <<= 1){
        int u = (t >= d) ? sh[t-d] : 0;
        __syncthreads();
        sh[t] += u;
        __syncthreads();
    }
    int bstart = (t == 0) ? 0 : sh[t-1];
    if (t < CB){
        for (int c = 0; c < NCH; c++) ghist[(size_t)c*CB + t] += bstart;
    }
}

// C: LDS-staged bin: stage chunk, reorder by coarse bucket in LDS, flush
//    linearly -> all global writes are block-private contiguous runs.
__global__ __launch_bounds__(256) void bin_lds(
        const int* __restrict__ src, const int* __restrict__ dst,
        const int* __restrict__ ghist, unsigned int* __restrict__ ebuf){
    __shared__ unsigned int lbuf[CHUNK];
    __shared__ unsigned int lbuf2[CHUNK];
    __shared__ int hist[CB], lstart[CB], cursor[CB], gbase[CB];
    __shared__ int sc[256];
    int t = threadIdx.x, c = blockIdx.x;
    for (int i = t; i < CB; i += 256){
        hist[i] = 0;
        gbase[i] = ghist[(size_t)c*CB + i];
    }
    __syncthreads();
    int base = c * CHUNK;
    int nend = base + CHUNK; if (nend > NE) nend = NE;
    nend -= base;
    for (int i = t; i < nend; i += 256){
        int d = dst[base + i];
        lbuf[i] = (unsigned int)src[base + i] | ((unsigned int)d << 16);
        atomicAdd(&hist[d >> CBSH], 1);
    }
    __syncthreads();
    sc[t] = (t < CB) ? hist[t] : 0;
    __syncthreads();
    for (int d = 1; d < 256; d <<= 1){
        int u = (t >= d) ? sc[t-d] : 0;
        __syncthreads();
        sc[t] += u;
        __syncthreads();
    }
    if (t < CB){
        lstart[t] = sc[t] - hist[t];
        cursor[t] = sc[t] - hist[t];
    }
    __syncthreads();
    for (int i = t; i < nend; i += 256){
        unsigned int u = lbuf[i];
        int b = (int)(u >> 16) >> CBSH;
        int p = atomicAdd(&cursor[b], 1);
        lbuf2[p] = u;
    }
    __syncthreads();
    for (int p = t; p < nend; p += 256){
        unsigned int u = lbuf2[p];
        int b = (int)(u >> 16) >> CBSH;
        ebuf[gbase[b] + (p - lstart[b])] = u;
    }
}

// D: per-coarse-bucket scatter to exact CSR; node cursors in LDS, csr window
//    (~33KB) written by a single block -> dense lines.
__global__ __launch_bounds__(256) void scatter_win(
        const unsigned int* __restrict__ ebuf, const int* __restrict__ off,
        int* __restrict__ csr, int n){
    __shared__ int lcur[1 << CBSH];
    int b  = blockIdx.x;
    int n0 = b << CBSH;
    int n1 = n0 + (1 << CBSH); if (n1 > n) n1 = n;
    for (int i = threadIdx.x; i < n1 - n0; i += 256) lcur[i] = off[n0 + i];
    __syncthreads();
    int lo = off[n0], hi = off[n1];
    for (int j = lo + threadIdx.x; j < hi; j += 256){
        unsigned int u = ebuf[j];
        int d = (int)(u >> 16);
        int p = atomicAdd(&lcur[d - n0], 1);
        csr[p] = (int)(u & 0xffffu);
    }
}

// ---------------- fp32 tall-skinny linear: out[n,64] = A[n,K]@W[K,64] -----
template<int K>
__global__ __launch_bounds__(256) void linear64(
        const float* __restrict__ A, int lda,
        const float* __restrict__ W,
        const float* __restrict__ bias,
        float* __restrict__ out, int ldo,
        unsigned short* __restrict__ outb, int ldob,
        int n, int act)
{
    int lane = threadIdx.x & 63;
    int c0 = __builtin_amdgcn_readfirstlane((threadIdx.x >> 6) << 4);
    int row = blockIdx.x * 64 + lane;
    if (row >= n) return;
    float acc[16];
#pragma unroll
    for (int j = 0; j < 16; j++) acc[j] = 0.f;
    const float* a  = A + (size_t)row * lda;
    const float* wp = W + c0;
    for (int k = 0; k < K; k += 4){
        float4 av = *(const float4*)(a + k);
        float aa[4] = {av.x, av.y, av.z, av.w};
#pragma unroll
        for (int kk = 0; kk < 4; kk++){
            const float* wr = wp + (k + kk) * 64;
#pragma unroll
            for (int j = 0; j < 16; j++)
                acc[j] = fmaf(aa[kk], wr[j], acc[j]);
        }
    }
    if (bias){
#pragma unroll
        for (int j = 0; j < 16; j++) acc[j] += bias[c0 + j];
    }
    if (act == 1){
#pragma unroll
        for (int j = 0; j < 16; j++) acc[j] = fmaxf(acc[j], 0.f);
    }
    float* o = out + (size_t)row * ldo + c0;
#pragma unroll
    for (int q = 0; q < 4; q++){
        float4 v;
        v.x = acc[q*4+0]; v.y = acc[q*4+1]; v.z = acc[q*4+2]; v.w = acc[q*4+3];
        *(float4*)(o + q*4) = v;
    }
    if (outb){
        unsigned int pk[8];
#pragma unroll
        for (int j = 0; j < 8; j++)
            pk[j] = (unsigned int)f2bf(acc[2*j]) | ((unsigned int)f2bf(acc[2*j+1]) << 16);
        unsigned short* ob = outb + (size_t)row * ldob + c0;
        uint4 u0; u0.x = pk[0]; u0.y = pk[1]; u0.z = pk[2]; u0.w = pk[3];
        uint4 u1; u1.x = pk[4]; u1.y = pk[5]; u1.z = pk[6]; u1.w = pk[7];
        *(uint4*)(ob)     = u0;
        *(uint4*)(ob + 8) = u1;
    }
}

// ---------------- GIN aggregation (bf16 gather table) ----------------------
__global__ __launch_bounds__(256) void gin_agg(
        const float* __restrict__ xc, const unsigned int* __restrict__ xcb,
        const int* __restrict__ off, const int* __restrict__ csr,
        float* __restrict__ hpre, int n)
{
    int node = __builtin_amdgcn_readfirstlane(blockIdx.x * 4 + (threadIdx.x >> 6));
    int lane = threadIdx.x & 63;
    if (node >= n) return;
    int beg = off[node], end = off[node+1];
    float2 self = *(const float2*)(xc + (size_t)node*128 + 2*lane);
    float a0 = self.x, a1 = self.y;
    int e = beg;
    for (; e + 4 <= end; e += 4){
        int s0 = csr[e], s1 = csr[e+1], s2 = csr[e+2], s3 = csr[e+3];
        unsigned int p0 = xcb[(size_t)s0*64 + lane];
        unsigned int p1 = xcb[(size_t)s1*64 + lane];
        unsigned int p2 = xcb[(size_t)s2*64 + lane];
        unsigned int p3 = xcb[(size_t)s3*64 + lane];
        a0 += (bf_lo(p0) + bf_lo(p1)) + (bf_lo(p2) + bf_lo(p3));
        a1 += (bf_hi(p0) + bf_hi(p1)) + (bf_hi(p2) + bf_hi(p3));
    }
    for (; e < end; e++){
        unsigned int p0 = xcb[(size_t)csr[e]*64 + lane];
        a0 += bf_lo(p0);
        a1 += bf_hi(p0);
    }
    float2 r; r.x = a0; r.y = a1;
    *(float2*)(hpre + (size_t)node*128 + 2*lane) = r;
}

// ---------------- GCN aggregation (bf16 gather) + self + tanh --------------
__global__ __launch_bounds__(256) void gcn_agg(
        const float* __restrict__ hs, const unsigned short* __restrict__ hsb,
        const float* __restrict__ dinv,
        const int* __restrict__ off, const int* __restrict__ csr,
        const float* __restrict__ bias, float* __restrict__ xc,
        unsigned short* __restrict__ xcb, int n)
{
    int node = __builtin_amdgcn_readfirstlane(blockIdx.x * 4 + (threadIdx.x >> 6));
    int lane = threadIdx.x & 63;
    if (node >= n) return;
    int beg = off[node], end = off[node+1];
    float acc = 0.f;
    int e = beg;
    for (; e + 4 <= end; e += 4){
        int s0 = csr[e], s1 = csr[e+1], s2 = csr[e+2], s3 = csr[e+3];
        float v0 = dinv[s0] * __uint_as_float((unsigned int)hsb[(size_t)s0*64 + lane] << 16);
        float v1 = dinv[s1] * __uint_as_float((unsigned int)hsb[(size_t)s1*64 + lane] << 16);
        float v2 = dinv[s2] * __uint_as_float((unsigned int)hsb[(size_t)s2*64 + lane] << 16);
        float v3 = dinv[s3] * __uint_as_float((unsigned int)hsb[(size_t)s3*64 + lane] << 16);
        acc += (v0 + v1) + (v2 + v3);
    }
    for (; e < end; e++){
        int s0 = csr[e];
        acc += dinv[s0] * __uint_as_float((unsigned int)hsb[(size_t)s0*64 + lane] << 16);
    }
    float di   = dinv[node];
    float self = hs[(size_t)node*64 + lane];
    float v = tanhf(di*acc + self*di*di + bias[lane]);
    xc [(size_t)node*128 + 64 + lane] = v;
    xcb[(size_t)node*128 + 64 + lane] = f2bf(v);
}

// ---------------- global_add_pool (batch sorted, int32) -------------------
__global__ __launch_bounds__(64) void pool_kernel(
        const float* __restrict__ xw, const int* __restrict__ batch,
        float* __restrict__ g, int n)
{
    int lane = threadIdx.x;
    int r0 = blockIdx.x * 128;
    if (r0 >= n) return;
    int r1 = r0 + 128; if (r1 > n) r1 = n;
    float acc = 0.f;
    int cb = batch[r0];
    for (int r = r0; r < r1; r++){
        int b = batch[r];
        if (b != cb){
            atomicAdd(&g[(size_t)cb*64 + lane], acc);
            acc = 0.f; cb = b;
        }
        acc += xw[(size_t)r*64 + lane];
    }
    atomicAdd(&g[(size_t)cb*64 + lane], acc);
}

// ---------------- head ----------------------------------------------------
__global__ __launch_bounds__(256) void head_kernel(
        const float* __restrict__ g, const float* __restrict__ postW,
        const float* __restrict__ postb, const float* __restrict__ roW,
        const float* __restrict__ rob, float* __restrict__ out, int ngraph)
{
    int gr = __builtin_amdgcn_readfirstlane(blockIdx.x * 4 + (threadIdx.x >> 6));
    int lane = threadIdx.x & 63;
    if (gr >= ngraph) return;
    float gv = g[(size_t)gr*64 + lane];
    float t = postb[lane];
    for (int k = 0; k < 64; k++){
        float a = __shfl(gv, k);
        t = fmaf(a, postW[k*64 + lane], t);
    }
    t = fmaxf(t, 0.f);
    float lg = (lane < NCLS) ? rob[lane] : 0.f;
    for (int k = 0; k < 64; k++){
        float a = __shfl(t, k);
        float w = (lane < NCLS) ? roW[k*NCLS + lane] : 0.f;
        lg = fmaf(a, w, lg);
    }
    float m = (lane < NCLS) ? lg : -INFINITY;
#pragma unroll
    for (int d = 1; d < 16; d <<= 1) m = fmaxf(m, __shfl_xor(m, d, 16));
    float ex = (lane < NCLS) ? expf(lg - m) : 0.f;
    float ssum = ex;
#pragma unroll
    for (int d = 1; d < 16; d <<= 1) ssum += __shfl_xor(ssum, d, 16);
    if (lane < NCLS) out[(size_t)gr*NCLS + lane] = lg - m - logf(ssum);
}

// ---------------- launch --------------------------------------------------
extern "C" void kernel_launch(void* const* d_in, const int* in_sizes, int n_in,
                              void* d_out, int out_size, void* d_ws, size_t ws_size,
                              hipStream_t stream) {
    const float* x      = (const float*)d_in[0];
    const float* s      = (const float*)d_in[1];
    const int*   ei     = (const int*)d_in[2];    // int32
    const int*   batch  = (const int*)d_in[3];    // int32
    const float* pre_W  = (const float*)d_in[4];
    const float* pre_b  = (const float*)d_in[5];
    const float* emb_W  = (const float*)d_in[6];
    const float* emb_b  = (const float*)d_in[7];
    const float* gin_W1 = (const float*)d_in[8];
    const float* gin_b1 = (const float*)d_in[9];
    const float* gin_W2 = (const float*)d_in[10];
    const float* gin_b2 = (const float*)d_in[11];
    const float* gcn_W  = (const float*)d_in[12];
    const float* gcn_b  = (const float*)d_in[13];
    const float* whp_W  = (const float*)d_in[14];
    const float* whp_b  = (const float*)d_in[15];
    const float* post_W = (const float*)d_in[16];
    const float* post_b = (const float*)d_in[17];
    const float* ro_W   = (const float*)d_in[18];
    const float* ro_b   = (const float*)d_in[19];
    float* out = (float*)d_out;

    char* w = (char*)d_ws;
    auto alloc = [&](size_t bytes) -> void* {
        void* p = (void*)w;
        w += (bytes + 255) & ~(size_t)255;
        return p;
    };
    int*   cnt   = (int*)  alloc((size_t)NN * 4);
    int*   off   = (int*)  alloc((size_t)(NN+1) * 4);
    int*   csr   = (int*)  alloc((size_t)NE * 4);
    int*   bsum  = (int*)  alloc((size_t)SNB * 4);
    int*   ghist = (int*)  alloc((size_t)NCH * CB * 4);
    unsigned int* ebuf = (unsigned int*)alloc((size_t)NE * 4);
    float* dinv = (float*)alloc((size_t)NN * 4);
    float* xc   = (float*)alloc((size_t)NN * 128 * 4);
    unsigned short* xcb = (unsigned short*)alloc((size_t)NN * 128 * 2);
    float* hpre = (float*)alloc((size_t)NN * 128 * 4);   // aliased as hs in GCN phase
    unsigned short* hsb = (unsigned short*)alloc((size_t)NN * 64 * 2);
    float* h1   = (float*)alloc((size_t)NN * 64 * 4);    // aliased as xw after layers
    float* gbuf = (float*)alloc((size_t)NG * 64 * 4);
    float* hs = hpre;
    float* xw = h1;

    const int B = 256;
    // degree + off/dinv
    zero_i32<<<(NN + B-1)/B, B, 0, stream>>>(cnt, NN);
    count_deg<<<(NE + B-1)/B, B, 0, stream>>>(ei + NE, cnt, NE);
    scan_local <<<SNB, SBLK, 0, stream>>>(cnt, off, bsum, NN);
    scan_bsum  <<<1,   SBLK, 0, stream>>>(bsum, SNB);
    scan_finish<<<SNB, SBLK, 0, stream>>>(off, cnt, bsum, dinv, NN, NE);
    // two-level counting sort -> csr
    coarse_hist<<<NCH, 256, 0, stream>>>(ei + NE, ghist);
    coarse_scan<<<1,   256, 0, stream>>>(ghist);
    bin_lds    <<<NCH, 256, 0, stream>>>(ei, ei + NE, ghist, ebuf);
    scatter_win<<<CB,  256, 0, stream>>>(ebuf, off, csr, NN);

    const int GL = (NN + 63) / 64;   // linear64 grid
    const int GA = (NN + 3) / 4;     // agg grid

    // pre / emb -> xc = [x | s], with bf16 shadow
    linear64<FEATD><<<GL, B, 0, stream>>>(x, FEATD, pre_W, pre_b, xc,      128, xcb,      128, NN, 0);
    linear64<SED>  <<<GL, B, 0, stream>>>(s, SED,   emb_W, emb_b, xc + 64, 128, xcb + 64, 128, NN, 0);

    for (int i = 0; i < NLAY; i++){
        gin_agg<<<GA, B, 0, stream>>>(xc, (const unsigned int*)xcb, off, csr, hpre, NN);
        linear64<128><<<GL, B, 0, stream>>>(hpre, 128, gin_W1 + (size_t)i*128*64,
                                            gin_b1 + i*64, h1, 64, nullptr, 0, NN, 1);
        linear64<64> <<<GL, B, 0, stream>>>(h1, 64, gin_W2 + (size_t)i*64*64,
                                            gin_b2 + i*64, xc, 128, xcb, 128, NN, 1);
        linear64<64> <<<GL, B, 0, stream>>>(xc + 64, 128, gcn_W + (size_t)i*64*64,
                                            nullptr, hs, 64, hsb, 64, NN, 0);
        gcn_agg<<<GA, B, 0, stream>>>(hs, hsb, dinv, off, csr, gcn_b + i*64, xc, xcb, NN);
    }

    // whp -> xw
    linear64<128><<<GL, B, 0, stream>>>(xc, 128, whp_W, whp_b, xw, 64, nullptr, 0, NN, 0);

    // pool
    zero_f32<<<(NG*64 + B-1)/B, B, 0, stream>>>(gbuf, NG*64);
    pool_kernel<<<(NN + 127)/128, 64, 0, stream>>>(xw, batch, gbuf, NN);

    // head
    head_kernel<<<(NG + 3)/4, B, 0, stream>>>(gbuf, post_W, post_b, ro_W, ro_b, out, NG);
}

// Round 7
// 621.341 us; speedup vs baseline: 1.0875x; 1.0524x over previous
//
#include <hip/hip_runtime.h>
#include <math.h>

#define NN   50000
#define NE   800000
#define FEATD 128
#define SED  16
#define HD   64
#define NCLS 10
#define NLAY 3
#define NG   500

// two-level counting sort params
#define CHUNK 8192                        // edges per bin block
#define NCH   ((NE + CHUNK - 1) / CHUNK)  // 98 chunks
#define CBSH  9                           // coarse bucket = dst >> 9 (512 nodes)
#define CB    ((NN + (1 << CBSH) - 1) >> CBSH)  // 98 coarse buckets

// ---- bf16 helpers ---------------------------------------------------------
__device__ inline unsigned short f2bf(float f){
    unsigned int u = __float_as_uint(f);
    u += 0x7fffu + ((u >> 16) & 1u);
    return (unsigned short)(u >> 16);
}
__device__ inline float bf_lo(unsigned int p){ return __uint_as_float(p << 16); }
__device__ inline float bf_hi(unsigned int p){ return __uint_as_float(p & 0xffff0000u); }
__device__ inline float bf_up(unsigned short h){ return __uint_as_float((unsigned int)h << 16); }

// ---------------- two-level counting sort of edges by dst ------------------
// A: per-chunk coarse histogram (LDS) -> ghist[c*CB+b]
__global__ __launch_bounds__(256) void coarse_hist(
        const int* __restrict__ dst, int* __restrict__ ghist){
    __shared__ int h[CB];
    for (int i = threadIdx.x; i < CB; i += 256) h[i] = 0;
    __syncthreads();
    int base = blockIdx.x * CHUNK;
    int end  = base + CHUNK; if (end > NE) end = NE;
    for (int i = base + threadIdx.x; i < end; i += 256)
        atomicAdd(&h[dst[i] >> CBSH], 1);
    __syncthreads();
    for (int i = threadIdx.x; i < CB; i += 256)
        ghist[(size_t)blockIdx.x * CB + i] = h[i];
}

// B: ghist[c][b] -> global base offset for chunk c's bucket-b segment
//    (bucket-major order; ghist[0*CB+b] == bucketStart[b])
__global__ __launch_bounds__(256) void coarse_scan(int* __restrict__ ghist){
    __shared__ int sh[256];
    int t = threadIdx.x;
    int run = 0;
    if (t < CB){
        for (int c = 0; c < NCH; c++){
            int v = ghist[(size_t)c*CB + t];
            ghist[(size_t)c*CB + t] = run;
            run += v;
        }
    }
    sh[t] = (t < CB) ? run : 0;
    __syncthreads();
    for (int d = 1; d < 256; d <<= 1){
        int u = (t >= d) ? sh[t-d] : 0;
        __syncthreads();
        sh[t] += u;
        __syncthreads();
    }
    int bstart = (t == 0) ? 0 : sh[t-1];
    if (t < CB){
        for (int c = 0; c < NCH; c++) ghist[(size_t)c*CB + t] += bstart;
    }
}

// C: LDS-staged bin: stage chunk, reorder by coarse bucket in LDS, flush
//    linearly -> all global writes are block-private contiguous runs.
__global__ __launch_bounds__(256) void bin_lds(
        const int* __restrict__ src, const int* __restrict__ dst,
        const int* __restrict__ ghist, unsigned int* __restrict__ ebuf){
    __shared__ unsigned int lbuf[CHUNK];
    __shared__ unsigned int lbuf2[CHUNK];
    __shared__ int hist[CB], lstart[CB], cursor[CB], gbase[CB];
    __shared__ int sc[256];
    int t = threadIdx.x, c = blockIdx.x;
    for (int i = t; i < CB; i += 256){
        hist[i] = 0;
        gbase[i] = ghist[(size_t)c*CB + i];
    }
    __syncthreads();
    int base = c * CHUNK;
    int nend = base + CHUNK; if (nend > NE) nend = NE;
    nend -= base;
    for (int i = t; i < nend; i += 256){
        int d = dst[base + i];
        lbuf[i] = (unsigned int)src[base + i] | ((unsigned int)d << 16);
        atomicAdd(&hist[d >> CBSH], 1);
    }
    __syncthreads();
    sc[t] = (t < CB) ? hist[t] : 0;
    __syncthreads();
    for (int d = 1; d < 256; d <<= 1){
        int u = (t >= d) ? sc[t-d] : 0;
        __syncthreads();
        sc[t] += u;
        __syncthreads();
    }
    if (t < CB){
        lstart[t] = sc[t] - hist[t];
        cursor[t] = sc[t] - hist[t];
    }
    __syncthreads();
    for (int i = t; i < nend; i += 256){
        unsigned int u = lbuf[i];
        int b = (int)(u >> 16) >> CBSH;
        int p = atomicAdd(&cursor[b], 1);
        lbuf2[p] = u;
    }
    __syncthreads();
    for (int p = t; p < nend; p += 256){
        unsigned int u = lbuf2[p];
        int b = (int)(u >> 16) >> CBSH;
        ebuf[gbase[b] + (p - lstart[b])] = u;
    }
}

// D: per-bucket: node hist + LDS scan -> off, dinv, then dense csr scatter.
//    Replaces zero/count_deg/scan_local/scan_bsum/scan_finish/scatter_win.
__global__ __launch_bounds__(256) void scatter_all(
        const unsigned int* __restrict__ ebuf, const int* __restrict__ ghist,
        int* __restrict__ off, float* __restrict__ dinv,
        int* __restrict__ csr, int n){
    __shared__ int lcnt[512];
    __shared__ int lex[512];
    __shared__ int sc[256];
    int t = threadIdx.x, b = blockIdx.x;
    int n0 = b << CBSH;
    int nn = n - n0; if (nn > 512) nn = 512;
    int lo = ghist[b];
    int hi = (b + 1 < CB) ? ghist[b + 1] : NE;
    lcnt[t] = 0; lcnt[t + 256] = 0;
    __syncthreads();
    for (int j = lo + t; j < hi; j += 256)
        atomicAdd(&lcnt[(int)(ebuf[j] >> 16) - n0], 1);
    __syncthreads();
    int c0 = lcnt[2*t], c1 = lcnt[2*t+1];
    sc[t] = c0 + c1;
    __syncthreads();
    for (int d = 1; d < 256; d <<= 1){
        int u = (t >= d) ? sc[t-d] : 0;
        __syncthreads();
        sc[t] += u;
        __syncthreads();
    }
    int bse = sc[t] - (c0 + c1);
    lex[2*t]   = bse;
    lex[2*t+1] = bse + c0;
    __syncthreads();
    for (int i = t; i < nn; i += 256){
        off[n0 + i]  = lo + lex[i];
        dinv[n0 + i] = rsqrtf((float)lcnt[i] + 1.0f);
    }
    if (b == 0 && t == 0) off[n] = NE;
    __syncthreads();
    for (int j = lo + t; j < hi; j += 256){
        unsigned int u = ebuf[j];
        int d = (int)(u >> 16) - n0;
        int p = atomicAdd(&lex[d], 1);
        csr[lo + p] = (int)(u & 0xffffu);
    }
}

// ---------------- fp32 tall-skinny linear: out[n,64] = A[n,K]@W[K,64] -----
template<int K>
__global__ __launch_bounds__(256) void linear64(
        const float* __restrict__ A, int lda,
        const float* __restrict__ W,
        const float* __restrict__ bias,
        float* __restrict__ out, int ldo,
        unsigned short* __restrict__ outb, int ldob,
        int n, int act)
{
    int lane = threadIdx.x & 63;
    int c0 = __builtin_amdgcn_readfirstlane((threadIdx.x >> 6) << 4);
    int row = blockIdx.x * 64 + lane;
    if (row >= n) return;
    float acc[16];
#pragma unroll
    for (int j = 0; j < 16; j++) acc[j] = 0.f;
    const float* a  = A + (size_t)row * lda;
    const float* wp = W + c0;
    for (int k = 0; k < K; k += 4){
        float4 av = *(const float4*)(a + k);
        float aa[4] = {av.x, av.y, av.z, av.w};
#pragma unroll
        for (int kk = 0; kk < 4; kk++){
            const float* wr = wp + (k + kk) * 64;
#pragma unroll
            for (int j = 0; j < 16; j++)
                acc[j] = fmaf(aa[kk], wr[j], acc[j]);
        }
    }
    if (bias){
#pragma unroll
        for (int j = 0; j < 16; j++) acc[j] += bias[c0 + j];
    }
    if (act == 1){
#pragma unroll
        for (int j = 0; j < 16; j++) acc[j] = fmaxf(acc[j], 0.f);
    }
    float* o = out + (size_t)row * ldo + c0;
#pragma unroll
    for (int q = 0; q < 4; q++){
        float4 v;
        v.x = acc[q*4+0]; v.y = acc[q*4+1]; v.z = acc[q*4+2]; v.w = acc[q*4+3];
        *(float4*)(o + q*4) = v;
    }
    if (outb){
        unsigned int pk[8];
#pragma unroll
        for (int j = 0; j < 8; j++)
            pk[j] = (unsigned int)f2bf(acc[2*j]) | ((unsigned int)f2bf(acc[2*j+1]) << 16);
        unsigned short* ob = outb + (size_t)row * ldob + c0;
        uint4 u0; u0.x = pk[0]; u0.y = pk[1]; u0.z = pk[2]; u0.w = pk[3];
        uint4 u1; u1.x = pk[4]; u1.y = pk[5]; u1.z = pk[6]; u1.w = pk[7];
        *(uint4*)(ob)     = u0;
        *(uint4*)(ob + 8) = u1;
    }
}

// ---------------- merged GIN + GCN aggregation (one csr walk) --------------
// gin: hpre[n,128] = xc[n] + sum xcb_cur[src]   (lane -> col pair 2l,2l+1)
// gcn: s_new = tanh(di*sum(dinv[s]*hsb[s]) + hs[n]*di^2 + bias)
// writes s_new to xc right half (fp32) and xcb_nxt right half (bf16).
__global__ __launch_bounds__(256) void merged_agg(
        const float* __restrict__ xc, const unsigned int* __restrict__ xcb_cur,
        const float* __restrict__ hs, const unsigned short* __restrict__ hsb,
        const float* __restrict__ dinv,
        const int* __restrict__ off, const int* __restrict__ csr,
        const float* __restrict__ bias,
        float* __restrict__ hpre, float* __restrict__ xc_out,
        unsigned short* __restrict__ xcb_nxt, int n)
{
    int node = __builtin_amdgcn_readfirstlane(blockIdx.x * 4 + (threadIdx.x >> 6));
    int lane = threadIdx.x & 63;
    if (node >= n) return;
    int beg = off[node], end = off[node+1];
    float2 self2 = *(const float2*)(xc + (size_t)node*128 + 2*lane);
    float a0 = self2.x, a1 = self2.y;
    float ag = 0.f;
    int e = beg;
    for (; e + 4 <= end; e += 4){
        int s0 = csr[e], s1 = csr[e+1], s2 = csr[e+2], s3 = csr[e+3];
        unsigned int p0 = xcb_cur[(size_t)s0*64 + lane];
        unsigned int p1 = xcb_cur[(size_t)s1*64 + lane];
        unsigned int p2 = xcb_cur[(size_t)s2*64 + lane];
        unsigned int p3 = xcb_cur[(size_t)s3*64 + lane];
        float h0 = bf_up(hsb[(size_t)s0*64 + lane]);
        float h1 = bf_up(hsb[(size_t)s1*64 + lane]);
        float h2 = bf_up(hsb[(size_t)s2*64 + lane]);
        float h3 = bf_up(hsb[(size_t)s3*64 + lane]);
        a0 += (bf_lo(p0) + bf_lo(p1)) + (bf_lo(p2) + bf_lo(p3));
        a1 += (bf_hi(p0) + bf_hi(p1)) + (bf_hi(p2) + bf_hi(p3));
        ag += (dinv[s0]*h0 + dinv[s1]*h1) + (dinv[s2]*h2 + dinv[s3]*h3);
    }
    for (; e < end; e++){
        int s0 = csr[e];
        unsigned int p0 = xcb_cur[(size_t)s0*64 + lane];
        a0 += bf_lo(p0);
        a1 += bf_hi(p0);
        ag += dinv[s0] * bf_up(hsb[(size_t)s0*64 + lane]);
    }
    float2 r; r.x = a0; r.y = a1;
    *(float2*)(hpre + (size_t)node*128 + 2*lane) = r;
    float di   = dinv[node];
    float self = hs[(size_t)node*64 + lane];
    float v = tanhf(di*ag + self*di*di + bias[lane]);
    xc_out [(size_t)node*128 + 64 + lane] = v;
    xcb_nxt[(size_t)node*128 + 64 + lane] = f2bf(v);
}

// ---------------- fused GIN MLP: x = relu(relu(hpre@W1+b1)@W2+b2) ----------
// block: 64 rows, 4 waves (wave = 16-col group for both GEMMs); h in LDS.
__global__ __launch_bounds__(256) void gin_mlp(
        const float* __restrict__ hpre,
        const float* __restrict__ W1, const float* __restrict__ b1,
        const float* __restrict__ W2, const float* __restrict__ b2,
        float* __restrict__ xc, unsigned short* __restrict__ xcb_nxt, int n)
{
    __shared__ float hsh[64][65];
    int lane = threadIdx.x & 63;
    int c0 = __builtin_amdgcn_readfirstlane((threadIdx.x >> 6) << 4);
    int row = blockIdx.x * 64 + lane;
    float acc[16];
#pragma unroll
    for (int j = 0; j < 16; j++) acc[j] = 0.f;
    if (row < n){
        const float* a = hpre + (size_t)row * 128;
        for (int k = 0; k < 128; k += 4){
            float4 av = *(const float4*)(a + k);
            float aa[4] = {av.x, av.y, av.z, av.w};
#pragma unroll
            for (int kk = 0; kk < 4; kk++){
                const float* wr = W1 + (k + kk) * 64 + c0;
#pragma unroll
                for (int j = 0; j < 16; j++)
                    acc[j] = fmaf(aa[kk], wr[j], acc[j]);
            }
        }
    }
#pragma unroll
    for (int j = 0; j < 16; j++)
        hsh[lane][c0 + j] = fmaxf(acc[j] + b1[c0 + j], 0.f);
    __syncthreads();
    float acc2[16];
#pragma unroll
    for (int j = 0; j < 16; j++) acc2[j] = 0.f;
    for (int k = 0; k < 64; k++){
        float a = hsh[lane][k];
        const float* wr = W2 + k * 64 + c0;
#pragma unroll
        for (int j = 0; j < 16; j++)
            acc2[j] = fmaf(a, wr[j], acc2[j]);
    }
    if (row < n){
#pragma unroll
        for (int j = 0; j < 16; j++) acc2[j] = fmaxf(acc2[j] + b2[c0 + j], 0.f);
        float* o = xc + (size_t)row * 128 + c0;
#pragma unroll
        for (int q = 0; q < 4; q++){
            float4 v;
            v.x = acc2[q*4+0]; v.y = acc2[q*4+1]; v.z = acc2[q*4+2]; v.w = acc2[q*4+3];
            *(float4*)(o + q*4) = v;
        }
        unsigned int pk[8];
#pragma unroll
        for (int j = 0; j < 8; j++)
            pk[j] = (unsigned int)f2bf(acc2[2*j]) | ((unsigned int)f2bf(acc2[2*j+1]) << 16);
        unsigned short* ob = xcb_nxt + (size_t)row * 128 + c0;
        uint4 u0; u0.x = pk[0]; u0.y = pk[1]; u0.z = pk[2]; u0.w = pk[3];
        uint4 u1; u1.x = pk[4]; u1.y = pk[5]; u1.z = pk[6]; u1.w = pk[7];
        *(uint4*)(ob)     = u0;
        *(uint4*)(ob + 8) = u1;
    }
}

// ---------------- global_add_pool: block per graph, binary search ----------
__global__ __launch_bounds__(64) void pool_kernel(
        const float* __restrict__ xw, const int* __restrict__ batch,
        float* __restrict__ g, int n)
{
    int gr = blockIdx.x;
    int lane = threadIdx.x;
    int lo = 0, hi = n;
    while (lo < hi){ int m = (lo + hi) >> 1; if (batch[m] < gr) lo = m + 1; else hi = m; }
    int r0 = lo;
    hi = n;
    while (lo < hi){ int m = (lo + hi) >> 1; if (batch[m] < gr + 1) lo = m + 1; else hi = m; }
    int r1 = lo;
    float acc = 0.f;
    for (int r = r0; r < r1; r++) acc += xw[(size_t)r*64 + lane];
    g[(size_t)gr*64 + lane] = acc;
}

// ---------------- head ----------------------------------------------------
__global__ __launch_bounds__(256) void head_kernel(
        const float* __restrict__ g, const float* __restrict__ postW,
        const float* __restrict__ postb, const float* __restrict__ roW,
        const float* __restrict__ rob, float* __restrict__ out, int ngraph)
{
    int gr = __builtin_amdgcn_readfirstlane(blockIdx.x * 4 + (threadIdx.x >> 6));
    int lane = threadIdx.x & 63;
    if (gr >= ngraph) return;
    float gv = g[(size_t)gr*64 + lane];
    float t = postb[lane];
    for (int k = 0; k < 64; k++){
        float a = __shfl(gv, k);
        t = fmaf(a, postW[k*64 + lane], t);
    }
    t = fmaxf(t, 0.f);
    float lg = (lane < NCLS) ? rob[lane] : 0.f;
    for (int k = 0; k < 64; k++){
        float a = __shfl(t, k);
        float w = (lane < NCLS) ? roW[k*NCLS + lane] : 0.f;
        lg = fmaf(a, w, lg);
    }
    float m = (lane < NCLS) ? lg : -INFINITY;
#pragma unroll
    for (int d = 1; d < 16; d <<= 1) m = fmaxf(m, __shfl_xor(m, d, 16));
    float ex = (lane < NCLS) ? expf(lg - m) : 0.f;
    float ssum = ex;
#pragma unroll
    for (int d = 1; d < 16; d <<= 1) ssum += __shfl_xor(ssum, d, 16);
    if (lane < NCLS) out[(size_t)gr*NCLS + lane] = lg - m - logf(ssum);
}

// ---------------- launch --------------------------------------------------
extern "C" void kernel_launch(void* const* d_in, const int* in_sizes, int n_in,
                              void* d_out, int out_size, void* d_ws, size_t ws_size,
                              hipStream_t stream) {
    const float* x      = (const float*)d_in[0];
    const float* s      = (const float*)d_in[1];
    const int*   ei     = (const int*)d_in[2];    // int32
    const int*   batch  = (const int*)d_in[3];    // int32
    const float* pre_W  = (const float*)d_in[4];
    const float* pre_b  = (const float*)d_in[5];
    const float* emb_W  = (const float*)d_in[6];
    const float* emb_b  = (const float*)d_in[7];
    const float* gin_W1 = (const float*)d_in[8];
    const float* gin_b1 = (const float*)d_in[9];
    const float* gin_W2 = (const float*)d_in[10];
    const float* gin_b2 = (const float*)d_in[11];
    const float* gcn_W  = (const float*)d_in[12];
    const float* gcn_b  = (const float*)d_in[13];
    const float* whp_W  = (const float*)d_in[14];
    const float* whp_b  = (const float*)d_in[15];
    const float* post_W = (const float*)d_in[16];
    const float* post_b = (const float*)d_in[17];
    const float* ro_W   = (const float*)d_in[18];
    const float* ro_b   = (const float*)d_in[19];
    float* out = (float*)d_out;

    char* w = (char*)d_ws;
    auto alloc = [&](size_t bytes) -> void* {
        void* p = (void*)w;
        w += (bytes + 255) & ~(size_t)255;
        return p;
    };
    int*   off   = (int*)  alloc((size_t)(NN+1) * 4);
    int*   csr   = (int*)  alloc((size_t)NE * 4);
    int*   ghist = (int*)  alloc((size_t)NCH * CB * 4);
    unsigned int* ebuf = (unsigned int*)alloc((size_t)NE * 4);
    float* dinv = (float*)alloc((size_t)NN * 4);
    float* xc   = (float*)alloc((size_t)NN * 128 * 4);
    unsigned short* xcb0 = (unsigned short*)alloc((size_t)NN * 128 * 2);
    unsigned short* xcb1 = (unsigned short*)alloc((size_t)NN * 128 * 2);
    float* hpre = (float*)alloc((size_t)NN * 128 * 4);
    float* hs   = (float*)alloc((size_t)NN * 64 * 4);
    unsigned short* hsb = (unsigned short*)alloc((size_t)NN * 64 * 2);
    float* xw   = (float*)alloc((size_t)NN * 64 * 4);
    float* gbuf = (float*)alloc((size_t)NG * 64 * 4);

    const int B  = 256;
    const int GL = (NN + 63) / 64;   // 782
    const int GA = (NN + 3) / 4;     // 12500

    // CSR build: 4 dispatches
    coarse_hist<<<NCH, 256, 0, stream>>>(ei + NE, ghist);
    coarse_scan<<<1,   256, 0, stream>>>(ghist);
    bin_lds    <<<NCH, 256, 0, stream>>>(ei, ei + NE, ghist, ebuf);
    scatter_all<<<CB,  256, 0, stream>>>(ebuf, ghist, off, dinv, csr, NN);

    // pre / emb -> xc = [x | s], bf16 shadow into xcb0
    linear64<FEATD><<<GL, B, 0, stream>>>(x, FEATD, pre_W, pre_b, xc,      128, xcb0,      128, NN, 0);
    linear64<SED>  <<<GL, B, 0, stream>>>(s, SED,   emb_W, emb_b, xc + 64, 128, xcb0 + 64, 128, NN, 0);

    for (int i = 0; i < NLAY; i++){
        unsigned short* cur = (i & 1) ? xcb1 : xcb0;
        unsigned short* nxt = (i & 1) ? xcb0 : xcb1;
        // hs = s_{i-1} @ gcn_W  (must precede merged_agg)
        linear64<64><<<GL, B, 0, stream>>>(xc + 64, 128, gcn_W + (size_t)i*64*64,
                                           nullptr, hs, 64, hsb, 64, NN, 0);
        merged_agg<<<GA, B, 0, stream>>>(xc, (const unsigned int*)cur, hs, hsb, dinv,
                                         off, csr, gcn_b + i*64, hpre, xc, nxt, NN);
        gin_mlp<<<GL, B, 0, stream>>>(hpre, gin_W1 + (size_t)i*128*64, gin_b1 + i*64,
                                      gin_W2 + (size_t)i*64*64, gin_b2 + i*64,
                                      xc, nxt, NN);
    }

    // whp -> xw
    linear64<128><<<GL, B, 0, stream>>>(xc, 128, whp_W, whp_b, xw, 64, nullptr, 0, NN, 0);

    // pool (atomic-free, block per graph) + head
    pool_kernel<<<NG, 64, 0, stream>>>(xw, batch, gbuf, NN);
    head_kernel<<<(NG + 3)/4, B, 0, stream>>>(gbuf, post_W, post_b, ro_W, ro_b, out, NG);
}

// Round 8
// 613.219 us; speedup vs baseline: 1.1019x; 1.0132x over previous
//
#include <hip/hip_runtime.h>
#include <math.h>

#define NN   50000
#define NE   800000
#define FEATD 128
#define SED  16
#define HD   64
#define NCLS 10
#define NLAY 3
#define NG   500

// two-level counting sort params
#define CHUNK 8192                        // edges per bin block
#define NCH   ((NE + CHUNK - 1) / CHUNK)  // 98 chunks
#define CBSH  9                           // coarse bucket = dst >> 9 (512 nodes)
#define CB    ((NN + (1 << CBSH) - 1) >> CBSH)  // 98 coarse buckets

// ---- bf16 helpers ---------------------------------------------------------
__device__ inline unsigned short f2bf(float f){
    unsigned int u = __float_as_uint(f);
    u += 0x7fffu + ((u >> 16) & 1u);
    return (unsigned short)(u >> 16);
}
__device__ inline float bf_lo(unsigned int p){ return __uint_as_float(p << 16); }
__device__ inline float bf_hi(unsigned int p){ return __uint_as_float(p & 0xffff0000u); }
__device__ inline float bf_up(unsigned short h){ return __uint_as_float((unsigned int)h << 16); }

// ---------------- two-level counting sort of edges by dst ------------------
__global__ __launch_bounds__(256) void coarse_hist(
        const int* __restrict__ dst, int* __restrict__ ghist){
    __shared__ int h[CB];
    for (int i = threadIdx.x; i < CB; i += 256) h[i] = 0;
    __syncthreads();
    int base = blockIdx.x * CHUNK;
    int end  = base + CHUNK; if (end > NE) end = NE;
    for (int i = base + threadIdx.x; i < end; i += 256)
        atomicAdd(&h[dst[i] >> CBSH], 1);
    __syncthreads();
    for (int i = threadIdx.x; i < CB; i += 256)
        ghist[(size_t)blockIdx.x * CB + i] = h[i];
}

__global__ __launch_bounds__(256) void coarse_scan(int* __restrict__ ghist){
    __shared__ int sh[256];
    int t = threadIdx.x;
    int run = 0;
    if (t < CB){
        for (int c = 0; c < NCH; c++){
            int v = ghist[(size_t)c*CB + t];
            ghist[(size_t)c*CB + t] = run;
            run += v;
        }
    }
    sh[t] = (t < CB) ? run : 0;
    __syncthreads();
    for (int d = 1; d < 256; d <<= 1){
        int u = (t >= d) ? sh[t-d] : 0;
        __syncthreads();
        sh[t] += u;
        __syncthreads();
    }
    int bstart = (t == 0) ? 0 : sh[t-1];
    if (t < CB){
        for (int c = 0; c < NCH; c++) ghist[(size_t)c*CB + t] += bstart;
    }
}

__global__ __launch_bounds__(256) void bin_lds(
        const int* __restrict__ src, const int* __restrict__ dst,
        const int* __restrict__ ghist, unsigned int* __restrict__ ebuf){
    __shared__ unsigned int lbuf[CHUNK];
    __shared__ unsigned int lbuf2[CHUNK];
    __shared__ int hist[CB], lstart[CB], cursor[CB], gbase[CB];
    __shared__ int sc[256];
    int t = threadIdx.x, c = blockIdx.x;
    for (int i = t; i < CB; i += 256){
        hist[i] = 0;
        gbase[i] = ghist[(size_t)c*CB + i];
    }
    __syncthreads();
    int base = c * CHUNK;
    int nend = base + CHUNK; if (nend > NE) nend = NE;
    nend -= base;
    for (int i = t; i < nend; i += 256){
        int d = dst[base + i];
        lbuf[i] = (unsigned int)src[base + i] | ((unsigned int)d << 16);
        atomicAdd(&hist[d >> CBSH], 1);
    }
    __syncthreads();
    sc[t] = (t < CB) ? hist[t] : 0;
    __syncthreads();
    for (int d = 1; d < 256; d <<= 1){
        int u = (t >= d) ? sc[t-d] : 0;
        __syncthreads();
        sc[t] += u;
        __syncthreads();
    }
    if (t < CB){
        lstart[t] = sc[t] - hist[t];
        cursor[t] = sc[t] - hist[t];
    }
    __syncthreads();
    for (int i = t; i < nend; i += 256){
        unsigned int u = lbuf[i];
        int b = (int)(u >> 16) >> CBSH;
        int p = atomicAdd(&cursor[b], 1);
        lbuf2[p] = u;
    }
    __syncthreads();
    for (int p = t; p < nend; p += 256){
        unsigned int u = lbuf2[p];
        int b = (int)(u >> 16) >> CBSH;
        ebuf[gbase[b] + (p - lstart[b])] = u;
    }
}

__global__ __launch_bounds__(256) void scatter_all(
        const unsigned int* __restrict__ ebuf, const int* __restrict__ ghist,
        int* __restrict__ off, float* __restrict__ dinv,
        int* __restrict__ csr, int n){
    __shared__ int lcnt[512];
    __shared__ int lex[512];
    __shared__ int sc[256];
    int t = threadIdx.x, b = blockIdx.x;
    int n0 = b << CBSH;
    int nn = n - n0; if (nn > 512) nn = 512;
    int lo = ghist[b];
    int hi = (b + 1 < CB) ? ghist[b + 1] : NE;
    lcnt[t] = 0; lcnt[t + 256] = 0;
    __syncthreads();
    for (int j = lo + t; j < hi; j += 256)
        atomicAdd(&lcnt[(int)(ebuf[j] >> 16) - n0], 1);
    __syncthreads();
    int c0 = lcnt[2*t], c1 = lcnt[2*t+1];
    sc[t] = c0 + c1;
    __syncthreads();
    for (int d = 1; d < 256; d <<= 1){
        int u = (t >= d) ? sc[t-d] : 0;
        __syncthreads();
        sc[t] += u;
        __syncthreads();
    }
    int bse = sc[t] - (c0 + c1);
    lex[2*t]   = bse;
    lex[2*t+1] = bse + c0;
    __syncthreads();
    for (int i = t; i < nn; i += 256){
        off[n0 + i]  = lo + lex[i];
        dinv[n0 + i] = rsqrtf((float)lcnt[i] + 1.0f);
    }
    if (b == 0 && t == 0) off[n] = NE;
    __syncthreads();
    for (int j = lo + t; j < hi; j += 256){
        unsigned int u = ebuf[j];
        int d = (int)(u >> 16) - n0;
        int p = atomicAdd(&lex[d], 1);
        csr[lo + p] = (int)(u & 0xffffu);
    }
}

// ---------------- fp32 tall-skinny linear: out[n,64] = A[n,K]@W[K,64] -----
// A-tile staged into LDS with coalesced loads; lane=row reads its row via
// ds_read_b128 (stride K+4 floats, 16B aligned). W reads are wave-uniform
// (scalar). Optional bf16 shadow output.
template<int K>
__global__ __launch_bounds__(256) void linear64(
        const float* __restrict__ A, int lda,
        const float* __restrict__ W,
        const float* __restrict__ bias,
        float* __restrict__ out, int ldo,
        unsigned short* __restrict__ outb, int ldob,
        int n, int act)
{
    constexpr int STR = K + 4;
    constexpr int NQ  = K / 4;
    __shared__ float at[64 * STR];
    int tid = threadIdx.x;
    int r0  = blockIdx.x * 64;
    for (int idx = tid; idx < 64 * NQ; idx += 256){
        int row = idx / NQ, kq = idx - row * NQ;
        float4 v = make_float4(0.f, 0.f, 0.f, 0.f);
        if (r0 + row < n) v = *(const float4*)(A + (size_t)(r0 + row) * lda + kq * 4);
        *(float4*)(&at[row * STR + kq * 4]) = v;
    }
    __syncthreads();
    int lane = tid & 63;
    int c0 = __builtin_amdgcn_readfirstlane((tid >> 6) << 4);
    int row = r0 + lane;
    if (row >= n) return;
    float acc[16];
#pragma unroll
    for (int j = 0; j < 16; j++) acc[j] = 0.f;
    const float* wp = W + c0;
    for (int k = 0; k < K; k += 4){
        float4 av = *(const float4*)(&at[lane * STR + k]);
        float aa[4] = {av.x, av.y, av.z, av.w};
#pragma unroll
        for (int kk = 0; kk < 4; kk++){
            const float* wr = wp + (k + kk) * 64;
#pragma unroll
            for (int j = 0; j < 16; j++)
                acc[j] = fmaf(aa[kk], wr[j], acc[j]);
        }
    }
    if (bias){
#pragma unroll
        for (int j = 0; j < 16; j++) acc[j] += bias[c0 + j];
    }
    if (act == 1){
#pragma unroll
        for (int j = 0; j < 16; j++) acc[j] = fmaxf(acc[j], 0.f);
    }
    float* o = out + (size_t)row * ldo + c0;
#pragma unroll
    for (int q = 0; q < 4; q++){
        float4 v;
        v.x = acc[q*4+0]; v.y = acc[q*4+1]; v.z = acc[q*4+2]; v.w = acc[q*4+3];
        *(float4*)(o + q*4) = v;
    }
    if (outb){
        unsigned int pk[8];
#pragma unroll
        for (int j = 0; j < 8; j++)
            pk[j] = (unsigned int)f2bf(acc[2*j]) | ((unsigned int)f2bf(acc[2*j+1]) << 16);
        unsigned short* ob = outb + (size_t)row * ldob + c0;
        uint4 u0; u0.x = pk[0]; u0.y = pk[1]; u0.z = pk[2]; u0.w = pk[3];
        uint4 u1; u1.x = pk[4]; u1.y = pk[5]; u1.z = pk[6]; u1.w = pk[7];
        *(uint4*)(ob)     = u0;
        *(uint4*)(ob + 8) = u1;
    }
}

// ---------------- merged GIN + GCN aggregation (one csr walk) --------------
__global__ __launch_bounds__(256) void merged_agg(
        const float* __restrict__ xc, const unsigned int* __restrict__ xcb_cur,
        const float* __restrict__ hs, const unsigned short* __restrict__ hsb,
        const float* __restrict__ dinv,
        const int* __restrict__ off, const int* __restrict__ csr,
        const float* __restrict__ bias,
        float* __restrict__ hpre, float* __restrict__ xc_out,
        unsigned short* __restrict__ xcb_nxt, int n)
{
    int node = __builtin_amdgcn_readfirstlane(blockIdx.x * 4 + (threadIdx.x >> 6));
    int lane = threadIdx.x & 63;
    if (node >= n) return;
    int beg = off[node], end = off[node+1];
    float2 self2 = *(const float2*)(xc + (size_t)node*128 + 2*lane);
    float a0 = self2.x, a1 = self2.y;
    float ag = 0.f;
    int e = beg;
    for (; e + 4 <= end; e += 4){
        int s0 = csr[e], s1 = csr[e+1], s2 = csr[e+2], s3 = csr[e+3];
        unsigned int p0 = xcb_cur[(size_t)s0*64 + lane];
        unsigned int p1 = xcb_cur[(size_t)s1*64 + lane];
        unsigned int p2 = xcb_cur[(size_t)s2*64 + lane];
        unsigned int p3 = xcb_cur[(size_t)s3*64 + lane];
        float h0 = bf_up(hsb[(size_t)s0*64 + lane]);
        float h1 = bf_up(hsb[(size_t)s1*64 + lane]);
        float h2 = bf_up(hsb[(size_t)s2*64 + lane]);
        float h3 = bf_up(hsb[(size_t)s3*64 + lane]);
        a0 += (bf_lo(p0) + bf_lo(p1)) + (bf_lo(p2) + bf_lo(p3));
        a1 += (bf_hi(p0) + bf_hi(p1)) + (bf_hi(p2) + bf_hi(p3));
        ag += (dinv[s0]*h0 + dinv[s1]*h1) + (dinv[s2]*h2 + dinv[s3]*h3);
    }
    for (; e < end; e++){
        int s0 = csr[e];
        unsigned int p0 = xcb_cur[(size_t)s0*64 + lane];
        a0 += bf_lo(p0);
        a1 += bf_hi(p0);
        ag += dinv[s0] * bf_up(hsb[(size_t)s0*64 + lane]);
    }
    float2 r; r.x = a0; r.y = a1;
    *(float2*)(hpre + (size_t)node*128 + 2*lane) = r;
    float di   = dinv[node];
    float self = hs[(size_t)node*64 + lane];
    float v = tanhf(di*ag + self*di*di + bias[lane]);
    xc_out [(size_t)node*128 + 64 + lane] = v;
    xcb_nxt[(size_t)node*128 + 64 + lane] = f2bf(v);
}

// ---------------- fused GIN MLP: x = relu(relu(hpre@W1+b1)@W2+b2) ----------
// A-tile (64x128) staged coalesced into LDS; h round-trip also in LDS.
__global__ __launch_bounds__(256) void gin_mlp(
        const float* __restrict__ hpre,
        const float* __restrict__ W1, const float* __restrict__ b1,
        const float* __restrict__ W2, const float* __restrict__ b2,
        float* __restrict__ xc, unsigned short* __restrict__ xcb_nxt, int n)
{
    __shared__ float at[64 * 132];
    __shared__ float hsh[64][65];
    int tid = threadIdx.x;
    int r0  = blockIdx.x * 64;
    for (int idx = tid; idx < 64 * 32; idx += 256){
        int row = idx >> 5, kq = idx & 31;
        float4 v = make_float4(0.f, 0.f, 0.f, 0.f);
        if (r0 + row < n) v = *(const float4*)(hpre + (size_t)(r0 + row) * 128 + kq * 4);
        *(float4*)(&at[row * 132 + kq * 4]) = v;
    }
    __syncthreads();
    int lane = tid & 63;
    int c0 = __builtin_amdgcn_readfirstlane((tid >> 6) << 4);
    int row = r0 + lane;
    float acc[16];
#pragma unroll
    for (int j = 0; j < 16; j++) acc[j] = 0.f;
    for (int k = 0; k < 128; k += 4){
        float4 av = *(const float4*)(&at[lane * 132 + k]);
        float aa[4] = {av.x, av.y, av.z, av.w};
#pragma unroll
        for (int kk = 0; kk < 4; kk++){
            const float* wr = W1 + (k + kk) * 64 + c0;
#pragma unroll
            for (int j = 0; j < 16; j++)
                acc[j] = fmaf(aa[kk], wr[j], acc[j]);
        }
    }
#pragma unroll
    for (int j = 0; j < 16; j++)
        hsh[lane][c0 + j] = fmaxf(acc[j] + b1[c0 + j], 0.f);
    __syncthreads();
    float acc2[16];
#pragma unroll
    for (int j = 0; j < 16; j++) acc2[j] = 0.f;
    for (int k = 0; k < 64; k++){
        float a = hsh[lane][k];
        const float* wr = W2 + k * 64 + c0;
#pragma unroll
        for (int j = 0; j < 16; j++)
            acc2[j] = fmaf(a, wr[j], acc2[j]);
    }
    if (row < n){
#pragma unroll
        for (int j = 0; j < 16; j++) acc2[j] = fmaxf(acc2[j] + b2[c0 + j], 0.f);
        float* o = xc + (size_t)row * 128 + c0;
#pragma unroll
        for (int q = 0; q < 4; q++){
            float4 v;
            v.x = acc2[q*4+0]; v.y = acc2[q*4+1]; v.z = acc2[q*4+2]; v.w = acc2[q*4+3];
            *(float4*)(o + q*4) = v;
        }
        unsigned int pk[8];
#pragma unroll
        for (int j = 0; j < 8; j++)
            pk[j] = (unsigned int)f2bf(acc2[2*j]) | ((unsigned int)f2bf(acc2[2*j+1]) << 16);
        unsigned short* ob = xcb_nxt + (size_t)row * 128 + c0;
        uint4 u0; u0.x = pk[0]; u0.y = pk[1]; u0.z = pk[2]; u0.w = pk[3];
        uint4 u1; u1.x = pk[4]; u1.y = pk[5]; u1.z = pk[6]; u1.w = pk[7];
        *(uint4*)(ob)     = u0;
        *(uint4*)(ob + 8) = u1;
    }
}

// ---------------- global_add_pool: block per graph, binary search ----------
__global__ __launch_bounds__(64) void pool_kernel(
        const float* __restrict__ xw, const int* __restrict__ batch,
        float* __restrict__ g, int n)
{
    int gr = blockIdx.x;
    int lane = threadIdx.x;
    int lo = 0, hi = n;
    while (lo < hi){ int m = (lo + hi) >> 1; if (batch[m] < gr) lo = m + 1; else hi = m; }
    int r0 = lo;
    hi = n;
    while (lo < hi){ int m = (lo + hi) >> 1; if (batch[m] < gr + 1) lo = m + 1; else hi = m; }
    int r1 = lo;
    float acc = 0.f;
    for (int r = r0; r < r1; r++) acc += xw[(size_t)r*64 + lane];
    g[(size_t)gr*64 + lane] = acc;
}

// ---------------- head ----------------------------------------------------
__global__ __launch_bounds__(256) void head_kernel(
        const float* __restrict__ g, const float* __restrict__ postW,
        const float* __restrict__ postb, const float* __restrict__ roW,
        const float* __restrict__ rob, float* __restrict__ out, int ngraph)
{
    int gr = __builtin_amdgcn_readfirstlane(blockIdx.x * 4 + (threadIdx.x >> 6));
    int lane = threadIdx.x & 63;
    if (gr >= ngraph) return;
    float gv = g[(size_t)gr*64 + lane];
    float t = postb[lane];
    for (int k = 0; k < 64; k++){
        float a = __shfl(gv, k);
        t = fmaf(a, postW[k*64 + lane], t);
    }
    t = fmaxf(t, 0.f);
    float lg = (lane < NCLS) ? rob[lane] : 0.f;
    for (int k = 0; k < 64; k++){
        float a = __shfl(t, k);
        float w = (lane < NCLS) ? roW[k*NCLS + lane] : 0.f;
        lg = fmaf(a, w, lg);
    }
    float m = (lane < NCLS) ? lg : -INFINITY;
#pragma unroll
    for (int d = 1; d < 16; d <<= 1) m = fmaxf(m, __shfl_xor(m, d, 16));
    float ex = (lane < NCLS) ? expf(lg - m) : 0.f;
    float ssum = ex;
#pragma unroll
    for (int d = 1; d < 16; d <<= 1) ssum += __shfl_xor(ssum, d, 16);
    if (lane < NCLS) out[(size_t)gr*NCLS + lane] = lg - m - logf(ssum);
}

// ---------------- launch --------------------------------------------------
extern "C" void kernel_launch(void* const* d_in, const int* in_sizes, int n_in,
                              void* d_out, int out_size, void* d_ws, size_t ws_size,
                              hipStream_t stream) {
    const float* x      = (const float*)d_in[0];
    const float* s      = (const float*)d_in[1];
    const int*   ei     = (const int*)d_in[2];    // int32
    const int*   batch  = (const int*)d_in[3];    // int32
    const float* pre_W  = (const float*)d_in[4];
    const float* pre_b  = (const float*)d_in[5];
    const float* emb_W  = (const float*)d_in[6];
    const float* emb_b  = (const float*)d_in[7];
    const float* gin_W1 = (const float*)d_in[8];
    const float* gin_b1 = (const float*)d_in[9];
    const float* gin_W2 = (const float*)d_in[10];
    const float* gin_b2 = (const float*)d_in[11];
    const float* gcn_W  = (const float*)d_in[12];
    const float* gcn_b  = (const float*)d_in[13];
    const float* whp_W  = (const float*)d_in[14];
    const float* whp_b  = (const float*)d_in[15];
    const float* post_W = (const float*)d_in[16];
    const float* post_b = (const float*)d_in[17];
    const float* ro_W   = (const float*)d_in[18];
    const float* ro_b   = (const float*)d_in[19];
    float* out = (float*)d_out;

    char* w = (char*)d_ws;
    auto alloc = [&](size_t bytes) -> void* {
        void* p = (void*)w;
        w += (bytes + 255) & ~(size_t)255;
        return p;
    };
    int*   off   = (int*)  alloc((size_t)(NN+1) * 4);
    int*   csr   = (int*)  alloc((size_t)NE * 4);
    int*   ghist = (int*)  alloc((size_t)NCH * CB * 4);
    unsigned int* ebuf = (unsigned int*)alloc((size_t)NE * 4);
    float* dinv = (float*)alloc((size_t)NN * 4);
    float* xc   = (float*)alloc((size_t)NN * 128 * 4);
    unsigned short* xcb0 = (unsigned short*)alloc((size_t)NN * 128 * 2);
    unsigned short* xcb1 = (unsigned short*)alloc((size_t)NN * 128 * 2);
    float* hpre = (float*)alloc((size_t)NN * 128 * 4);
    float* hs   = (float*)alloc((size_t)NN * 64 * 4);
    unsigned short* hsb = (unsigned short*)alloc((size_t)NN * 64 * 2);
    float* xw   = (float*)alloc((size_t)NN * 64 * 4);
    float* gbuf = (float*)alloc((size_t)NG * 64 * 4);

    const int B  = 256;
    const int GL = (NN + 63) / 64;   // 782
    const int GA = (NN + 3) / 4;     // 12500

    // CSR build: 4 dispatches
    coarse_hist<<<NCH, 256, 0, stream>>>(ei + NE, ghist);
    coarse_scan<<<1,   256, 0, stream>>>(ghist);
    bin_lds    <<<NCH, 256, 0, stream>>>(ei, ei + NE, ghist, ebuf);
    scatter_all<<<CB,  256, 0, stream>>>(ebuf, ghist, off, dinv, csr, NN);

    // pre / emb -> xc = [x | s], bf16 shadow into xcb0
    linear64<FEATD><<<GL, B, 0, stream>>>(x, FEATD, pre_W, pre_b, xc,      128, xcb0,      128, NN, 0);
    linear64<SED>  <<<GL, B, 0, stream>>>(s, SED,   emb_W, emb_b, xc + 64, 128, xcb0 + 64, 128, NN, 0);

    for (int i = 0; i < NLAY; i++){
        unsigned short* cur = (i & 1) ? xcb1 : xcb0;
        unsigned short* nxt = (i & 1) ? xcb0 : xcb1;
        // hs = s_{i-1} @ gcn_W  (must precede merged_agg)
        linear64<64><<<GL, B, 0, stream>>>(xc + 64, 128, gcn_W + (size_t)i*64*64,
                                           nullptr, hs, 64, hsb, 64, NN, 0);
        merged_agg<<<GA, B, 0, stream>>>(xc, (const unsigned int*)cur, hs, hsb, dinv,
                                         off, csr, gcn_b + i*64, hpre, xc, nxt, NN);
        gin_mlp<<<GL, B, 0, stream>>>(hpre, gin_W1 + (size_t)i*128*64, gin_b1 + i*64,
                                      gin_W2 + (size_t)i*64*64, gin_b2 + i*64,
                                      xc, nxt, NN);
    }

    // whp -> xw
    linear64<128><<<GL, B, 0, stream>>>(xc, 128, whp_W, whp_b, xw, 64, nullptr, 0, NN, 0);

    // pool (atomic-free, block per graph) + head
    pool_kernel<<<NG, 64, 0, stream>>>(xw, batch, gbuf, NN);
    head_kernel<<<(NG + 3)/4, B, 0, stream>>>(gbuf, post_W, post_b, ro_W, ro_b, out, NG);
}

// Round 9
// 492.539 us; speedup vs baseline: 1.3719x; 1.2450x over previous
//
#include <hip/hip_runtime.h>
#include <math.h>

#define NN   50000
#define NE   800000
#define FEATD 128
#define SED  16
#define HD   64
#define NCLS 10
#define NLAY 3
#define NG   500

// two-level counting sort params
#define CHUNK 8192
#define NCH   ((NE + CHUNK - 1) / CHUNK)  // 98
#define CBSH  9
#define CB    ((NN + (1 << CBSH) - 1) >> CBSH)  // 98

typedef short  v8s __attribute__((ext_vector_type(8)));
typedef float  v4f __attribute__((ext_vector_type(4)));

// ---- bf16 helpers ---------------------------------------------------------
__device__ inline unsigned short f2bf(float f){
    unsigned int u = __float_as_uint(f);
    u += 0x7fffu + ((u >> 16) & 1u);
    return (unsigned short)(u >> 16);
}
__device__ inline float bf_lo(unsigned int p){ return __uint_as_float(p << 16); }
__device__ inline float bf_hi(unsigned int p){ return __uint_as_float(p & 0xffff0000u); }
__device__ inline float bf_up(unsigned short h){ return __uint_as_float((unsigned int)h << 16); }

// ---------------- weight prep: bf16 + transpose to WT[n][k] ----------------
// gcnWT[3][64*64] | W1T[3][64*128] | W2T[3][64*64] | whpWT[64*128]
__global__ __launch_bounds__(256) void wprep(
        const float* __restrict__ gcn_W, const float* __restrict__ gin_W1,
        const float* __restrict__ gin_W2, const float* __restrict__ whp_W,
        unsigned short* __restrict__ gcnWT, unsigned short* __restrict__ W1T,
        unsigned short* __restrict__ W2T,  unsigned short* __restrict__ whpWT)
{
    int i = blockIdx.x*256 + threadIdx.x;
    if (i < 12288){
        int li = i / 4096, r = i % 4096, nn = r / 64, kk = r % 64;
        gcnWT[li*4096 + nn*64 + kk] = f2bf(gcn_W[li*4096 + kk*64 + nn]);
    } else if (i < 36864){
        int j = i - 12288; int li = j / 8192, r = j % 8192, nn = r / 128, kk = r % 128;
        W1T[li*8192 + nn*128 + kk] = f2bf(gin_W1[li*8192 + kk*64 + nn]);
    } else if (i < 49152){
        int j = i - 36864; int li = j / 4096, r = j % 4096, nn = r / 64, kk = r % 64;
        W2T[li*4096 + nn*64 + kk] = f2bf(gin_W2[li*4096 + kk*64 + nn]);
    } else if (i < 57344){
        int j = i - 49152; int nn = j / 128, kk = j % 128;
        whpWT[nn*128 + kk] = f2bf(whp_W[kk*64 + nn]);
    }
}

// ---------------- two-level counting sort of edges by dst ------------------
__global__ __launch_bounds__(256) void coarse_hist(
        const int* __restrict__ dst, int* __restrict__ ghist){
    __shared__ int h[CB];
    for (int i = threadIdx.x; i < CB; i += 256) h[i] = 0;
    __syncthreads();
    int base = blockIdx.x * CHUNK;
    int end  = base + CHUNK; if (end > NE) end = NE;
    for (int i = base + threadIdx.x; i < end; i += 256)
        atomicAdd(&h[dst[i] >> CBSH], 1);
    __syncthreads();
    for (int i = threadIdx.x; i < CB; i += 256)
        ghist[(size_t)blockIdx.x * CB + i] = h[i];
}

__global__ __launch_bounds__(256) void coarse_scan(int* __restrict__ ghist){
    __shared__ int sh[256];
    int t = threadIdx.x;
    int run = 0;
    if (t < CB){
        for (int c = 0; c < NCH; c++){
            int v = ghist[(size_t)c*CB + t];
            ghist[(size_t)c*CB + t] = run;
            run += v;
        }
    }
    sh[t] = (t < CB) ? run : 0;
    __syncthreads();
    for (int d = 1; d < 256; d <<= 1){
        int u = (t >= d) ? sh[t-d] : 0;
        __syncthreads();
        sh[t] += u;
        __syncthreads();
    }
    int bstart = (t == 0) ? 0 : sh[t-1];
    if (t < CB){
        for (int c = 0; c < NCH; c++) ghist[(size_t)c*CB + t] += bstart;
    }
}

__global__ __launch_bounds__(256) void bin_lds(
        const int* __restrict__ src, const int* __restrict__ dst,
        const int* __restrict__ ghist, unsigned int* __restrict__ ebuf){
    __shared__ unsigned int lbuf[CHUNK];
    __shared__ unsigned int lbuf2[CHUNK];
    __shared__ int hist[CB], lstart[CB], cursor[CB], gbase[CB];
    __shared__ int sc[256];
    int t = threadIdx.x, c = blockIdx.x;
    for (int i = t; i < CB; i += 256){
        hist[i] = 0;
        gbase[i] = ghist[(size_t)c*CB + i];
    }
    __syncthreads();
    int base = c * CHUNK;
    int nend = base + CHUNK; if (nend > NE) nend = NE;
    nend -= base;
    for (int i = t; i < nend; i += 256){
        int d = dst[base + i];
        lbuf[i] = (unsigned int)src[base + i] | ((unsigned int)d << 16);
        atomicAdd(&hist[d >> CBSH], 1);
    }
    __syncthreads();
    sc[t] = (t < CB) ? hist[t] : 0;
    __syncthreads();
    for (int d = 1; d < 256; d <<= 1){
        int u = (t >= d) ? sc[t-d] : 0;
        __syncthreads();
        sc[t] += u;
        __syncthreads();
    }
    if (t < CB){
        lstart[t] = sc[t] - hist[t];
        cursor[t] = sc[t] - hist[t];
    }
    __syncthreads();
    for (int i = t; i < nend; i += 256){
        unsigned int u = lbuf[i];
        int b = (int)(u >> 16) >> CBSH;
        int p = atomicAdd(&cursor[b], 1);
        lbuf2[p] = u;
    }
    __syncthreads();
    for (int p = t; p < nend; p += 256){
        unsigned int u = lbuf2[p];
        int b = (int)(u >> 16) >> CBSH;
        ebuf[gbase[b] + (p - lstart[b])] = u;
    }
}

__global__ __launch_bounds__(256) void scatter_all(
        const unsigned int* __restrict__ ebuf, const int* __restrict__ ghist,
        int* __restrict__ off, float* __restrict__ dinv,
        int* __restrict__ csr, int n){
    __shared__ int lcnt[512];
    __shared__ int lex[512];
    __shared__ int sc[256];
    int t = threadIdx.x, b = blockIdx.x;
    int n0 = b << CBSH;
    int nn = n - n0; if (nn > 512) nn = 512;
    int lo = ghist[b];
    int hi = (b + 1 < CB) ? ghist[b + 1] : NE;
    lcnt[t] = 0; lcnt[t + 256] = 0;
    __syncthreads();
    for (int j = lo + t; j < hi; j += 256)
        atomicAdd(&lcnt[(int)(ebuf[j] >> 16) - n0], 1);
    __syncthreads();
    int c0 = lcnt[2*t], c1 = lcnt[2*t+1];
    sc[t] = c0 + c1;
    __syncthreads();
    for (int d = 1; d < 256; d <<= 1){
        int u = (t >= d) ? sc[t-d] : 0;
        __syncthreads();
        sc[t] += u;
        __syncthreads();
    }
    int bse = sc[t] - (c0 + c1);
    lex[2*t]   = bse;
    lex[2*t+1] = bse + c0;
    __syncthreads();
    for (int i = t; i < nn; i += 256){
        off[n0 + i]  = lo + lex[i];
        dinv[n0 + i] = rsqrtf((float)lcnt[i] + 1.0f);
    }
    if (b == 0 && t == 0) off[n] = NE;
    __syncthreads();
    for (int j = lo + t; j < hi; j += 256){
        unsigned int u = ebuf[j];
        int d = (int)(u >> 16) - n0;
        int p = atomicAdd(&lex[d], 1);
        csr[lo + p] = (int)(u & 0xffffu);
    }
}

// ---------------- fp32 linear (pre/emb only): out[n,64]=A@W ---------------
template<int K>
__global__ __launch_bounds__(256) void linear64(
        const float* __restrict__ A, int lda,
        const float* __restrict__ W,
        const float* __restrict__ bias,
        float* __restrict__ out, int ldo,
        unsigned short* __restrict__ outb, int ldob,
        int n, int act)
{
    constexpr int STR = K + 4;
    constexpr int NQ  = K / 4;
    __shared__ float at[64 * STR];
    int tid = threadIdx.x;
    int r0  = blockIdx.x * 64;
    for (int idx = tid; idx < 64 * NQ; idx += 256){
        int row = idx / NQ, kq = idx - row * NQ;
        float4 v = make_float4(0.f, 0.f, 0.f, 0.f);
        if (r0 + row < n) v = *(const float4*)(A + (size_t)(r0 + row) * lda + kq * 4);
        *(float4*)(&at[row * STR + kq * 4]) = v;
    }
    __syncthreads();
    int lane = tid & 63;
    int c0 = __builtin_amdgcn_readfirstlane((tid >> 6) << 4);
    int row = r0 + lane;
    if (row >= n) return;
    float acc[16];
#pragma unroll
    for (int j = 0; j < 16; j++) acc[j] = 0.f;
    const float* wp = W + c0;
    for (int k = 0; k < K; k += 4){
        float4 av = *(const float4*)(&at[lane * STR + k]);
        float aa[4] = {av.x, av.y, av.z, av.w};
#pragma unroll
        for (int kk = 0; kk < 4; kk++){
            const float* wr = wp + (k + kk) * 64;
#pragma unroll
            for (int j = 0; j < 16; j++)
                acc[j] = fmaf(aa[kk], wr[j], acc[j]);
        }
    }
    if (bias){
#pragma unroll
        for (int j = 0; j < 16; j++) acc[j] += bias[c0 + j];
    }
    if (act == 1){
#pragma unroll
        for (int j = 0; j < 16; j++) acc[j] = fmaxf(acc[j], 0.f);
    }
    float* o = out + (size_t)row * ldo + c0;
#pragma unroll
    for (int q = 0; q < 4; q++){
        float4 v;
        v.x = acc[q*4+0]; v.y = acc[q*4+1]; v.z = acc[q*4+2]; v.w = acc[q*4+3];
        *(float4*)(o + q*4) = v;
    }
    if (outb){
        unsigned int pk[8];
#pragma unroll
        for (int j = 0; j < 8; j++)
            pk[j] = (unsigned int)f2bf(acc[2*j]) | ((unsigned int)f2bf(acc[2*j+1]) << 16);
        unsigned short* ob = outb + (size_t)row * ldob + c0;
        uint4 u0; u0.x = pk[0]; u0.y = pk[1]; u0.z = pk[2]; u0.w = pk[3];
        uint4 u1; u1.x = pk[4]; u1.y = pk[5]; u1.z = pk[6]; u1.w = pk[7];
        *(uint4*)(ob)     = u0;
        *(uint4*)(ob + 8) = u1;
    }
}

// ---------------- MFMA bf16 linear: out[n,64] = A_bf16[n,K] @ W[K,64] -----
// WT is bf16 transposed [64][K]. Block=256: wave w -> rows b*64+16w..+15.
// A-frag: lane l holds A[m=l&15][k=(l>>4)*8+j]; B-frag from WT rows=outcol.
// D-frag: col=l&15, row=(l>>4)*4+reg  (HW-verified mapping).
template<int K>
__global__ __launch_bounds__(256) void mfma_linear(
        const unsigned short* __restrict__ A, int lda,
        const unsigned short* __restrict__ WT,
        const float* __restrict__ bias,
        float* __restrict__ out, int ldo,
        unsigned short* __restrict__ outb, int ldob,
        int n, int act)
{
    constexpr int NKO = K / 32;
    int tid = threadIdx.x;
    int w = tid >> 6, l = tid & 63;
    int m = l & 15, q = l >> 4;
    int rbase = blockIdx.x * 64 + w * 16;
    int arow  = rbase + m;
    bool valid = arow < n;
    v8s a[NKO];
#pragma unroll
    for (int ko = 0; ko < NKO; ko++){
        v8s z = {0,0,0,0,0,0,0,0};
        a[ko] = valid ? *(const v8s*)(A + (size_t)arow * lda + ko*32 + q*8) : z;
    }
#pragma unroll
    for (int ct = 0; ct < 4; ct++){
        v4f acc = {0.f, 0.f, 0.f, 0.f};
#pragma unroll
        for (int ko = 0; ko < NKO; ko++){
            v8s b = *(const v8s*)(WT + (size_t)(ct*16 + m) * K + ko*32 + q*8);
            acc = __builtin_amdgcn_mfma_f32_16x16x32_bf16(a[ko], b, acc, 0, 0, 0);
        }
        int col = ct*16 + m;
        float bv = bias ? bias[col] : 0.f;
#pragma unroll
        for (int r = 0; r < 4; r++){
            int orow = rbase + q*4 + r;
            float v = acc[r] + bv;
            if (act == 1) v = fmaxf(v, 0.f);
            if (orow < n){
                out[(size_t)orow * ldo + col] = v;
                if (outb) outb[(size_t)orow * ldob + col] = f2bf(v);
            }
        }
    }
}

// ---------------- MFMA fused GIN MLP -------------------------------------
// x_new = relu(relu(hpreb@W1+b1)@W2+b2); h round-trips through LDS (bf16).
__global__ __launch_bounds__(256) void ginmlp_mfma(
        const unsigned short* __restrict__ hpreb,   // [n,128] bf16
        const unsigned short* __restrict__ W1T,     // [64][128]
        const float* __restrict__ b1,
        const unsigned short* __restrict__ W2T,     // [64][64]
        const float* __restrict__ b2,
        float* __restrict__ xc, unsigned short* __restrict__ xcb_nxt, int n)
{
    __shared__ unsigned short hsh[64 * 72];
    int tid = threadIdx.x;
    int w = tid >> 6, l = tid & 63;
    int m = l & 15, q = l >> 4;
    int rbase = blockIdx.x * 64 + w * 16;
    int arow  = rbase + m;
    bool valid = arow < n;
    v8s a[4];
#pragma unroll
    for (int ko = 0; ko < 4; ko++){
        v8s z = {0,0,0,0,0,0,0,0};
        a[ko] = valid ? *(const v8s*)(hpreb + (size_t)arow * 128 + ko*32 + q*8) : z;
    }
#pragma unroll
    for (int ct = 0; ct < 4; ct++){
        v4f acc = {0.f, 0.f, 0.f, 0.f};
#pragma unroll
        for (int ko = 0; ko < 4; ko++){
            v8s b = *(const v8s*)(W1T + (size_t)(ct*16 + m) * 128 + ko*32 + q*8);
            acc = __builtin_amdgcn_mfma_f32_16x16x32_bf16(a[ko], b, acc, 0, 0, 0);
        }
        int col = ct*16 + m;
        float bv = b1[col];
#pragma unroll
        for (int r = 0; r < 4; r++){
            int lrow = w*16 + q*4 + r;
            hsh[lrow*72 + col] = f2bf(fmaxf(acc[r] + bv, 0.f));
        }
    }
    __syncthreads();
    v8s a2[2];
#pragma unroll
    for (int ko = 0; ko < 2; ko++)
        a2[ko] = *(const v8s*)(&hsh[(w*16 + m)*72 + ko*32 + q*8]);
#pragma unroll
    for (int ct = 0; ct < 4; ct++){
        v4f acc = {0.f, 0.f, 0.f, 0.f};
#pragma unroll
        for (int ko = 0; ko < 2; ko++){
            v8s b = *(const v8s*)(W2T + (size_t)(ct*16 + m) * 64 + ko*32 + q*8);
            acc = __builtin_amdgcn_mfma_f32_16x16x32_bf16(a2[ko], b, acc, 0, 0, 0);
        }
        int col = ct*16 + m;
        float bv = b2[col];
#pragma unroll
        for (int r = 0; r < 4; r++){
            int orow = rbase + q*4 + r;
            float v = fmaxf(acc[r] + bv, 0.f);
            if (orow < n){
                xc[(size_t)orow * 128 + col] = v;
                xcb_nxt[(size_t)orow * 128 + col] = f2bf(v);
            }
        }
    }
}

// ---------------- merged GIN + GCN aggregation (one csr walk) --------------
// gin: hpreb[n,128]bf16 = xc[n] + sum xcb_cur[src]
// gcn: s_new = tanh(di*sum(dinv[s]*hsb[s]) + hs[n]*di^2 + bias) -> xc, xcb_nxt
__global__ __launch_bounds__(256) void merged_agg(
        const float* __restrict__ xc, const unsigned int* __restrict__ xcb_cur,
        const float* __restrict__ hs, const unsigned short* __restrict__ hsb,
        const float* __restrict__ dinv,
        const int* __restrict__ off, const int* __restrict__ csr,
        const float* __restrict__ bias,
        unsigned int* __restrict__ hpreb, float* __restrict__ xc_out,
        unsigned short* __restrict__ xcb_nxt, int n)
{
    int node = __builtin_amdgcn_readfirstlane(blockIdx.x * 4 + (threadIdx.x >> 6));
    int lane = threadIdx.x & 63;
    if (node >= n) return;
    int beg = off[node], end = off[node+1];
    float2 self2 = *(const float2*)(xc + (size_t)node*128 + 2*lane);
    float a0 = self2.x, a1 = self2.y;
    float ag = 0.f;
    int e = beg;
    for (; e + 4 <= end; e += 4){
        int s0 = csr[e], s1 = csr[e+1], s2 = csr[e+2], s3 = csr[e+3];
        unsigned int p0 = xcb_cur[(size_t)s0*64 + lane];
        unsigned int p1 = xcb_cur[(size_t)s1*64 + lane];
        unsigned int p2 = xcb_cur[(size_t)s2*64 + lane];
        unsigned int p3 = xcb_cur[(size_t)s3*64 + lane];
        float h0 = bf_up(hsb[(size_t)s0*64 + lane]);
        float h1 = bf_up(hsb[(size_t)s1*64 + lane]);
        float h2 = bf_up(hsb[(size_t)s2*64 + lane]);
        float h3 = bf_up(hsb[(size_t)s3*64 + lane]);
        a0 += (bf_lo(p0) + bf_lo(p1)) + (bf_lo(p2) + bf_lo(p3));
        a1 += (bf_hi(p0) + bf_hi(p1)) + (bf_hi(p2) + bf_hi(p3));
        ag += (dinv[s0]*h0 + dinv[s1]*h1) + (dinv[s2]*h2 + dinv[s3]*h3);
    }
    for (; e < end; e++){
        int s0 = csr[e];
        unsigned int p0 = xcb_cur[(size_t)s0*64 + lane];
        a0 += bf_lo(p0);
        a1 += bf_hi(p0);
        ag += dinv[s0] * bf_up(hsb[(size_t)s0*64 + lane]);
    }
    hpreb[(size_t)node*64 + lane] =
        (unsigned int)f2bf(a0) | ((unsigned int)f2bf(a1) << 16);
    float di   = dinv[node];
    float self = hs[(size_t)node*64 + lane];
    float v = tanhf(di*ag + self*di*di + bias[lane]);
    xc_out [(size_t)node*128 + 64 + lane] = v;
    xcb_nxt[(size_t)node*128 + 64 + lane] = f2bf(v);
}

// ---------------- global_add_pool: block per graph, binary search ----------
__global__ __launch_bounds__(64) void pool_kernel(
        const float* __restrict__ xw, const int* __restrict__ batch,
        float* __restrict__ g, int n)
{
    int gr = blockIdx.x;
    int lane = threadIdx.x;
    int lo = 0, hi = n;
    while (lo < hi){ int m = (lo + hi) >> 1; if (batch[m] < gr) lo = m + 1; else hi = m; }
    int r0 = lo;
    hi = n;
    while (lo < hi){ int m = (lo + hi) >> 1; if (batch[m] < gr + 1) lo = m + 1; else hi = m; }
    int r1 = lo;
    float acc = 0.f;
    for (int r = r0; r < r1; r++) acc += xw[(size_t)r*64 + lane];
    g[(size_t)gr*64 + lane] = acc;
}

// ---------------- head ----------------------------------------------------
__global__ __launch_bounds__(256) void head_kernel(
        const float* __restrict__ g, const float* __restrict__ postW,
        const float* __restrict__ postb, const float* __restrict__ roW,
        const float* __restrict__ rob, float* __restrict__ out, int ngraph)
{
    int gr = __builtin_amdgcn_readfirstlane(blockIdx.x * 4 + (threadIdx.x >> 6));
    int lane = threadIdx.x & 63;
    if (gr >= ngraph) return;
    float gv = g[(size_t)gr*64 + lane];
    float t = postb[lane];
    for (int k = 0; k < 64; k++){
        float a = __shfl(gv, k);
        t = fmaf(a, postW[k*64 + lane], t);
    }
    t = fmaxf(t, 0.f);
    float lg = (lane < NCLS) ? rob[lane] : 0.f;
    for (int k = 0; k < 64; k++){
        float a = __shfl(t, k);
        float w = (lane < NCLS) ? roW[k*NCLS + lane] : 0.f;
        lg = fmaf(a, w, lg);
    }
    float m = (lane < NCLS) ? lg : -INFINITY;
#pragma unroll
    for (int d = 1; d < 16; d <<= 1) m = fmaxf(m, __shfl_xor(m, d, 16));
    float ex = (lane < NCLS) ? expf(lg - m) : 0.f;
    float ssum = ex;
#pragma unroll
    for (int d = 1; d < 16; d <<= 1) ssum += __shfl_xor(ssum, d, 16);
    if (lane < NCLS) out[(size_t)gr*NCLS + lane] = lg - m - logf(ssum);
}

// ---------------- launch --------------------------------------------------
extern "C" void kernel_launch(void* const* d_in, const int* in_sizes, int n_in,
                              void* d_out, int out_size, void* d_ws, size_t ws_size,
                              hipStream_t stream) {
    const float* x      = (const float*)d_in[0];
    const float* s      = (const float*)d_in[1];
    const int*   ei     = (const int*)d_in[2];    // int32
    const int*   batch  = (const int*)d_in[3];    // int32
    const float* pre_W  = (const float*)d_in[4];
    const float* pre_b  = (const float*)d_in[5];
    const float* emb_W  = (const float*)d_in[6];
    const float* emb_b  = (const float*)d_in[7];
    const float* gin_W1 = (const float*)d_in[8];
    const float* gin_b1 = (const float*)d_in[9];
    const float* gin_W2 = (const float*)d_in[10];
    const float* gin_b2 = (const float*)d_in[11];
    const float* gcn_W  = (const float*)d_in[12];
    const float* gcn_b  = (const float*)d_in[13];
    const float* whp_W  = (const float*)d_in[14];
    const float* whp_b  = (const float*)d_in[15];
    const float* post_W = (const float*)d_in[16];
    const float* post_b = (const float*)d_in[17];
    const float* ro_W   = (const float*)d_in[18];
    const float* ro_b   = (const float*)d_in[19];
    float* out = (float*)d_out;

    char* w = (char*)d_ws;
    auto alloc = [&](size_t bytes) -> void* {
        void* p = (void*)w;
        w += (bytes + 255) & ~(size_t)255;
        return p;
    };
    int*   off   = (int*)  alloc((size_t)(NN+1) * 4);
    int*   csr   = (int*)  alloc((size_t)NE * 4);
    int*   ghist = (int*)  alloc((size_t)NCH * CB * 4);
    unsigned int* ebuf = (unsigned int*)alloc((size_t)NE * 4);
    float* dinv = (float*)alloc((size_t)NN * 4);
    float* xc   = (float*)alloc((size_t)NN * 128 * 4);
    unsigned short* xcb0 = (unsigned short*)alloc((size_t)NN * 128 * 2);
    unsigned short* xcb1 = (unsigned short*)alloc((size_t)NN * 128 * 2);
    unsigned int*   hpreb = (unsigned int*)alloc((size_t)NN * 64 * 4);  // bf16 [n,128]
    float* hs   = (float*)alloc((size_t)NN * 64 * 4);
    unsigned short* hsb = (unsigned short*)alloc((size_t)NN * 64 * 2);
    float* xw   = (float*)alloc((size_t)NN * 64 * 4);
    float* gbuf = (float*)alloc((size_t)NG * 64 * 4);
    unsigned short* gcnWT = (unsigned short*)alloc((size_t)3 * 4096 * 2);
    unsigned short* W1T   = (unsigned short*)alloc((size_t)3 * 8192 * 2);
    unsigned short* W2T   = (unsigned short*)alloc((size_t)3 * 4096 * 2);
    unsigned short* whpWT = (unsigned short*)alloc((size_t)8192 * 2);

    const int B  = 256;
    const int GL = (NN + 63) / 64;   // 782
    const int GA = (NN + 3) / 4;     // 12500

    // weight prep (bf16 transpose) + CSR build
    wprep<<<224, 256, 0, stream>>>(gcn_W, gin_W1, gin_W2, whp_W, gcnWT, W1T, W2T, whpWT);
    coarse_hist<<<NCH, 256, 0, stream>>>(ei + NE, ghist);
    coarse_scan<<<1,   256, 0, stream>>>(ghist);
    bin_lds    <<<NCH, 256, 0, stream>>>(ei, ei + NE, ghist, ebuf);
    scatter_all<<<CB,  256, 0, stream>>>(ebuf, ghist, off, dinv, csr, NN);

    // pre / emb -> xc = [x | s], bf16 shadow into xcb0 (fp32 path, one-shot)
    linear64<FEATD><<<GL, B, 0, stream>>>(x, FEATD, pre_W, pre_b, xc,      128, xcb0,      128, NN, 0);
    linear64<SED>  <<<GL, B, 0, stream>>>(s, SED,   emb_W, emb_b, xc + 64, 128, xcb0 + 64, 128, NN, 0);

    for (int i = 0; i < NLAY; i++){
        unsigned short* cur = (i & 1) ? xcb1 : xcb0;
        unsigned short* nxt = (i & 1) ? xcb0 : xcb1;
        // hs = s @ gcn_W via MFMA (input: bf16 s = right half of cur)
        mfma_linear<64><<<GL, B, 0, stream>>>(cur + 64, 128, gcnWT + (size_t)i*4096,
                                              nullptr, hs, 64, hsb, 64, NN, 0);
        merged_agg<<<GA, B, 0, stream>>>(xc, (const unsigned int*)cur, hs, hsb, dinv,
                                         off, csr, gcn_b + i*64, hpreb, xc, nxt, NN);
        ginmlp_mfma<<<GL, B, 0, stream>>>((const unsigned short*)hpreb,
                                          W1T + (size_t)i*8192, gin_b1 + i*64,
                                          W2T + (size_t)i*4096, gin_b2 + i*64,
                                          xc, nxt, NN);
    }

    // whp via MFMA (input: final full bf16 state = xcb1 after 3 layers)
    mfma_linear<128><<<GL, B, 0, stream>>>(xcb1, 128, whpWT, whp_b,
                                           xw, 64, nullptr, 0, NN, 0);

    // pool + head
    pool_kernel<<<NG, 64, 0, stream>>>(xw, batch, gbuf, NN);
    head_kernel<<<(NG + 3)/4, B, 0, stream>>>(gbuf, post_W, post_b, ro_W, ro_b, out, NG);
}

// Round 10
// 427.581 us; speedup vs baseline: 1.5803x; 1.1519x over previous
//
#include <hip/hip_runtime.h>
#include <math.h>

#define NN   50000
#define NE   800000
#define FEATD 128
#define SED  16
#define HD   64
#define NCLS 10
#define NLAY 3
#define NG   500

// two-level counting sort params
#define CHUNK 8192
#define NCH   ((NE + CHUNK - 1) / CHUNK)  // 98
#define CBSH  9
#define CB    ((NN + (1 << CBSH) - 1) >> CBSH)  // 98

typedef short  v8s __attribute__((ext_vector_type(8)));
typedef float  v4f __attribute__((ext_vector_type(4)));

// ---- bf16 helpers ---------------------------------------------------------
__device__ inline unsigned short f2bf(float f){
    unsigned int u = __float_as_uint(f);
    u += 0x7fffu + ((u >> 16) & 1u);
    return (unsigned short)(u >> 16);
}
__device__ inline unsigned int pack2bf(float a, float b){
    return (unsigned int)f2bf(a) | ((unsigned int)f2bf(b) << 16);
}
__device__ inline float bf_lo(unsigned int p){ return __uint_as_float(p << 16); }
__device__ inline float bf_hi(unsigned int p){ return __uint_as_float(p & 0xffff0000u); }

// ---------------- weight prep: bf16 + transpose to WT[n][k] ----------------
__global__ __launch_bounds__(256) void wprep(
        const float* __restrict__ gcn_W, const float* __restrict__ gin_W1,
        const float* __restrict__ gin_W2, const float* __restrict__ whp_W,
        unsigned short* __restrict__ gcnWT, unsigned short* __restrict__ W1T,
        unsigned short* __restrict__ W2T,  unsigned short* __restrict__ whpWT)
{
    int i = blockIdx.x*256 + threadIdx.x;
    if (i < 12288){
        int li = i / 4096, r = i % 4096, nn = r / 64, kk = r % 64;
        gcnWT[li*4096 + nn*64 + kk] = f2bf(gcn_W[li*4096 + kk*64 + nn]);
    } else if (i < 36864){
        int j = i - 12288; int li = j / 8192, r = j % 8192, nn = r / 128, kk = r % 128;
        W1T[li*8192 + nn*128 + kk] = f2bf(gin_W1[li*8192 + kk*64 + nn]);
    } else if (i < 49152){
        int j = i - 36864; int li = j / 4096, r = j % 4096, nn = r / 64, kk = r % 64;
        W2T[li*4096 + nn*64 + kk] = f2bf(gin_W2[li*4096 + kk*64 + nn]);
    } else if (i < 57344){
        int j = i - 49152; int nn = j / 128, kk = j % 128;
        whpWT[nn*128 + kk] = f2bf(whp_W[kk*64 + nn]);
    }
}

// ---------------- two-level counting sort of edges by dst ------------------
__global__ __launch_bounds__(256) void coarse_hist(
        const int* __restrict__ dst, int* __restrict__ ghist){
    __shared__ int h[CB];
    for (int i = threadIdx.x; i < CB; i += 256) h[i] = 0;
    __syncthreads();
    int base = blockIdx.x * CHUNK;
    int end  = base + CHUNK; if (end > NE) end = NE;
    for (int i = base + threadIdx.x; i < end; i += 256)
        atomicAdd(&h[dst[i] >> CBSH], 1);
    __syncthreads();
    for (int i = threadIdx.x; i < CB; i += 256)
        ghist[(size_t)blockIdx.x * CB + i] = h[i];
}

__global__ __launch_bounds__(256) void coarse_scan(int* __restrict__ ghist){
    __shared__ int sh[256];
    int t = threadIdx.x;
    int run = 0;
    if (t < CB){
        for (int c = 0; c < NCH; c++){
            int v = ghist[(size_t)c*CB + t];
            ghist[(size_t)c*CB + t] = run;
            run += v;
        }
    }
    sh[t] = (t < CB) ? run : 0;
    __syncthreads();
    for (int d = 1; d < 256; d <<= 1){
        int u = (t >= d) ? sh[t-d] : 0;
        __syncthreads();
        sh[t] += u;
        __syncthreads();
    }
    int bstart = (t == 0) ? 0 : sh[t-1];
    if (t < CB){
        for (int c = 0; c < NCH; c++) ghist[(size_t)c*CB + t] += bstart;
    }
}

__global__ __launch_bounds__(256) void bin_lds(
        const int* __restrict__ src, const int* __restrict__ dst,
        const int* __restrict__ ghist, unsigned int* __restrict__ ebuf){
    __shared__ unsigned int lbuf[CHUNK];
    __shared__ unsigned int lbuf2[CHUNK];
    __shared__ int hist[CB], lstart[CB], cursor[CB], gbase[CB];
    __shared__ int sc[256];
    int t = threadIdx.x, c = blockIdx.x;
    for (int i = t; i < CB; i += 256){
        hist[i] = 0;
        gbase[i] = ghist[(size_t)c*CB + i];
    }
    __syncthreads();
    int base = c * CHUNK;
    int nend = base + CHUNK; if (nend > NE) nend = NE;
    nend -= base;
    for (int i = t; i < nend; i += 256){
        int d = dst[base + i];
        lbuf[i] = (unsigned int)src[base + i] | ((unsigned int)d << 16);
        atomicAdd(&hist[d >> CBSH], 1);
    }
    __syncthreads();
    sc[t] = (t < CB) ? hist[t] : 0;
    __syncthreads();
    for (int d = 1; d < 256; d <<= 1){
        int u = (t >= d) ? sc[t-d] : 0;
        __syncthreads();
        sc[t] += u;
        __syncthreads();
    }
    if (t < CB){
        lstart[t] = sc[t] - hist[t];
        cursor[t] = sc[t] - hist[t];
    }
    __syncthreads();
    for (int i = t; i < nend; i += 256){
        unsigned int u = lbuf[i];
        int b = (int)(u >> 16) >> CBSH;
        int p = atomicAdd(&cursor[b], 1);
        lbuf2[p] = u;
    }
    __syncthreads();
    for (int p = t; p < nend; p += 256){
        unsigned int u = lbuf2[p];
        int b = (int)(u >> 16) >> CBSH;
        ebuf[gbase[b] + (p - lstart[b])] = u;
    }
}

__global__ __launch_bounds__(256) void scatter_all(
        const unsigned int* __restrict__ ebuf, const int* __restrict__ ghist,
        int* __restrict__ off, float* __restrict__ dinv,
        int* __restrict__ csr, int n){
    __shared__ int lcnt[512];
    __shared__ int lex[512];
    __shared__ int sc[256];
    int t = threadIdx.x, b = blockIdx.x;
    int n0 = b << CBSH;
    int nn = n - n0; if (nn > 512) nn = 512;
    int lo = ghist[b];
    int hi = (b + 1 < CB) ? ghist[b + 1] : NE;
    lcnt[t] = 0; lcnt[t + 256] = 0;
    __syncthreads();
    for (int j = lo + t; j < hi; j += 256)
        atomicAdd(&lcnt[(int)(ebuf[j] >> 16) - n0], 1);
    __syncthreads();
    int c0 = lcnt[2*t], c1 = lcnt[2*t+1];
    sc[t] = c0 + c1;
    __syncthreads();
    for (int d = 1; d < 256; d <<= 1){
        int u = (t >= d) ? sc[t-d] : 0;
        __syncthreads();
        sc[t] += u;
        __syncthreads();
    }
    int bse = sc[t] - (c0 + c1);
    lex[2*t]   = bse;
    lex[2*t+1] = bse + c0;
    __syncthreads();
    for (int i = t; i < nn; i += 256){
        off[n0 + i]  = lo + lex[i];
        dinv[n0 + i] = rsqrtf((float)lcnt[i] + 1.0f);
    }
    if (b == 0 && t == 0) off[n] = NE;
    __syncthreads();
    for (int j = lo + t; j < hi; j += 256){
        unsigned int u = ebuf[j];
        int d = (int)(u >> 16) - n0;
        int p = atomicAdd(&lex[d], 1);
        csr[lo + p] = (int)(u & 0xffffu);
    }
}

// ---------------- fp32 linear (pre/emb only): outb = bf16(A@W + b) --------
template<int K>
__global__ __launch_bounds__(256) void linear64(
        const float* __restrict__ A, int lda,
        const float* __restrict__ W,
        const float* __restrict__ bias,
        unsigned short* __restrict__ outb, int ldob, int n)
{
    constexpr int STR = K + 4;
    constexpr int NQ  = K / 4;
    __shared__ float at[64 * STR];
    int tid = threadIdx.x;
    int r0  = blockIdx.x * 64;
    for (int idx = tid; idx < 64 * NQ; idx += 256){
        int row = idx / NQ, kq = idx - row * NQ;
        float4 v = make_float4(0.f, 0.f, 0.f, 0.f);
        if (r0 + row < n) v = *(const float4*)(A + (size_t)(r0 + row) * lda + kq * 4);
        *(float4*)(&at[row * STR + kq * 4]) = v;
    }
    __syncthreads();
    int lane = tid & 63;
    int c0 = __builtin_amdgcn_readfirstlane((tid >> 6) << 4);
    int row = r0 + lane;
    if (row >= n) return;
    float acc[16];
#pragma unroll
    for (int j = 0; j < 16; j++) acc[j] = 0.f;
    const float* wp = W + c0;
    for (int k = 0; k < K; k += 4){
        float4 av = *(const float4*)(&at[lane * STR + k]);
        float aa[4] = {av.x, av.y, av.z, av.w};
#pragma unroll
        for (int kk = 0; kk < 4; kk++){
            const float* wr = wp + (k + kk) * 64;
#pragma unroll
            for (int j = 0; j < 16; j++)
                acc[j] = fmaf(aa[kk], wr[j], acc[j]);
        }
    }
#pragma unroll
    for (int j = 0; j < 16; j++) acc[j] += bias[c0 + j];
    unsigned int pk[8];
#pragma unroll
    for (int j = 0; j < 8; j++) pk[j] = pack2bf(acc[2*j], acc[2*j+1]);
    unsigned short* ob = outb + (size_t)row * ldob + c0;
    uint4 u0; u0.x = pk[0]; u0.y = pk[1]; u0.z = pk[2]; u0.w = pk[3];
    uint4 u1; u1.x = pk[4]; u1.y = pk[5]; u1.z = pk[6]; u1.w = pk[7];
    *(uint4*)(ob)     = u0;
    *(uint4*)(ob + 8) = u1;
}

// ---------------- MFMA bf16 linear (whp): out fp32 -----------------------
template<int K>
__global__ __launch_bounds__(256) void mfma_linear(
        const unsigned short* __restrict__ A, int lda,
        const unsigned short* __restrict__ WT,
        const float* __restrict__ bias,
        float* __restrict__ out, int ldo, int n)
{
    constexpr int NKO = K / 32;
    int tid = threadIdx.x;
    int w = tid >> 6, l = tid & 63;
    int m = l & 15, q = l >> 4;
    int rbase = blockIdx.x * 64 + w * 16;
    int arow  = rbase + m;
    bool valid = arow < n;
    v8s a[NKO];
#pragma unroll
    for (int ko = 0; ko < NKO; ko++){
        v8s z = {0,0,0,0,0,0,0,0};
        a[ko] = valid ? *(const v8s*)(A + (size_t)arow * lda + ko*32 + q*8) : z;
    }
#pragma unroll
    for (int ct = 0; ct < 4; ct++){
        v4f acc = {0.f, 0.f, 0.f, 0.f};
#pragma unroll
        for (int ko = 0; ko < NKO; ko++){
            v8s b = *(const v8s*)(WT + (size_t)(ct*16 + m) * K + ko*32 + q*8);
            acc = __builtin_amdgcn_mfma_f32_16x16x32_bf16(a[ko], b, acc, 0, 0, 0);
        }
        int col = ct*16 + m;
        float bv = bias ? bias[col] : 0.f;
#pragma unroll
        for (int r = 0; r < 4; r++){
            int orow = rbase + q*4 + r;
            if (orow < n) out[(size_t)orow * ldo + col] = acc[r] + bv;
        }
    }
}

// ---------------- merged aggregation: ONE gather feeds GIN + GCN -----------
// hpreb[n,128]bf16 = xcb[n] + sum xcb[src]
// ub[n,64]bf16     = dinv[n]*sum(dinv[s]*s_prev[s]) + dinv[n]^2*s_prev[n]
//   (s_prev = right half of xcb; GCN weight applied later by linearity)
__global__ __launch_bounds__(256) void merged_agg(
        const unsigned int* __restrict__ xcb_cur,
        const float* __restrict__ dinv,
        const int* __restrict__ off, const int* __restrict__ csr,
        unsigned int* __restrict__ hpreb, unsigned int* __restrict__ ub, int n)
{
    int node = __builtin_amdgcn_readfirstlane(blockIdx.x * 4 + (threadIdx.x >> 6));
    int lane = threadIdx.x & 63;
    if (node >= n) return;
    int beg = off[node], end = off[node+1];
    unsigned int ps = xcb_cur[(size_t)node*64 + lane];
    float s0f = bf_lo(ps), s1f = bf_hi(ps);
    float a0 = s0f, a1 = s1f;
    float g0 = 0.f, g1 = 0.f;
    int e = beg;
    for (; e + 4 <= end; e += 4){
        int s0 = csr[e], s1 = csr[e+1], s2 = csr[e+2], s3 = csr[e+3];
        unsigned int p0 = xcb_cur[(size_t)s0*64 + lane];
        unsigned int p1 = xcb_cur[(size_t)s1*64 + lane];
        unsigned int p2 = xcb_cur[(size_t)s2*64 + lane];
        unsigned int p3 = xcb_cur[(size_t)s3*64 + lane];
        float d0 = dinv[s0], d1 = dinv[s1], d2 = dinv[s2], d3 = dinv[s3];
        float v0 = bf_lo(p0), v1 = bf_lo(p1), v2 = bf_lo(p2), v3 = bf_lo(p3);
        float w0 = bf_hi(p0), w1 = bf_hi(p1), w2 = bf_hi(p2), w3 = bf_hi(p3);
        a0 += (v0 + v1) + (v2 + v3);
        a1 += (w0 + w1) + (w2 + w3);
        g0 = fmaf(d0, v0, fmaf(d1, v1, fmaf(d2, v2, fmaf(d3, v3, g0))));
        g1 = fmaf(d0, w0, fmaf(d1, w1, fmaf(d2, w2, fmaf(d3, w3, g1))));
    }
    for (; e < end; e++){
        int s0 = csr[e];
        unsigned int p0 = xcb_cur[(size_t)s0*64 + lane];
        float d0 = dinv[s0];
        float v0 = bf_lo(p0), w0 = bf_hi(p0);
        a0 += v0; a1 += w0;
        g0 = fmaf(d0, v0, g0);
        g1 = fmaf(d0, w0, g1);
    }
    hpreb[(size_t)node*64 + lane] = pack2bf(a0, a1);
    if (lane >= 32){   // lanes 32..63 hold s_prev cols (64..127)
        float di = dinv[node];
        float u0 = fmaf(di, g0, di*di*s0f);
        float u1 = fmaf(di, g1, di*di*s1f);
        ub[(size_t)node*32 + (lane - 32)] = pack2bf(u0, u1);
    }
}

// ---------------- fused per-layer MFMA: GIN MLP + GCN linear ---------------
// xcb_nxt left  = relu(relu(hpreb@W1+b1)@W2+b2)
// xcb_nxt right = tanh(ub@gcnW + gcn_b)
__global__ __launch_bounds__(256) void ginmlp3(
        const unsigned short* __restrict__ hpreb,   // [n,128] bf16
        const unsigned short* __restrict__ ub,      // [n,64]  bf16
        const unsigned short* __restrict__ W1T,     // [64][128]
        const float* __restrict__ b1,
        const unsigned short* __restrict__ W2T,     // [64][64]
        const float* __restrict__ b2,
        const unsigned short* __restrict__ gcnWT,   // [64][64]
        const float* __restrict__ gcnb,
        unsigned short* __restrict__ xcb_nxt, int n)
{
    __shared__ unsigned short hsh[64 * 72];
    int tid = threadIdx.x;
    int w = tid >> 6, l = tid & 63;
    int m = l & 15, q = l >> 4;
    int rbase = blockIdx.x * 64 + w * 16;
    int arow  = rbase + m;
    bool valid = arow < n;
    v8s z = {0,0,0,0,0,0,0,0};
    // GEMM3: s_new = tanh(ub @ gcnW + b)
    {
        v8s a3[2];
#pragma unroll
        for (int ko = 0; ko < 2; ko++)
            a3[ko] = valid ? *(const v8s*)(ub + (size_t)arow * 64 + ko*32 + q*8) : z;
#pragma unroll
        for (int ct = 0; ct < 4; ct++){
            v4f acc = {0.f, 0.f, 0.f, 0.f};
#pragma unroll
            for (int ko = 0; ko < 2; ko++){
                v8s b = *(const v8s*)(gcnWT + (size_t)(ct*16 + m) * 64 + ko*32 + q*8);
                acc = __builtin_amdgcn_mfma_f32_16x16x32_bf16(a3[ko], b, acc, 0, 0, 0);
            }
            int col = ct*16 + m;
            float bv = gcnb[col];
#pragma unroll
            for (int r = 0; r < 4; r++){
                int orow = rbase + q*4 + r;
                if (orow < n)
                    xcb_nxt[(size_t)orow * 128 + 64 + col] = f2bf(tanhf(acc[r] + bv));
            }
        }
    }
    // GEMM1: h = relu(hpreb @ W1 + b1) -> LDS (bf16)
    {
        v8s a[4];
#pragma unroll
        for (int ko = 0; ko < 4; ko++)
            a[ko] = valid ? *(const v8s*)(hpreb + (size_t)arow * 128 + ko*32 + q*8) : z;
#pragma unroll
        for (int ct = 0; ct < 4; ct++){
            v4f acc = {0.f, 0.f, 0.f, 0.f};
#pragma unroll
            for (int ko = 0; ko < 4; ko++){
                v8s b = *(const v8s*)(W1T + (size_t)(ct*16 + m) * 128 + ko*32 + q*8);
                acc = __builtin_amdgcn_mfma_f32_16x16x32_bf16(a[ko], b, acc, 0, 0, 0);
            }
            int col = ct*16 + m;
            float bv = b1[col];
#pragma unroll
            for (int r = 0; r < 4; r++){
                int lrow = w*16 + q*4 + r;
                hsh[lrow*72 + col] = f2bf(fmaxf(acc[r] + bv, 0.f));
            }
        }
    }
    __syncthreads();
    // GEMM2: x_new = relu(h @ W2 + b2)
    v8s a2[2];
#pragma unroll
    for (int ko = 0; ko < 2; ko++)
        a2[ko] = *(const v8s*)(&hsh[(w*16 + m)*72 + ko*32 + q*8]);
#pragma unroll
    for (int ct = 0; ct < 4; ct++){
        v4f acc = {0.f, 0.f, 0.f, 0.f};
#pragma unroll
        for (int ko = 0; ko < 2; ko++){
            v8s b = *(const v8s*)(W2T + (size_t)(ct*16 + m) * 64 + ko*32 + q*8);
            acc = __builtin_amdgcn_mfma_f32_16x16x32_bf16(a2[ko], b, acc, 0, 0, 0);
        }
        int col = ct*16 + m;
        float bv = b2[col];
#pragma unroll
        for (int r = 0; r < 4; r++){
            int orow = rbase + q*4 + r;
            if (orow < n)
                xcb_nxt[(size_t)orow * 128 + col] = f2bf(fmaxf(acc[r] + bv, 0.f));
        }
    }
}

// ---------------- global_add_pool: block per graph, binary search ----------
__global__ __launch_bounds__(64) void pool_kernel(
        const float* __restrict__ xw, const int* __restrict__ batch,
        float* __restrict__ g, int n)
{
    int gr = blockIdx.x;
    int lane = threadIdx.x;
    int lo = 0, hi = n;
    while (lo < hi){ int m = (lo + hi) >> 1; if (batch[m] < gr) lo = m + 1; else hi = m; }
    int r0 = lo;
    hi = n;
    while (lo < hi){ int m = (lo + hi) >> 1; if (batch[m] < gr + 1) lo = m + 1; else hi = m; }
    int r1 = lo;
    float acc = 0.f;
    for (int r = r0; r < r1; r++) acc += xw[(size_t)r*64 + lane];
    g[(size_t)gr*64 + lane] = acc;
}

// ---------------- head ----------------------------------------------------
__global__ __launch_bounds__(256) void head_kernel(
        const float* __restrict__ g, const float* __restrict__ postW,
        const float* __restrict__ postb, const float* __restrict__ roW,
        const float* __restrict__ rob, float* __restrict__ out, int ngraph)
{
    int gr = __builtin_amdgcn_readfirstlane(blockIdx.x * 4 + (threadIdx.x >> 6));
    int lane = threadIdx.x & 63;
    if (gr >= ngraph) return;
    float gv = g[(size_t)gr*64 + lane];
    float t = postb[lane];
    for (int k = 0; k < 64; k++){
        float a = __shfl(gv, k);
        t = fmaf(a, postW[k*64 + lane], t);
    }
    t = fmaxf(t, 0.f);
    float lg = (lane < NCLS) ? rob[lane] : 0.f;
    for (int k = 0; k < 64; k++){
        float a = __shfl(t, k);
        float w = (lane < NCLS) ? roW[k*NCLS + lane] : 0.f;
        lg = fmaf(a, w, lg);
    }
    float m = (lane < NCLS) ? lg : -INFINITY;
#pragma unroll
    for (int d = 1; d < 16; d <<= 1) m = fmaxf(m, __shfl_xor(m, d, 16));
    float ex = (lane < NCLS) ? expf(lg - m) : 0.f;
    float ssum = ex;
#pragma unroll
    for (int d = 1; d < 16; d <<= 1) ssum += __shfl_xor(ssum, d, 16);
    if (lane < NCLS) out[(size_t)gr*NCLS + lane] = lg - m - logf(ssum);
}

// ---------------- launch --------------------------------------------------
extern "C" void kernel_launch(void* const* d_in, const int* in_sizes, int n_in,
                              void* d_out, int out_size, void* d_ws, size_t ws_size,
                              hipStream_t stream) {
    const float* x      = (const float*)d_in[0];
    const float* s      = (const float*)d_in[1];
    const int*   ei     = (const int*)d_in[2];    // int32
    const int*   batch  = (const int*)d_in[3];    // int32
    const float* pre_W  = (const float*)d_in[4];
    const float* pre_b  = (const float*)d_in[5];
    const float* emb_W  = (const float*)d_in[6];
    const float* emb_b  = (const float*)d_in[7];
    const float* gin_W1 = (const float*)d_in[8];
    const float* gin_b1 = (const float*)d_in[9];
    const float* gin_W2 = (const float*)d_in[10];
    const float* gin_b2 = (const float*)d_in[11];
    const float* gcn_W  = (const float*)d_in[12];
    const float* gcn_b  = (const float*)d_in[13];
    const float* whp_W  = (const float*)d_in[14];
    const float* whp_b  = (const float*)d_in[15];
    const float* post_W = (const float*)d_in[16];
    const float* post_b = (const float*)d_in[17];
    const float* ro_W   = (const float*)d_in[18];
    const float* ro_b   = (const float*)d_in[19];
    float* out = (float*)d_out;

    char* w = (char*)d_ws;
    auto alloc = [&](size_t bytes) -> void* {
        void* p = (void*)w;
        w += (bytes + 255) & ~(size_t)255;
        return p;
    };
    int*   off   = (int*)  alloc((size_t)(NN+1) * 4);
    int*   csr   = (int*)  alloc((size_t)NE * 4);
    int*   ghist = (int*)  alloc((size_t)NCH * CB * 4);
    unsigned int* ebuf = (unsigned int*)alloc((size_t)NE * 4);
    float* dinv = (float*)alloc((size_t)NN * 4);
    unsigned short* xcb0 = (unsigned short*)alloc((size_t)NN * 128 * 2);
    unsigned short* xcb1 = (unsigned short*)alloc((size_t)NN * 128 * 2);
    unsigned int*   hpreb = (unsigned int*)alloc((size_t)NN * 64 * 4);  // bf16 [n,128]
    unsigned int*   ub    = (unsigned int*)alloc((size_t)NN * 32 * 4);  // bf16 [n,64]
    float* xw   = (float*)alloc((size_t)NN * 64 * 4);
    float* gbuf = (float*)alloc((size_t)NG * 64 * 4);
    unsigned short* gcnWT = (unsigned short*)alloc((size_t)3 * 4096 * 2);
    unsigned short* W1T   = (unsigned short*)alloc((size_t)3 * 8192 * 2);
    unsigned short* W2T   = (unsigned short*)alloc((size_t)3 * 4096 * 2);
    unsigned short* whpWT = (unsigned short*)alloc((size_t)8192 * 2);

    const int B  = 256;
    const int GL = (NN + 63) / 64;   // 782
    const int GA = (NN + 3) / 4;     // 12500

    // weight prep + CSR build
    wprep<<<224, 256, 0, stream>>>(gcn_W, gin_W1, gin_W2, whp_W, gcnWT, W1T, W2T, whpWT);
    coarse_hist<<<NCH, 256, 0, stream>>>(ei + NE, ghist);
    coarse_scan<<<1,   256, 0, stream>>>(ghist);
    bin_lds    <<<NCH, 256, 0, stream>>>(ei, ei + NE, ghist, ebuf);
    scatter_all<<<CB,  256, 0, stream>>>(ebuf, ghist, off, dinv, csr, NN);

    // pre / emb -> xcb0 = bf16([x|s] @ W + b)
    linear64<FEATD><<<GL, B, 0, stream>>>(x, FEATD, pre_W, pre_b, xcb0,      128, NN);
    linear64<SED>  <<<GL, B, 0, stream>>>(s, SED,   emb_W, emb_b, xcb0 + 64, 128, NN);

    for (int i = 0; i < NLAY; i++){
        unsigned short* cur = (i & 1) ? xcb1 : xcb0;
        unsigned short* nxt = (i & 1) ? xcb0 : xcb1;
        merged_agg<<<GA, B, 0, stream>>>((const unsigned int*)cur, dinv, off, csr,
                                         hpreb, ub, NN);
        ginmlp3<<<GL, B, 0, stream>>>((const unsigned short*)hpreb,
                                      (const unsigned short*)ub,
                                      W1T + (size_t)i*8192, gin_b1 + i*64,
                                      W2T + (size_t)i*4096, gin_b2 + i*64,
                                      gcnWT + (size_t)i*4096, gcn_b + i*64,
                                      nxt, NN);
    }

    // whp (final state in xcb1 after 3 layers)
    mfma_linear<128><<<GL, B, 0, stream>>>(xcb1, 128, whpWT, whp_b, xw, 64, NN);

    // pool + head
    pool_kernel<<<NG, 64, 0, stream>>>(xw, batch, gbuf, NN);
    head_kernel<<<(NG + 3)/4, B, 0, stream>>>(gbuf, post_W, post_b, ro_W, ro_b, out, NG);
}

// Round 11
// 426.134 us; speedup vs baseline: 1.5857x; 1.0034x over previous
//
#include <hip/hip_runtime.h>
#include <math.h>

#define NN   50000
#define NE   800000
#define FEATD 128
#define SED  16
#define HD   64
#define NCLS 10
#define NLAY 3
#define NG   500

// two-level counting sort params
#define CHUNK 8192
#define NCH   ((NE + CHUNK - 1) / CHUNK)  // 98
#define CBSH  9
#define CB    ((NN + (1 << CBSH) - 1) >> CBSH)  // 98

typedef short  v8s __attribute__((ext_vector_type(8)));
typedef float  v4f __attribute__((ext_vector_type(4)));

// ---- bf16 helpers ---------------------------------------------------------
__device__ inline unsigned short f2bf(float f){
    unsigned int u = __float_as_uint(f);
    u += 0x7fffu + ((u >> 16) & 1u);
    return (unsigned short)(u >> 16);
}
__device__ inline unsigned int pack2bf(float a, float b){
    return (unsigned int)f2bf(a) | ((unsigned int)f2bf(b) << 16);
}
__device__ inline float bf_lo(unsigned int p){ return __uint_as_float(p << 16); }
__device__ inline float bf_hi(unsigned int p){ return __uint_as_float(p & 0xffff0000u); }

// ---------------- weight prep: bf16 + transpose to WT[n][k] ----------------
__global__ __launch_bounds__(256) void wprep(
        const float* __restrict__ gcn_W, const float* __restrict__ gin_W1,
        const float* __restrict__ gin_W2, const float* __restrict__ whp_W,
        unsigned short* __restrict__ gcnWT, unsigned short* __restrict__ W1T,
        unsigned short* __restrict__ W2T,  unsigned short* __restrict__ whpWT)
{
    int i = blockIdx.x*256 + threadIdx.x;
    if (i < 12288){
        int li = i / 4096, r = i % 4096, nn = r / 64, kk = r % 64;
        gcnWT[li*4096 + nn*64 + kk] = f2bf(gcn_W[li*4096 + kk*64 + nn]);
    } else if (i < 36864){
        int j = i - 12288; int li = j / 8192, r = j % 8192, nn = r / 128, kk = r % 128;
        W1T[li*8192 + nn*128 + kk] = f2bf(gin_W1[li*8192 + kk*64 + nn]);
    } else if (i < 49152){
        int j = i - 36864; int li = j / 4096, r = j % 4096, nn = r / 64, kk = r % 64;
        W2T[li*4096 + nn*64 + kk] = f2bf(gin_W2[li*4096 + kk*64 + nn]);
    } else if (i < 57344){
        int j = i - 49152; int nn = j / 128, kk = j % 128;
        whpWT[nn*128 + kk] = f2bf(whp_W[kk*64 + nn]);
    }
}

// ---------------- two-level counting sort of edges by dst ------------------
__global__ __launch_bounds__(256) void coarse_hist(
        const int* __restrict__ dst, int* __restrict__ ghist){
    __shared__ int h[CB];
    for (int i = threadIdx.x; i < CB; i += 256) h[i] = 0;
    __syncthreads();
    int base = blockIdx.x * CHUNK;
    int end  = base + CHUNK; if (end > NE) end = NE;
    for (int i = base + threadIdx.x; i < end; i += 256)
        atomicAdd(&h[dst[i] >> CBSH], 1);
    __syncthreads();
    for (int i = threadIdx.x; i < CB; i += 256)
        ghist[(size_t)blockIdx.x * CB + i] = h[i];
}

__global__ __launch_bounds__(256) void coarse_scan(int* __restrict__ ghist){
    __shared__ int sh[256];
    int t = threadIdx.x;
    int run = 0;
    if (t < CB){
        for (int c = 0; c < NCH; c++){
            int v = ghist[(size_t)c*CB + t];
            ghist[(size_t)c*CB + t] = run;
            run += v;
        }
    }
    sh[t] = (t < CB) ? run : 0;
    __syncthreads();
    for (int d = 1; d < 256; d <<= 1){
        int u = (t >= d) ? sh[t-d] : 0;
        __syncthreads();
        sh[t] += u;
        __syncthreads();
    }
    int bstart = (t == 0) ? 0 : sh[t-1];
    if (t < CB){
        for (int c = 0; c < NCH; c++) ghist[(size_t)c*CB + t] += bstart;
    }
}

__global__ __launch_bounds__(256) void bin_lds(
        const int* __restrict__ src, const int* __restrict__ dst,
        const int* __restrict__ ghist, unsigned int* __restrict__ ebuf){
    __shared__ unsigned int lbuf[CHUNK];
    __shared__ unsigned int lbuf2[CHUNK];
    __shared__ int hist[CB], lstart[CB], cursor[CB], gbase[CB];
    __shared__ int sc[256];
    int t = threadIdx.x, c = blockIdx.x;
    for (int i = t; i < CB; i += 256){
        hist[i] = 0;
        gbase[i] = ghist[(size_t)c*CB + i];
    }
    __syncthreads();
    int base = c * CHUNK;
    int nend = base + CHUNK; if (nend > NE) nend = NE;
    nend -= base;
    for (int i = t; i < nend; i += 256){
        int d = dst[base + i];
        lbuf[i] = (unsigned int)src[base + i] | ((unsigned int)d << 16);
        atomicAdd(&hist[d >> CBSH], 1);
    }
    __syncthreads();
    sc[t] = (t < CB) ? hist[t] : 0;
    __syncthreads();
    for (int d = 1; d < 256; d <<= 1){
        int u = (t >= d) ? sc[t-d] : 0;
        __syncthreads();
        sc[t] += u;
        __syncthreads();
    }
    if (t < CB){
        lstart[t] = sc[t] - hist[t];
        cursor[t] = sc[t] - hist[t];
    }
    __syncthreads();
    for (int i = t; i < nend; i += 256){
        unsigned int u = lbuf[i];
        int b = (int)(u >> 16) >> CBSH;
        int p = atomicAdd(&cursor[b], 1);
        lbuf2[p] = u;
    }
    __syncthreads();
    for (int p = t; p < nend; p += 256){
        unsigned int u = lbuf2[p];
        int b = (int)(u >> 16) >> CBSH;
        ebuf[gbase[b] + (p - lstart[b])] = u;
    }
}

__global__ __launch_bounds__(256) void scatter_all(
        const unsigned int* __restrict__ ebuf, const int* __restrict__ ghist,
        int* __restrict__ off, float* __restrict__ dinv,
        int* __restrict__ csr, int n){
    __shared__ int lcnt[512];
    __shared__ int lex[512];
    __shared__ int sc[256];
    int t = threadIdx.x, b = blockIdx.x;
    int n0 = b << CBSH;
    int nn = n - n0; if (nn > 512) nn = 512;
    int lo = ghist[b];
    int hi = (b + 1 < CB) ? ghist[b + 1] : NE;
    lcnt[t] = 0; lcnt[t + 256] = 0;
    __syncthreads();
    for (int j = lo + t; j < hi; j += 256)
        atomicAdd(&lcnt[(int)(ebuf[j] >> 16) - n0], 1);
    __syncthreads();
    int c0 = lcnt[2*t], c1 = lcnt[2*t+1];
    sc[t] = c0 + c1;
    __syncthreads();
    for (int d = 1; d < 256; d <<= 1){
        int u = (t >= d) ? sc[t-d] : 0;
        __syncthreads();
        sc[t] += u;
        __syncthreads();
    }
    int bse = sc[t] - (c0 + c1);
    lex[2*t]   = bse;
    lex[2*t+1] = bse + c0;
    __syncthreads();
    for (int i = t; i < nn; i += 256){
        off[n0 + i]  = lo + lex[i];
        dinv[n0 + i] = rsqrtf((float)lcnt[i] + 1.0f);
    }
    if (b == 0 && t == 0) off[n] = NE;
    __syncthreads();
    for (int j = lo + t; j < hi; j += 256){
        unsigned int u = ebuf[j];
        int d = (int)(u >> 16) - n0;
        int p = atomicAdd(&lex[d], 1);
        csr[lo + p] = (int)(u & 0xffffu);
    }
}

// ---------------- fp32 linear (pre/emb only): outb = bf16(A@W + b) --------
template<int K>
__global__ __launch_bounds__(256) void linear64(
        const float* __restrict__ A, int lda,
        const float* __restrict__ W,
        const float* __restrict__ bias,
        unsigned short* __restrict__ outb, int ldob, int n)
{
    constexpr int STR = K + 4;
    constexpr int NQ  = K / 4;
    __shared__ float at[64 * STR];
    int tid = threadIdx.x;
    int r0  = blockIdx.x * 64;
    for (int idx = tid; idx < 64 * NQ; idx += 256){
        int row = idx / NQ, kq = idx - row * NQ;
        float4 v = make_float4(0.f, 0.f, 0.f, 0.f);
        if (r0 + row < n) v = *(const float4*)(A + (size_t)(r0 + row) * lda + kq * 4);
        *(float4*)(&at[row * STR + kq * 4]) = v;
    }
    __syncthreads();
    int lane = tid & 63;
    int c0 = __builtin_amdgcn_readfirstlane((tid >> 6) << 4);
    int row = r0 + lane;
    if (row >= n) return;
    float acc[16];
#pragma unroll
    for (int j = 0; j < 16; j++) acc[j] = 0.f;
    const float* wp = W + c0;
    for (int k = 0; k < K; k += 4){
        float4 av = *(const float4*)(&at[lane * STR + k]);
        float aa[4] = {av.x, av.y, av.z, av.w};
#pragma unroll
        for (int kk = 0; kk < 4; kk++){
            const float* wr = wp + (k + kk) * 64;
#pragma unroll
            for (int j = 0; j < 16; j++)
                acc[j] = fmaf(aa[kk], wr[j], acc[j]);
        }
    }
#pragma unroll
    for (int j = 0; j < 16; j++) acc[j] += bias[c0 + j];
    unsigned int pk[8];
#pragma unroll
    for (int j = 0; j < 8; j++) pk[j] = pack2bf(acc[2*j], acc[2*j+1]);
    unsigned short* ob = outb + (size_t)row * ldob + c0;
    uint4 u0; u0.x = pk[0]; u0.y = pk[1]; u0.z = pk[2]; u0.w = pk[3];
    uint4 u1; u1.x = pk[4]; u1.y = pk[5]; u1.z = pk[6]; u1.w = pk[7];
    *(uint4*)(ob)     = u0;
    *(uint4*)(ob + 8) = u1;
}

// ---------------- MFMA bf16 linear (whp): out fp32 -----------------------
template<int K>
__global__ __launch_bounds__(256) void mfma_linear(
        const unsigned short* __restrict__ A, int lda,
        const unsigned short* __restrict__ WT,
        const float* __restrict__ bias,
        float* __restrict__ out, int ldo, int n)
{
    constexpr int NKO = K / 32;
    int tid = threadIdx.x;
    int w = tid >> 6, l = tid & 63;
    int m = l & 15, q = l >> 4;
    int rbase = blockIdx.x * 64 + w * 16;
    int arow  = rbase + m;
    bool valid = arow < n;
    v8s a[NKO];
#pragma unroll
    for (int ko = 0; ko < NKO; ko++){
        v8s z = {0,0,0,0,0,0,0,0};
        a[ko] = valid ? *(const v8s*)(A + (size_t)arow * lda + ko*32 + q*8) : z;
    }
#pragma unroll
    for (int ct = 0; ct < 4; ct++){
        v4f acc = {0.f, 0.f, 0.f, 0.f};
#pragma unroll
        for (int ko = 0; ko < NKO; ko++){
            v8s b = *(const v8s*)(WT + (size_t)(ct*16 + m) * K + ko*32 + q*8);
            acc = __builtin_amdgcn_mfma_f32_16x16x32_bf16(a[ko], b, acc, 0, 0, 0);
        }
        int col = ct*16 + m;
        float bv = bias ? bias[col] : 0.f;
#pragma unroll
        for (int r = 0; r < 4; r++){
            int orow = rbase + q*4 + r;
            if (orow < n) out[(size_t)orow * ldo + col] = acc[r] + bv;
        }
    }
}

// ---------------- merged aggregation: ONE gather feeds GIN + GCN -----------
__global__ __launch_bounds__(256) void merged_agg(
        const unsigned int* __restrict__ xcb_cur,
        const float* __restrict__ dinv,
        const int* __restrict__ off, const int* __restrict__ csr,
        unsigned int* __restrict__ hpreb, unsigned int* __restrict__ ub, int n)
{
    int node = __builtin_amdgcn_readfirstlane(blockIdx.x * 4 + (threadIdx.x >> 6));
    int lane = threadIdx.x & 63;
    if (node >= n) return;
    int beg = off[node], end = off[node+1];
    unsigned int ps = xcb_cur[(size_t)node*64 + lane];
    float s0f = bf_lo(ps), s1f = bf_hi(ps);
    float a0 = s0f, a1 = s1f;
    float g0 = 0.f, g1 = 0.f;
    int e = beg;
    for (; e + 4 <= end; e += 4){
        int s0 = csr[e], s1 = csr[e+1], s2 = csr[e+2], s3 = csr[e+3];
        unsigned int p0 = xcb_cur[(size_t)s0*64 + lane];
        unsigned int p1 = xcb_cur[(size_t)s1*64 + lane];
        unsigned int p2 = xcb_cur[(size_t)s2*64 + lane];
        unsigned int p3 = xcb_cur[(size_t)s3*64 + lane];
        float d0 = dinv[s0], d1 = dinv[s1], d2 = dinv[s2], d3 = dinv[s3];
        float v0 = bf_lo(p0), v1 = bf_lo(p1), v2 = bf_lo(p2), v3 = bf_lo(p3);
        float w0 = bf_hi(p0), w1 = bf_hi(p1), w2 = bf_hi(p2), w3 = bf_hi(p3);
        a0 += (v0 + v1) + (v2 + v3);
        a1 += (w0 + w1) + (w2 + w3);
        g0 = fmaf(d0, v0, fmaf(d1, v1, fmaf(d2, v2, fmaf(d3, v3, g0))));
        g1 = fmaf(d0, w0, fmaf(d1, w1, fmaf(d2, w2, fmaf(d3, w3, g1))));
    }
    for (; e < end; e++){
        int s0 = csr[e];
        unsigned int p0 = xcb_cur[(size_t)s0*64 + lane];
        float d0 = dinv[s0];
        float v0 = bf_lo(p0), w0 = bf_hi(p0);
        a0 += v0; a1 += w0;
        g0 = fmaf(d0, v0, g0);
        g1 = fmaf(d0, w0, g1);
    }
    hpreb[(size_t)node*64 + lane] = pack2bf(a0, a1);
    if (lane >= 32){   // lanes 32..63 hold s_prev cols (64..127)
        float di = dinv[node];
        float u0 = fmaf(di, g0, di*di*s0f);
        float u1 = fmaf(di, g1, di*di*s1f);
        ub[(size_t)node*32 + (lane - 32)] = pack2bf(u0, u1);
    }
}

// ---------------- fused per-layer MFMA: GIN MLP + GCN linear ---------------
__global__ __launch_bounds__(256) void ginmlp3(
        const unsigned short* __restrict__ hpreb,   // [n,128] bf16
        const unsigned short* __restrict__ ub,      // [n,64]  bf16
        const unsigned short* __restrict__ W1T,     // [64][128]
        const float* __restrict__ b1,
        const unsigned short* __restrict__ W2T,     // [64][64]
        const float* __restrict__ b2,
        const unsigned short* __restrict__ gcnWT,   // [64][64]
        const float* __restrict__ gcnb,
        unsigned short* __restrict__ xcb_nxt, int n)
{
    __shared__ unsigned short hsh[64 * 72];
    int tid = threadIdx.x;
    int w = tid >> 6, l = tid & 63;
    int m = l & 15, q = l >> 4;
    int rbase = blockIdx.x * 64 + w * 16;
    int arow  = rbase + m;
    bool valid = arow < n;
    v8s z = {0,0,0,0,0,0,0,0};
    // GEMM3: s_new = tanh(ub @ gcnW + b)
    {
        v8s a3[2];
#pragma unroll
        for (int ko = 0; ko < 2; ko++)
            a3[ko] = valid ? *(const v8s*)(ub + (size_t)arow * 64 + ko*32 + q*8) : z;
#pragma unroll
        for (int ct = 0; ct < 4; ct++){
            v4f acc = {0.f, 0.f, 0.f, 0.f};
#pragma unroll
            for (int ko = 0; ko < 2; ko++){
                v8s b = *(const v8s*)(gcnWT + (size_t)(ct*16 + m) * 64 + ko*32 + q*8);
                acc = __builtin_amdgcn_mfma_f32_16x16x32_bf16(a3[ko], b, acc, 0, 0, 0);
            }
            int col = ct*16 + m;
            float bv = gcnb[col];
#pragma unroll
            for (int r = 0; r < 4; r++){
                int orow = rbase + q*4 + r;
                if (orow < n)
                    xcb_nxt[(size_t)orow * 128 + 64 + col] = f2bf(tanhf(acc[r] + bv));
            }
        }
    }
    // GEMM1: h = relu(hpreb @ W1 + b1) -> LDS (bf16)
    {
        v8s a[4];
#pragma unroll
        for (int ko = 0; ko < 4; ko++)
            a[ko] = valid ? *(const v8s*)(hpreb + (size_t)arow * 128 + ko*32 + q*8) : z;
#pragma unroll
        for (int ct = 0; ct < 4; ct++){
            v4f acc = {0.f, 0.f, 0.f, 0.f};
#pragma unroll
            for (int ko = 0; ko < 4; ko++){
                v8s b = *(const v8s*)(W1T + (size_t)(ct*16 + m) * 128 + ko*32 + q*8);
                acc = __builtin_amdgcn_mfma_f32_16x16x32_bf16(a[ko], b, acc, 0, 0, 0);
            }
            int col = ct*16 + m;
            float bv = b1[col];
#pragma unroll
            for (int r = 0; r < 4; r++){
                int lrow = w*16 + q*4 + r;
                hsh[lrow*72 + col] = f2bf(fmaxf(acc[r] + bv, 0.f));
            }
        }
    }
    __syncthreads();
    // GEMM2: x_new = relu(h @ W2 + b2)
    v8s a2[2];
#pragma unroll
    for (int ko = 0; ko < 2; ko++)
        a2[ko] = *(const v8s*)(&hsh[(w*16 + m)*72 + ko*32 + q*8]);
#pragma unroll
    for (int ct = 0; ct < 4; ct++){
        v4f acc = {0.f, 0.f, 0.f, 0.f};
#pragma unroll
        for (int ko = 0; ko < 2; ko++){
            v8s b = *(const v8s*)(W2T + (size_t)(ct*16 + m) * 64 + ko*32 + q*8);
            acc = __builtin_amdgcn_mfma_f32_16x16x32_bf16(a2[ko], b, acc, 0, 0, 0);
        }
        int col = ct*16 + m;
        float bv = b2[col];
#pragma unroll
        for (int r = 0; r < 4; r++){
            int orow = rbase + q*4 + r;
            if (orow < n)
                xcb_nxt[(size_t)orow * 128 + col] = f2bf(fmaxf(acc[r] + bv, 0.f));
        }
    }
}

// ---------------- global_add_pool: chunked scan over sorted batch ----------
// 64 lanes = feature cols; each block scans 128 rows, one atomicAdd per
// (graph-segment, lane). gbuf must be zeroed (hipMemsetAsync).
__global__ __launch_bounds__(64) void pool_kernel(
        const float* __restrict__ xw, const int* __restrict__ batch,
        float* __restrict__ g, int n)
{
    int lane = threadIdx.x;
    int r0 = blockIdx.x * 128;
    if (r0 >= n) return;
    int r1 = r0 + 128; if (r1 > n) r1 = n;
    float acc = 0.f;
    int cb = batch[r0];
    for (int r = r0; r < r1; r++){
        int b = batch[r];
        if (b != cb){
            atomicAdd(&g[(size_t)cb*64 + lane], acc);
            acc = 0.f; cb = b;
        }
        acc += xw[(size_t)r*64 + lane];
    }
    atomicAdd(&g[(size_t)cb*64 + lane], acc);
}

// ---------------- head ----------------------------------------------------
__global__ __launch_bounds__(256) void head_kernel(
        const float* __restrict__ g, const float* __restrict__ postW,
        const float* __restrict__ postb, const float* __restrict__ roW,
        const float* __restrict__ rob, float* __restrict__ out, int ngraph)
{
    int gr = __builtin_amdgcn_readfirstlane(blockIdx.x * 4 + (threadIdx.x >> 6));
    int lane = threadIdx.x & 63;
    if (gr >= ngraph) return;
    float gv = g[(size_t)gr*64 + lane];
    float t = postb[lane];
    for (int k = 0; k < 64; k++){
        float a = __shfl(gv, k);
        t = fmaf(a, postW[k*64 + lane], t);
    }
    t = fmaxf(t, 0.f);
    float lg = (lane < NCLS) ? rob[lane] : 0.f;
    for (int k = 0; k < 64; k++){
        float a = __shfl(t, k);
        float w = (lane < NCLS) ? roW[k*NCLS + lane] : 0.f;
        lg = fmaf(a, w, lg);
    }
    float m = (lane < NCLS) ? lg : -INFINITY;
#pragma unroll
    for (int d = 1; d < 16; d <<= 1) m = fmaxf(m, __shfl_xor(m, d, 16));
    float ex = (lane < NCLS) ? expf(lg - m) : 0.f;
    float ssum = ex;
#pragma unroll
    for (int d = 1; d < 16; d <<= 1) ssum += __shfl_xor(ssum, d, 16);
    if (lane < NCLS) out[(size_t)gr*NCLS + lane] = lg - m - logf(ssum);
}

// ---------------- launch --------------------------------------------------
extern "C" void kernel_launch(void* const* d_in, const int* in_sizes, int n_in,
                              void* d_out, int out_size, void* d_ws, size_t ws_size,
                              hipStream_t stream) {
    const float* x      = (const float*)d_in[0];
    const float* s      = (const float*)d_in[1];
    const int*   ei     = (const int*)d_in[2];    // int32
    const int*   batch  = (const int*)d_in[3];    // int32
    const float* pre_W  = (const float*)d_in[4];
    const float* pre_b  = (const float*)d_in[5];
    const float* emb_W  = (const float*)d_in[6];
    const float* emb_b  = (const float*)d_in[7];
    const float* gin_W1 = (const float*)d_in[8];
    const float* gin_b1 = (const float*)d_in[9];
    const float* gin_W2 = (const float*)d_in[10];
    const float* gin_b2 = (const float*)d_in[11];
    const float* gcn_W  = (const float*)d_in[12];
    const float* gcn_b  = (const float*)d_in[13];
    const float* whp_W  = (const float*)d_in[14];
    const float* whp_b  = (const float*)d_in[15];
    const float* post_W = (const float*)d_in[16];
    const float* post_b = (const float*)d_in[17];
    const float* ro_W   = (const float*)d_in[18];
    const float* ro_b   = (const float*)d_in[19];
    float* out = (float*)d_out;

    char* w = (char*)d_ws;
    auto alloc = [&](size_t bytes) -> void* {
        void* p = (void*)w;
        w += (bytes + 255) & ~(size_t)255;
        return p;
    };
    int*   off   = (int*)  alloc((size_t)(NN+1) * 4);
    int*   csr   = (int*)  alloc((size_t)NE * 4);
    int*   ghist = (int*)  alloc((size_t)NCH * CB * 4);
    unsigned int* ebuf = (unsigned int*)alloc((size_t)NE * 4);
    float* dinv = (float*)alloc((size_t)NN * 4);
    unsigned short* xcb0 = (unsigned short*)alloc((size_t)NN * 128 * 2);
    unsigned short* xcb1 = (unsigned short*)alloc((size_t)NN * 128 * 2);
    unsigned int*   hpreb = (unsigned int*)alloc((size_t)NN * 64 * 4);  // bf16 [n,128]
    unsigned int*   ub    = (unsigned int*)alloc((size_t)NN * 32 * 4);  // bf16 [n,64]
    float* xw   = (float*)alloc((size_t)NN * 64 * 4);
    float* gbuf = (float*)alloc((size_t)NG * 64 * 4);
    unsigned short* gcnWT = (unsigned short*)alloc((size_t)3 * 4096 * 2);
    unsigned short* W1T   = (unsigned short*)alloc((size_t)3 * 8192 * 2);
    unsigned short* W2T   = (unsigned short*)alloc((size_t)3 * 4096 * 2);
    unsigned short* whpWT = (unsigned short*)alloc((size_t)8192 * 2);

    const int B  = 256;
    const int GL = (NN + 63) / 64;   // 782
    const int GA = (NN + 3) / 4;     // 12500

    // weight prep + CSR build
    wprep<<<224, 256, 0, stream>>>(gcn_W, gin_W1, gin_W2, whp_W, gcnWT, W1T, W2T, whpWT);
    coarse_hist<<<NCH, 256, 0, stream>>>(ei + NE, ghist);
    coarse_scan<<<1,   256, 0, stream>>>(ghist);
    bin_lds    <<<NCH, 256, 0, stream>>>(ei, ei + NE, ghist, ebuf);
    scatter_all<<<CB,  256, 0, stream>>>(ebuf, ghist, off, dinv, csr, NN);

    // pre / emb -> xcb0 = bf16([x|s] @ W + b)
    linear64<FEATD><<<GL, B, 0, stream>>>(x, FEATD, pre_W, pre_b, xcb0,      128, NN);
    linear64<SED>  <<<GL, B, 0, stream>>>(s, SED,   emb_W, emb_b, xcb0 + 64, 128, NN);

    for (int i = 0; i < NLAY; i++){
        unsigned short* cur = (i & 1) ? xcb1 : xcb0;
        unsigned short* nxt = (i & 1) ? xcb0 : xcb1;
        merged_agg<<<GA, B, 0, stream>>>((const unsigned int*)cur, dinv, off, csr,
                                         hpreb, ub, NN);
        ginmlp3<<<GL, B, 0, stream>>>((const unsigned short*)hpreb,
                                      (const unsigned short*)ub,
                                      W1T + (size_t)i*8192, gin_b1 + i*64,
                                      W2T + (size_t)i*4096, gin_b2 + i*64,
                                      gcnWT + (size_t)i*4096, gcn_b + i*64,
                                      nxt, NN);
    }

    // whp (final state in xcb1 after 3 layers)
    mfma_linear<128><<<GL, B, 0, stream>>>(xcb1, 128, whpWT, whp_b, xw, 64, NN);

    // pool (chunked scan + atomics) + head
    hipMemsetAsync(gbuf, 0, (size_t)NG * 64 * 4, stream);
    pool_kernel<<<(NN + 127)/128, 64, 0, stream>>>(xw, batch, gbuf, NN);
    head_kernel<<<(NG + 3)/4, B, 0, stream>>>(gbuf, post_W, post_b, ro_W, ro_b, out, NG);
}

// Round 12
// 390.348 us; speedup vs baseline: 1.7310x; 1.0917x over previous
//
#include <hip/hip_runtime.h>
#include <math.h>

#define NN   50000
#define NE   800000
#define FEATD 128
#define SED  16
#define HD   64
#define NCLS 10
#define NLAY 3
#define NG   500

// two-level counting sort params
#define CHUNK 8192
#define NCH   ((NE + CHUNK - 1) / CHUNK)  // 98
#define CBSH  9
#define CB    ((NN + (1 << CBSH) - 1) >> CBSH)  // 98

typedef short  v8s __attribute__((ext_vector_type(8)));
typedef float  v4f __attribute__((ext_vector_type(4)));

// ---- bf16 helpers ---------------------------------------------------------
__device__ inline unsigned short f2bf(float f){
    unsigned int u = __float_as_uint(f);
    u += 0x7fffu + ((u >> 16) & 1u);
    return (unsigned short)(u >> 16);
}
__device__ inline unsigned int pack2bf(float a, float b){
    return (unsigned int)f2bf(a) | ((unsigned int)f2bf(b) << 16);
}
__device__ inline float bf_lo(unsigned int p){ return __uint_as_float(p << 16); }
__device__ inline float bf_hi(unsigned int p){ return __uint_as_float(p & 0xffff0000u); }

// ---------------- weight prep: bf16 + transpose to WT[n][k] ----------------
__global__ __launch_bounds__(256) void wprep(
        const float* __restrict__ gcn_W, const float* __restrict__ gin_W1,
        const float* __restrict__ gin_W2, const float* __restrict__ whp_W,
        unsigned short* __restrict__ gcnWT, unsigned short* __restrict__ W1T,
        unsigned short* __restrict__ W2T,  unsigned short* __restrict__ whpWT)
{
    int i = blockIdx.x*256 + threadIdx.x;
    if (i < 12288){
        int li = i / 4096, r = i % 4096, nn = r / 64, kk = r % 64;
        gcnWT[li*4096 + nn*64 + kk] = f2bf(gcn_W[li*4096 + kk*64 + nn]);
    } else if (i < 36864){
        int j = i - 12288; int li = j / 8192, r = j % 8192, nn = r / 128, kk = r % 128;
        W1T[li*8192 + nn*128 + kk] = f2bf(gin_W1[li*8192 + kk*64 + nn]);
    } else if (i < 49152){
        int j = i - 36864; int li = j / 4096, r = j % 4096, nn = r / 64, kk = r % 64;
        W2T[li*4096 + nn*64 + kk] = f2bf(gin_W2[li*4096 + kk*64 + nn]);
    } else if (i < 57344){
        int j = i - 49152; int nn = j / 128, kk = j % 128;
        whpWT[nn*128 + kk] = f2bf(whp_W[kk*64 + nn]);
    }
}

// ---------------- two-level counting sort of edges by dst ------------------
__global__ __launch_bounds__(256) void coarse_hist(
        const int* __restrict__ dst, int* __restrict__ ghist){
    __shared__ int h[CB];
    for (int i = threadIdx.x; i < CB; i += 256) h[i] = 0;
    __syncthreads();
    int base = blockIdx.x * CHUNK;
    int end  = base + CHUNK; if (end > NE) end = NE;
    for (int i = base + threadIdx.x; i < end; i += 256)
        atomicAdd(&h[dst[i] >> CBSH], 1);
    __syncthreads();
    for (int i = threadIdx.x; i < CB; i += 256)
        ghist[(size_t)blockIdx.x * CB + i] = h[i];
}

// LDS-staged: whole ghist (98*98 = 9604 ints = 38.4KB) in LDS; serial loops
// hit LDS not L2. Coalesced global load/store.
__global__ __launch_bounds__(256) void coarse_scan(int* __restrict__ ghist){
    __shared__ int sh[NCH * CB];
    __shared__ int sc[256];
    int t = threadIdx.x;
    for (int i = t; i < NCH * CB; i += 256) sh[i] = ghist[i];
    __syncthreads();
    int run = 0;
    if (t < CB){
        for (int c = 0; c < NCH; c++){
            int v = sh[c*CB + t];
            sh[c*CB + t] = run;
            run += v;
        }
    }
    sc[t] = (t < CB) ? run : 0;
    __syncthreads();
    for (int d = 1; d < 256; d <<= 1){
        int u = (t >= d) ? sc[t-d] : 0;
        __syncthreads();
        sc[t] += u;
        __syncthreads();
    }
    int bstart = (t == 0) ? 0 : sc[t-1];
    if (t < CB){
        for (int c = 0; c < NCH; c++) sh[c*CB + t] += bstart;
    }
    __syncthreads();
    for (int i = t; i < NCH * CB; i += 256) ghist[i] = sh[i];
}

__global__ __launch_bounds__(256) void bin_lds(
        const int* __restrict__ src, const int* __restrict__ dst,
        const int* __restrict__ ghist, unsigned int* __restrict__ ebuf){
    __shared__ unsigned int lbuf[CHUNK];
    __shared__ unsigned int lbuf2[CHUNK];
    __shared__ int hist[CB], lstart[CB], cursor[CB], gbase[CB];
    __shared__ int sc[256];
    int t = threadIdx.x, c = blockIdx.x;
    for (int i = t; i < CB; i += 256){
        hist[i] = 0;
        gbase[i] = ghist[(size_t)c*CB + i];
    }
    __syncthreads();
    int base = c * CHUNK;
    int nend = base + CHUNK; if (nend > NE) nend = NE;
    nend -= base;
    for (int i = t; i < nend; i += 256){
        int d = dst[base + i];
        lbuf[i] = (unsigned int)src[base + i] | ((unsigned int)d << 16);
        atomicAdd(&hist[d >> CBSH], 1);
    }
    __syncthreads();
    sc[t] = (t < CB) ? hist[t] : 0;
    __syncthreads();
    for (int d = 1; d < 256; d <<= 1){
        int u = (t >= d) ? sc[t-d] : 0;
        __syncthreads();
        sc[t] += u;
        __syncthreads();
    }
    if (t < CB){
        lstart[t] = sc[t] - hist[t];
        cursor[t] = sc[t] - hist[t];
    }
    __syncthreads();
    for (int i = t; i < nend; i += 256){
        unsigned int u = lbuf[i];
        int b = (int)(u >> 16) >> CBSH;
        int p = atomicAdd(&cursor[b], 1);
        lbuf2[p] = u;
    }
    __syncthreads();
    for (int p = t; p < nend; p += 256){
        unsigned int u = lbuf2[p];
        int b = (int)(u >> 16) >> CBSH;
        ebuf[gbase[b] + (p - lstart[b])] = u;
    }
}

__global__ __launch_bounds__(256) void scatter_all(
        const unsigned int* __restrict__ ebuf, const int* __restrict__ ghist,
        int* __restrict__ off, float* __restrict__ dinv,
        int* __restrict__ csr, int n){
    __shared__ int lcnt[512];
    __shared__ int lex[512];
    __shared__ int sc[256];
    int t = threadIdx.x, b = blockIdx.x;
    int n0 = b << CBSH;
    int nn = n - n0; if (nn > 512) nn = 512;
    int lo = ghist[b];
    int hi = (b + 1 < CB) ? ghist[b + 1] : NE;
    lcnt[t] = 0; lcnt[t + 256] = 0;
    __syncthreads();
    for (int j = lo + t; j < hi; j += 256)
        atomicAdd(&lcnt[(int)(ebuf[j] >> 16) - n0], 1);
    __syncthreads();
    int c0 = lcnt[2*t], c1 = lcnt[2*t+1];
    sc[t] = c0 + c1;
    __syncthreads();
    for (int d = 1; d < 256; d <<= 1){
        int u = (t >= d) ? sc[t-d] : 0;
        __syncthreads();
        sc[t] += u;
        __syncthreads();
    }
    int bse = sc[t] - (c0 + c1);
    lex[2*t]   = bse;
    lex[2*t+1] = bse + c0;
    __syncthreads();
    for (int i = t; i < nn; i += 256){
        off[n0 + i]  = lo + lex[i];
        dinv[n0 + i] = rsqrtf((float)lcnt[i] + 1.0f);
    }
    if (b == 0 && t == 0) off[n] = NE;
    __syncthreads();
    for (int j = lo + t; j < hi; j += 256){
        unsigned int u = ebuf[j];
        int d = (int)(u >> 16) - n0;
        int p = atomicAdd(&lex[d], 1);
        csr[lo + p] = (int)(u & 0xffffu);
    }
}

// ---------------- fp32 linear (pre/emb only): outb = bf16(A@W + b) --------
template<int K>
__global__ __launch_bounds__(256) void linear64(
        const float* __restrict__ A, int lda,
        const float* __restrict__ W,
        const float* __restrict__ bias,
        unsigned short* __restrict__ outb, int ldob, int n)
{
    constexpr int STR = K + 4;
    constexpr int NQ  = K / 4;
    __shared__ float at[64 * STR];
    int tid = threadIdx.x;
    int r0  = blockIdx.x * 64;
    for (int idx = tid; idx < 64 * NQ; idx += 256){
        int row = idx / NQ, kq = idx - row * NQ;
        float4 v = make_float4(0.f, 0.f, 0.f, 0.f);
        if (r0 + row < n) v = *(const float4*)(A + (size_t)(r0 + row) * lda + kq * 4);
        *(float4*)(&at[row * STR + kq * 4]) = v;
    }
    __syncthreads();
    int lane = tid & 63;
    int c0 = __builtin_amdgcn_readfirstlane((tid >> 6) << 4);
    int row = r0 + lane;
    if (row >= n) return;
    float acc[16];
#pragma unroll
    for (int j = 0; j < 16; j++) acc[j] = 0.f;
    const float* wp = W + c0;
    for (int k = 0; k < K; k += 4){
        float4 av = *(const float4*)(&at[lane * STR + k]);
        float aa[4] = {av.x, av.y, av.z, av.w};
#pragma unroll
        for (int kk = 0; kk < 4; kk++){
            const float* wr = wp + (k + kk) * 64;
#pragma unroll
            for (int j = 0; j < 16; j++)
                acc[j] = fmaf(aa[kk], wr[j], acc[j]);
        }
    }
#pragma unroll
    for (int j = 0; j < 16; j++) acc[j] += bias[c0 + j];
    unsigned int pk[8];
#pragma unroll
    for (int j = 0; j < 8; j++) pk[j] = pack2bf(acc[2*j], acc[2*j+1]);
    unsigned short* ob = outb + (size_t)row * ldob + c0;
    uint4 u0; u0.x = pk[0]; u0.y = pk[1]; u0.z = pk[2]; u0.w = pk[3];
    uint4 u1; u1.x = pk[4]; u1.y = pk[5]; u1.z = pk[6]; u1.w = pk[7];
    *(uint4*)(ob)     = u0;
    *(uint4*)(ob + 8) = u1;
}

// ---------------- MFMA bf16 linear (whp): out fp32 -----------------------
template<int K>
__global__ __launch_bounds__(256) void mfma_linear(
        const unsigned short* __restrict__ A, int lda,
        const unsigned short* __restrict__ WT,
        const float* __restrict__ bias,
        float* __restrict__ out, int ldo, int n)
{
    constexpr int NKO = K / 32;
    int tid = threadIdx.x;
    int w = tid >> 6, l = tid & 63;
    int m = l & 15, q = l >> 4;
    int rbase = blockIdx.x * 64 + w * 16;
    int arow  = rbase + m;
    bool valid = arow < n;
    v8s a[NKO];
#pragma unroll
    for (int ko = 0; ko < NKO; ko++){
        v8s z = {0,0,0,0,0,0,0,0};
        a[ko] = valid ? *(const v8s*)(A + (size_t)arow * lda + ko*32 + q*8) : z;
    }
#pragma unroll
    for (int ct = 0; ct < 4; ct++){
        v4f acc = {0.f, 0.f, 0.f, 0.f};
#pragma unroll
        for (int ko = 0; ko < NKO; ko++){
            v8s b = *(const v8s*)(WT + (size_t)(ct*16 + m) * K + ko*32 + q*8);
            acc = __builtin_amdgcn_mfma_f32_16x16x32_bf16(a[ko], b, acc, 0, 0, 0);
        }
        int col = ct*16 + m;
        float bv = bias ? bias[col] : 0.f;
#pragma unroll
        for (int r = 0; r < 4; r++){
            int orow = rbase + q*4 + r;
            if (orow < n) out[(size_t)orow * ldo + col] = acc[r] + bv;
        }
    }
}

// ---------------- merged aggregation: ONE gather feeds GIN + GCN -----------
__global__ __launch_bounds__(256) void merged_agg(
        const unsigned int* __restrict__ xcb_cur,
        const float* __restrict__ dinv,
        const int* __restrict__ off, const int* __restrict__ csr,
        unsigned int* __restrict__ hpreb, unsigned int* __restrict__ ub, int n)
{
    int node = __builtin_amdgcn_readfirstlane(blockIdx.x * 4 + (threadIdx.x >> 6));
    int lane = threadIdx.x & 63;
    if (node >= n) return;
    int beg = off[node], end = off[node+1];
    unsigned int ps = xcb_cur[(size_t)node*64 + lane];
    float s0f = bf_lo(ps), s1f = bf_hi(ps);
    float a0 = s0f, a1 = s1f;
    float g0 = 0.f, g1 = 0.f;
    int e = beg;
    for (; e + 4 <= end; e += 4){
        int s0 = csr[e], s1 = csr[e+1], s2 = csr[e+2], s3 = csr[e+3];
        unsigned int p0 = xcb_cur[(size_t)s0*64 + lane];
        unsigned int p1 = xcb_cur[(size_t)s1*64 + lane];
        unsigned int p2 = xcb_cur[(size_t)s2*64 + lane];
        unsigned int p3 = xcb_cur[(size_t)s3*64 + lane];
        float d0 = dinv[s0], d1 = dinv[s1], d2 = dinv[s2], d3 = dinv[s3];
        float v0 = bf_lo(p0), v1 = bf_lo(p1), v2 = bf_lo(p2), v3 = bf_lo(p3);
        float w0 = bf_hi(p0), w1 = bf_hi(p1), w2 = bf_hi(p2), w3 = bf_hi(p3);
        a0 += (v0 + v1) + (v2 + v3);
        a1 += (w0 + w1) + (w2 + w3);
        g0 = fmaf(d0, v0, fmaf(d1, v1, fmaf(d2, v2, fmaf(d3, v3, g0))));
        g1 = fmaf(d0, w0, fmaf(d1, w1, fmaf(d2, w2, fmaf(d3, w3, g1))));
    }
    for (; e < end; e++){
        int s0 = csr[e];
        unsigned int p0 = xcb_cur[(size_t)s0*64 + lane];
        float d0 = dinv[s0];
        float v0 = bf_lo(p0), w0 = bf_hi(p0);
        a0 += v0; a1 += w0;
        g0 = fmaf(d0, v0, g0);
        g1 = fmaf(d0, w0, g1);
    }
    hpreb[(size_t)node*64 + lane] = pack2bf(a0, a1);
    if (lane >= 32){   // lanes 32..63 hold s_prev cols (64..127)
        float di = dinv[node];
        float u0 = fmaf(di, g0, di*di*s0f);
        float u1 = fmaf(di, g1, di*di*s1f);
        ub[(size_t)node*32 + (lane - 32)] = pack2bf(u0, u1);
    }
}

// ---------------- fused per-layer MFMA: GIN MLP + GCN linear ---------------
__global__ __launch_bounds__(256) void ginmlp3(
        const unsigned short* __restrict__ hpreb,   // [n,128] bf16
        const unsigned short* __restrict__ ub,      // [n,64]  bf16
        const unsigned short* __restrict__ W1T,     // [64][128]
        const float* __restrict__ b1,
        const unsigned short* __restrict__ W2T,     // [64][64]
        const float* __restrict__ b2,
        const unsigned short* __restrict__ gcnWT,   // [64][64]
        const float* __restrict__ gcnb,
        unsigned short* __restrict__ xcb_nxt, int n)
{
    __shared__ unsigned short hsh[64 * 72];
    int tid = threadIdx.x;
    int w = tid >> 6, l = tid & 63;
    int m = l & 15, q = l >> 4;
    int rbase = blockIdx.x * 64 + w * 16;
    int arow  = rbase + m;
    bool valid = arow < n;
    v8s z = {0,0,0,0,0,0,0,0};
    // GEMM3: s_new = tanh(ub @ gcnW + b)
    {
        v8s a3[2];
#pragma unroll
        for (int ko = 0; ko < 2; ko++)
            a3[ko] = valid ? *(const v8s*)(ub + (size_t)arow * 64 + ko*32 + q*8) : z;
#pragma unroll
        for (int ct = 0; ct < 4; ct++){
            v4f acc = {0.f, 0.f, 0.f, 0.f};
#pragma unroll
            for (int ko = 0; ko < 2; ko++){
                v8s b = *(const v8s*)(gcnWT + (size_t)(ct*16 + m) * 64 + ko*32 + q*8);
                acc = __builtin_amdgcn_mfma_f32_16x16x32_bf16(a3[ko], b, acc, 0, 0, 0);
            }
            int col = ct*16 + m;
            float bv = gcnb[col];
#pragma unroll
            for (int r = 0; r < 4; r++){
                int orow = rbase + q*4 + r;
                if (orow < n)
                    xcb_nxt[(size_t)orow * 128 + 64 + col] = f2bf(tanhf(acc[r] + bv));
            }
        }
    }
    // GEMM1: h = relu(hpreb @ W1 + b1) -> LDS (bf16)
    {
        v8s a[4];
#pragma unroll
        for (int ko = 0; ko < 4; ko++)
            a[ko] = valid ? *(const v8s*)(hpreb + (size_t)arow * 128 + ko*32 + q*8) : z;
#pragma unroll
        for (int ct = 0; ct < 4; ct++){
            v4f acc = {0.f, 0.f, 0.f, 0.f};
#pragma unroll
            for (int ko = 0; ko < 4; ko++){
                v8s b = *(const v8s*)(W1T + (size_t)(ct*16 + m) * 128 + ko*32 + q*8);
                acc = __builtin_amdgcn_mfma_f32_16x16x32_bf16(a[ko], b, acc, 0, 0, 0);
            }
            int col = ct*16 + m;
            float bv = b1[col];
#pragma unroll
            for (int r = 0; r < 4; r++){
                int lrow = w*16 + q*4 + r;
                hsh[lrow*72 + col] = f2bf(fmaxf(acc[r] + bv, 0.f));
            }
        }
    }
    __syncthreads();
    // GEMM2: x_new = relu(h @ W2 + b2)
    v8s a2[2];
#pragma unroll
    for (int ko = 0; ko < 2; ko++)
        a2[ko] = *(const v8s*)(&hsh[(w*16 + m)*72 + ko*32 + q*8]);
#pragma unroll
    for (int ct = 0; ct < 4; ct++){
        v4f acc = {0.f, 0.f, 0.f, 0.f};
#pragma unroll
        for (int ko = 0; ko < 2; ko++){
            v8s b = *(const v8s*)(W2T + (size_t)(ct*16 + m) * 64 + ko*32 + q*8);
            acc = __builtin_amdgcn_mfma_f32_16x16x32_bf16(a2[ko], b, acc, 0, 0, 0);
        }
        int col = ct*16 + m;
        float bv = b2[col];
#pragma unroll
        for (int r = 0; r < 4; r++){
            int orow = rbase + q*4 + r;
            if (orow < n)
                xcb_nxt[(size_t)orow * 128 + col] = f2bf(fmaxf(acc[r] + bv, 0.f));
        }
    }
}

// ---------------- global_add_pool: 16 rows per wave (latency-parallel) -----
// 3125 blocks x 64 lanes (lane = col). Sorted batch -> per-run register
// accumulate, one atomicAdd per (run, lane). gbuf zeroed via hipMemsetAsync.
#define PROWS 16
__global__ __launch_bounds__(64) void pool_kernel(
        const float* __restrict__ xw, const int* __restrict__ batch,
        float* __restrict__ g, int n)
{
    int lane = threadIdx.x;
    int r0 = blockIdx.x * PROWS;
    if (r0 >= n) return;
    int r1 = r0 + PROWS; if (r1 > n) r1 = n;
    float acc = 0.f;
    int cb = batch[r0];
    for (int r = r0; r < r1; r++){
        int b = batch[r];
        if (b != cb){
            atomicAdd(&g[(size_t)cb*64 + lane], acc);
            acc = 0.f; cb = b;
        }
        acc += xw[(size_t)r*64 + lane];
    }
    atomicAdd(&g[(size_t)cb*64 + lane], acc);
}

// ---------------- head ----------------------------------------------------
__global__ __launch_bounds__(256) void head_kernel(
        const float* __restrict__ g, const float* __restrict__ postW,
        const float* __restrict__ postb, const float* __restrict__ roW,
        const float* __restrict__ rob, float* __restrict__ out, int ngraph)
{
    int gr = __builtin_amdgcn_readfirstlane(blockIdx.x * 4 + (threadIdx.x >> 6));
    int lane = threadIdx.x & 63;
    if (gr >= ngraph) return;
    float gv = g[(size_t)gr*64 + lane];
    float t = postb[lane];
    for (int k = 0; k < 64; k++){
        float a = __shfl(gv, k);
        t = fmaf(a, postW[k*64 + lane], t);
    }
    t = fmaxf(t, 0.f);
    float lg = (lane < NCLS) ? rob[lane] : 0.f;
    for (int k = 0; k < 64; k++){
        float a = __shfl(t, k);
        float w = (lane < NCLS) ? roW[k*NCLS + lane] : 0.f;
        lg = fmaf(a, w, lg);
    }
    float m = (lane < NCLS) ? lg : -INFINITY;
#pragma unroll
    for (int d = 1; d < 16; d <<= 1) m = fmaxf(m, __shfl_xor(m, d, 16));
    float ex = (lane < NCLS) ? expf(lg - m) : 0.f;
    float ssum = ex;
#pragma unroll
    for (int d = 1; d < 16; d <<= 1) ssum += __shfl_xor(ssum, d, 16);
    if (lane < NCLS) out[(size_t)gr*NCLS + lane] = lg - m - logf(ssum);
}

// ---------------- launch --------------------------------------------------
extern "C" void kernel_launch(void* const* d_in, const int* in_sizes, int n_in,
                              void* d_out, int out_size, void* d_ws, size_t ws_size,
                              hipStream_t stream) {
    const float* x      = (const float*)d_in[0];
    const float* s      = (const float*)d_in[1];
    const int*   ei     = (const int*)d_in[2];    // int32
    const int*   batch  = (const int*)d_in[3];    // int32
    const float* pre_W  = (const float*)d_in[4];
    const float* pre_b  = (const float*)d_in[5];
    const float* emb_W  = (const float*)d_in[6];
    const float* emb_b  = (const float*)d_in[7];
    const float* gin_W1 = (const float*)d_in[8];
    const float* gin_b1 = (const float*)d_in[9];
    const float* gin_W2 = (const float*)d_in[10];
    const float* gin_b2 = (const float*)d_in[11];
    const float* gcn_W  = (const float*)d_in[12];
    const float* gcn_b  = (const float*)d_in[13];
    const float* whp_W  = (const float*)d_in[14];
    const float* whp_b  = (const float*)d_in[15];
    const float* post_W = (const float*)d_in[16];
    const float* post_b = (const float*)d_in[17];
    const float* ro_W   = (const float*)d_in[18];
    const float* ro_b   = (const float*)d_in[19];
    float* out = (float*)d_out;

    char* w = (char*)d_ws;
    auto alloc = [&](size_t bytes) -> void* {
        void* p = (void*)w;
        w += (bytes + 255) & ~(size_t)255;
        return p;
    };
    int*   off   = (int*)  alloc((size_t)(NN+1) * 4);
    int*   csr   = (int*)  alloc((size_t)NE * 4);
    int*   ghist = (int*)  alloc((size_t)NCH * CB * 4);
    unsigned int* ebuf = (unsigned int*)alloc((size_t)NE * 4);
    float* dinv = (float*)alloc((size_t)NN * 4);
    unsigned short* xcb0 = (unsigned short*)alloc((size_t)NN * 128 * 2);
    unsigned short* xcb1 = (unsigned short*)alloc((size_t)NN * 128 * 2);
    unsigned int*   hpreb = (unsigned int*)alloc((size_t)NN * 64 * 4);  // bf16 [n,128]
    unsigned int*   ub    = (unsigned int*)alloc((size_t)NN * 32 * 4);  // bf16 [n,64]
    float* xw   = (float*)alloc((size_t)NN * 64 * 4);
    float* gbuf = (float*)alloc((size_t)NG * 64 * 4);
    unsigned short* gcnWT = (unsigned short*)alloc((size_t)3 * 4096 * 2);
    unsigned short* W1T   = (unsigned short*)alloc((size_t)3 * 8192 * 2);
    unsigned short* W2T   = (unsigned short*)alloc((size_t)3 * 4096 * 2);
    unsigned short* whpWT = (unsigned short*)alloc((size_t)8192 * 2);

    const int B  = 256;
    const int GL = (NN + 63) / 64;   // 782
    const int GA = (NN + 3) / 4;     // 12500

    // weight prep + CSR build
    wprep<<<224, 256, 0, stream>>>(gcn_W, gin_W1, gin_W2, whp_W, gcnWT, W1T, W2T, whpWT);
    coarse_hist<<<NCH, 256, 0, stream>>>(ei + NE, ghist);
    coarse_scan<<<1,   256, 0, stream>>>(ghist);
    bin_lds    <<<NCH, 256, 0, stream>>>(ei, ei + NE, ghist, ebuf);
    scatter_all<<<CB,  256, 0, stream>>>(ebuf, ghist, off, dinv, csr, NN);

    // pre / emb -> xcb0 = bf16([x|s] @ W + b)
    linear64<FEATD><<<GL, B, 0, stream>>>(x, FEATD, pre_W, pre_b, xcb0,      128, NN);
    linear64<SED>  <<<GL, B, 0, stream>>>(s, SED,   emb_W, emb_b, xcb0 + 64, 128, NN);

    for (int i = 0; i < NLAY; i++){
        unsigned short* cur = (i & 1) ? xcb1 : xcb0;
        unsigned short* nxt = (i & 1) ? xcb0 : xcb1;
        merged_agg<<<GA, B, 0, stream>>>((const unsigned int*)cur, dinv, off, csr,
                                         hpreb, ub, NN);
        ginmlp3<<<GL, B, 0, stream>>>((const unsigned short*)hpreb,
                                      (const unsigned short*)ub,
                                      W1T + (size_t)i*8192, gin_b1 + i*64,
                                      W2T + (size_t)i*4096, gin_b2 + i*64,
                                      gcnWT + (size_t)i*4096, gcn_b + i*64,
                                      nxt, NN);
    }

    // whp (final state in xcb1 after 3 layers)
    mfma_linear<128><<<GL, B, 0, stream>>>(xcb1, 128, whpWT, whp_b, xw, 64, NN);

    // pool (16 rows/wave, 3125 blocks) + head
    hipMemsetAsync(gbuf, 0, (size_t)NG * 64 * 4, stream);
    pool_kernel<<<(NN + PROWS - 1)/PROWS, 64, 0, stream>>>(xw, batch, gbuf, NN);
    head_kernel<<<(NG + 3)/4, B, 0, stream>>>(gbuf, post_W, post_b, ro_W, ro_b, out, NG);
}

// Round 14
// 382.367 us; speedup vs baseline: 1.7672x; 1.0209x over previous
//
#include <hip/hip_runtime.h>
#include <math.h>

#define NN   50000
#define NE   800000
#define FEATD 128
#define SED  16
#define HD   64
#define NCLS 10
#define NLAY 3
#define NG   500

// two-level counting sort params
#define CHUNK 4096
#define NCH   ((NE + CHUNK - 1) / CHUNK)  // 196
#define CBSH  9
#define CB    ((NN + (1 << CBSH) - 1) >> CBSH)  // 98

typedef short  v8s __attribute__((ext_vector_type(8)));
typedef float  v4f __attribute__((ext_vector_type(4)));

// ---- bf16 helpers ---------------------------------------------------------
__device__ inline unsigned short f2bf(float f){
    unsigned int u = __float_as_uint(f);
    u += 0x7fffu + ((u >> 16) & 1u);
    return (unsigned short)(u >> 16);
}
__device__ inline unsigned int pack2bf(float a, float b){
    return (unsigned int)f2bf(a) | ((unsigned int)f2bf(b) << 16);
}
__device__ inline float bf_lo(unsigned int p){ return __uint_as_float(p << 16); }
__device__ inline float bf_hi(unsigned int p){ return __uint_as_float(p & 0xffff0000u); }

// ---------------- weight prep: bf16 + transpose to WT[n][k] ----------------
__global__ __launch_bounds__(256) void wprep(
        const float* __restrict__ gcn_W, const float* __restrict__ gin_W1,
        const float* __restrict__ gin_W2, const float* __restrict__ whp_W,
        unsigned short* __restrict__ gcnWT, unsigned short* __restrict__ W1T,
        unsigned short* __restrict__ W2T,  unsigned short* __restrict__ whpWT)
{
    int i = blockIdx.x*256 + threadIdx.x;
    if (i < 12288){
        int li = i / 4096, r = i % 4096, nn = r / 64, kk = r % 64;
        gcnWT[li*4096 + nn*64 + kk] = f2bf(gcn_W[li*4096 + kk*64 + nn]);
    } else if (i < 36864){
        int j = i - 12288; int li = j / 8192, r = j % 8192, nn = r / 128, kk = r % 128;
        W1T[li*8192 + nn*128 + kk] = f2bf(gin_W1[li*8192 + kk*64 + nn]);
    } else if (i < 49152){
        int j = i - 36864; int li = j / 4096, r = j % 4096, nn = r / 64, kk = r % 64;
        W2T[li*4096 + nn*64 + kk] = f2bf(gin_W2[li*4096 + kk*64 + nn]);
    } else if (i < 57344){
        int j = i - 49152; int nn = j / 128, kk = j % 128;
        whpWT[nn*128 + kk] = f2bf(whp_W[kk*64 + nn]);
    }
}

// ---------------- two-level counting sort of edges by dst ------------------
__global__ __launch_bounds__(256) void coarse_hist(
        const int* __restrict__ dst, int* __restrict__ ghist){
    __shared__ int h[CB];
    for (int i = threadIdx.x; i < CB; i += 256) h[i] = 0;
    __syncthreads();
    int base = blockIdx.x * CHUNK;
    int end  = base + CHUNK; if (end > NE) end = NE;
    for (int i = base + threadIdx.x; i < end; i += 256)
        atomicAdd(&h[dst[i] >> CBSH], 1);
    __syncthreads();
    for (int i = threadIdx.x; i < CB; i += 256)
        ghist[(size_t)blockIdx.x * CB + i] = h[i];
}

// LDS-staged scan of ghist (196*98 ints = 77KB LDS); single-block kernel.
__global__ __launch_bounds__(256) void coarse_scan(int* __restrict__ ghist){
    __shared__ int sh[NCH * CB];
    __shared__ int sc[256];
    int t = threadIdx.x;
    for (int i = t; i < NCH * CB; i += 256) sh[i] = ghist[i];
    __syncthreads();
    int run = 0;
    if (t < CB){
        for (int c = 0; c < NCH; c++){
            int v = sh[c*CB + t];
            sh[c*CB + t] = run;
            run += v;
        }
    }
    sc[t] = (t < CB) ? run : 0;
    __syncthreads();
    for (int d = 1; d < 256; d <<= 1){
        int u = (t >= d) ? sc[t-d] : 0;
        __syncthreads();
        sc[t] += u;
        __syncthreads();
    }
    int bstart = (t == 0) ? 0 : sc[t-1];
    if (t < CB){
        for (int c = 0; c < NCH; c++) sh[c*CB + t] += bstart;
    }
    __syncthreads();
    for (int i = t; i < NCH * CB; i += 256) ghist[i] = sh[i];
}

__global__ __launch_bounds__(256) void bin_lds(
        const int* __restrict__ src, const int* __restrict__ dst,
        const int* __restrict__ ghist, unsigned int* __restrict__ ebuf){
    __shared__ unsigned int lbuf[CHUNK];
    __shared__ unsigned int lbuf2[CHUNK];
    __shared__ int hist[CB], lstart[CB], cursor[CB], gbase[CB];
    __shared__ int sc[256];
    int t = threadIdx.x, c = blockIdx.x;
    for (int i = t; i < CB; i += 256){
        hist[i] = 0;
        gbase[i] = ghist[(size_t)c*CB + i];
    }
    __syncthreads();
    int base = c * CHUNK;
    int nend = base + CHUNK; if (nend > NE) nend = NE;
    nend -= base;
    for (int i = t; i < nend; i += 256){
        int d = dst[base + i];
        lbuf[i] = (unsigned int)src[base + i] | ((unsigned int)d << 16);
        atomicAdd(&hist[d >> CBSH], 1);
    }
    __syncthreads();
    sc[t] = (t < CB) ? hist[t] : 0;
    __syncthreads();
    for (int d = 1; d < 256; d <<= 1){
        int u = (t >= d) ? sc[t-d] : 0;
        __syncthreads();
        sc[t] += u;
        __syncthreads();
    }
    if (t < CB){
        lstart[t] = sc[t] - hist[t];
        cursor[t] = sc[t] - hist[t];
    }
    __syncthreads();
    for (int i = t; i < nend; i += 256){
        unsigned int u = lbuf[i];
        int b = (int)(u >> 16) >> CBSH;
        int p = atomicAdd(&cursor[b], 1);
        lbuf2[p] = u;
    }
    __syncthreads();
    for (int p = t; p < nend; p += 256){
        unsigned int u = lbuf2[p];
        int b = (int)(u >> 16) >> CBSH;
        ebuf[gbase[b] + (p - lstart[b])] = u;
    }
}

__global__ __launch_bounds__(256) void scatter_all(
        const unsigned int* __restrict__ ebuf, const int* __restrict__ ghist,
        int* __restrict__ off, float* __restrict__ dinv,
        int* __restrict__ csr, int n){
    __shared__ int lcnt[512];
    __shared__ int lex[512];
    __shared__ int sc[256];
    int t = threadIdx.x, b = blockIdx.x;
    int n0 = b << CBSH;
    int nn = n - n0; if (nn > 512) nn = 512;
    int lo = ghist[b];
    int hi = (b + 1 < CB) ? ghist[b + 1] : NE;
    lcnt[t] = 0; lcnt[t + 256] = 0;
    __syncthreads();
    for (int j = lo + t; j < hi; j += 256)
        atomicAdd(&lcnt[(int)(ebuf[j] >> 16) - n0], 1);
    __syncthreads();
    int c0 = lcnt[2*t], c1 = lcnt[2*t+1];
    sc[t] = c0 + c1;
    __syncthreads();
    for (int d = 1; d < 256; d <<= 1){
        int u = (t >= d) ? sc[t-d] : 0;
        __syncthreads();
        sc[t] += u;
        __syncthreads();
    }
    int bse = sc[t] - (c0 + c1);
    lex[2*t]   = bse;
    lex[2*t+1] = bse + c0;
    __syncthreads();
    for (int i = t; i < nn; i += 256){
        off[n0 + i]  = lo + lex[i];
        dinv[n0 + i] = rsqrtf((float)lcnt[i] + 1.0f);
    }
    if (b == 0 && t == 0) off[n] = NE;
    __syncthreads();
    for (int j = lo + t; j < hi; j += 256){
        unsigned int u = ebuf[j];
        int d = (int)(u >> 16) - n0;
        int p = atomicAdd(&lex[d], 1);
        csr[lo + p] = (int)(u & 0xffffu);
    }
}

// ---------------- fused pre+emb: xcb0 = bf16([x@preW+b | s@embW+b]) -------
__global__ __launch_bounds__(256) void pre_emb(
        const float* __restrict__ x, const float* __restrict__ preW,
        const float* __restrict__ preb,
        const float* __restrict__ s, const float* __restrict__ embW,
        const float* __restrict__ embb,
        unsigned short* __restrict__ xcb, int n)
{
    __shared__ float atx[64 * 132];
    __shared__ float ats[64 * 20];
    int tid = threadIdx.x;
    int r0  = blockIdx.x * 64;
    for (int idx = tid; idx < 64 * 32; idx += 256){
        int row = idx >> 5, kq = idx & 31;
        float4 v = make_float4(0.f, 0.f, 0.f, 0.f);
        if (r0 + row < n) v = *(const float4*)(x + (size_t)(r0 + row) * 128 + kq * 4);
        *(float4*)(&atx[row * 132 + kq * 4]) = v;
    }
    for (int idx = tid; idx < 64 * 4; idx += 256){
        int row = idx >> 2, kq = idx & 3;
        float4 v = make_float4(0.f, 0.f, 0.f, 0.f);
        if (r0 + row < n) v = *(const float4*)(s + (size_t)(r0 + row) * 16 + kq * 4);
        *(float4*)(&ats[row * 20 + kq * 4]) = v;
    }
    __syncthreads();
    int lane = tid & 63;
    int c0 = __builtin_amdgcn_readfirstlane((tid >> 6) << 4);
    int row = r0 + lane;
    if (row >= n) return;
    float acc[16];
#pragma unroll
    for (int j = 0; j < 16; j++) acc[j] = 0.f;
    for (int k = 0; k < 128; k += 4){
        float4 av = *(const float4*)(&atx[lane * 132 + k]);
        float aa[4] = {av.x, av.y, av.z, av.w};
#pragma unroll
        for (int kk = 0; kk < 4; kk++){
            const float* wr = preW + (k + kk) * 64 + c0;
#pragma unroll
            for (int j = 0; j < 16; j++)
                acc[j] = fmaf(aa[kk], wr[j], acc[j]);
        }
    }
#pragma unroll
    for (int j = 0; j < 16; j++) acc[j] += preb[c0 + j];
    unsigned int pk[8];
#pragma unroll
    for (int j = 0; j < 8; j++) pk[j] = pack2bf(acc[2*j], acc[2*j+1]);
    {
        unsigned short* ob = xcb + (size_t)row * 128 + c0;
        uint4 u0; u0.x = pk[0]; u0.y = pk[1]; u0.z = pk[2]; u0.w = pk[3];
        uint4 u1; u1.x = pk[4]; u1.y = pk[5]; u1.z = pk[6]; u1.w = pk[7];
        *(uint4*)(ob)     = u0;
        *(uint4*)(ob + 8) = u1;
    }
#pragma unroll
    for (int j = 0; j < 16; j++) acc[j] = 0.f;
    for (int k = 0; k < 16; k += 4){
        float4 av = *(const float4*)(&ats[lane * 20 + k]);
        float aa[4] = {av.x, av.y, av.z, av.w};
#pragma unroll
        for (int kk = 0; kk < 4; kk++){
            const float* wr = embW + (k + kk) * 64 + c0;
#pragma unroll
            for (int j = 0; j < 16; j++)
                acc[j] = fmaf(aa[kk], wr[j], acc[j]);
        }
    }
#pragma unroll
    for (int j = 0; j < 16; j++) acc[j] += embb[c0 + j];
#pragma unroll
    for (int j = 0; j < 8; j++) pk[j] = pack2bf(acc[2*j], acc[2*j+1]);
    {
        unsigned short* ob = xcb + (size_t)row * 128 + 64 + c0;
        uint4 u0; u0.x = pk[0]; u0.y = pk[1]; u0.z = pk[2]; u0.w = pk[3];
        uint4 u1; u1.x = pk[4]; u1.y = pk[5]; u1.z = pk[6]; u1.w = pk[7];
        *(uint4*)(ob)     = u0;
        *(uint4*)(ob + 8) = u1;
    }
}

// ---------------- MFMA bf16 linear (whp): out fp32 -----------------------
template<int K>
__global__ __launch_bounds__(256) void mfma_linear(
        const unsigned short* __restrict__ A, int lda,
        const unsigned short* __restrict__ WT,
        const float* __restrict__ bias,
        float* __restrict__ out, int ldo, int n)
{
    constexpr int NKO = K / 32;
    int tid = threadIdx.x;
    int w = tid >> 6, l = tid & 63;
    int m = l & 15, q = l >> 4;
    int rbase = blockIdx.x * 64 + w * 16;
    int arow  = rbase + m;
    bool valid = arow < n;
    v8s a[NKO];
#pragma unroll
    for (int ko = 0; ko < NKO; ko++){
        v8s z = {0,0,0,0,0,0,0,0};
        a[ko] = valid ? *(const v8s*)(A + (size_t)arow * lda + ko*32 + q*8) : z;
    }
#pragma unroll
    for (int ct = 0; ct < 4; ct++){
        v4f acc = {0.f, 0.f, 0.f, 0.f};
#pragma unroll
        for (int ko = 0; ko < NKO; ko++){
            v8s b = *(const v8s*)(WT + (size_t)(ct*16 + m) * K + ko*32 + q*8);
            acc = __builtin_amdgcn_mfma_f32_16x16x32_bf16(a[ko], b, acc, 0, 0, 0);
        }
        int col = ct*16 + m;
        float bv = bias ? bias[col] : 0.f;
#pragma unroll
        for (int r = 0; r < 4; r++){
            int orow = rbase + q*4 + r;
            if (orow < n) out[(size_t)orow * ldo + col] = acc[r] + bv;
        }
    }
}

// ---------------- merged aggregation: ONE gather feeds GIN + GCN -----------
__global__ __launch_bounds__(256) void merged_agg(
        const unsigned int* __restrict__ xcb_cur,
        const float* __restrict__ dinv,
        const int* __restrict__ off, const int* __restrict__ csr,
        unsigned int* __restrict__ hpreb, unsigned int* __restrict__ ub, int n)
{
    int node = __builtin_amdgcn_readfirstlane(blockIdx.x * 4 + (threadIdx.x >> 6));
    int lane = threadIdx.x & 63;
    if (node >= n) return;
    int beg = off[node], end = off[node+1];
    unsigned int ps = xcb_cur[(size_t)node*64 + lane];
    float s0f = bf_lo(ps), s1f = bf_hi(ps);
    float a0 = s0f, a1 = s1f;
    float g0 = 0.f, g1 = 0.f;
    int e = beg;
    for (; e + 4 <= end; e += 4){
        int s0 = csr[e], s1 = csr[e+1], s2 = csr[e+2], s3 = csr[e+3];
        unsigned int p0 = xcb_cur[(size_t)s0*64 + lane];
        unsigned int p1 = xcb_cur[(size_t)s1*64 + lane];
        unsigned int p2 = xcb_cur[(size_t)s2*64 + lane];
        unsigned int p3 = xcb_cur[(size_t)s3*64 + lane];
        float d0 = dinv[s0], d1 = dinv[s1], d2 = dinv[s2], d3 = dinv[s3];
        float v0 = bf_lo(p0), v1 = bf_lo(p1), v2 = bf_lo(p2), v3 = bf_lo(p3);
        float w0 = bf_hi(p0), w1 = bf_hi(p1), w2 = bf_hi(p2), w3 = bf_hi(p3);
        a0 += (v0 + v1) + (v2 + v3);
        a1 += (w0 + w1) + (w2 + w3);
        g0 = fmaf(d0, v0, fmaf(d1, v1, fmaf(d2, v2, fmaf(d3, v3, g0))));
        g1 = fmaf(d0, w0, fmaf(d1, w1, fmaf(d2, w2, fmaf(d3, w3, g1))));
    }
    for (; e < end; e++){
        int s0 = csr[e];
        unsigned int p0 = xcb_cur[(size_t)s0*64 + lane];
        float d0 = dinv[s0];
        float v0 = bf_lo(p0), w0 = bf_hi(p0);
        a0 += v0; a1 += w0;
        g0 = fmaf(d0, v0, g0);
        g1 = fmaf(d0, w0, g1);
    }
    hpreb[(size_t)node*64 + lane] = pack2bf(a0, a1);
    if (lane >= 32){   // lanes 32..63 hold s_prev cols (64..127)
        float di = dinv[node];
        float u0 = fmaf(di, g0, di*di*s0f);
        float u1 = fmaf(di, g1, di*di*s1f);
        ub[(size_t)node*32 + (lane - 32)] = pack2bf(u0, u1);
    }
}

// ---------------- fused per-layer MFMA: GIN MLP + GCN linear ---------------
__global__ __launch_bounds__(256) void ginmlp3(
        const unsigned short* __restrict__ hpreb,   // [n,128] bf16
        const unsigned short* __restrict__ ub,      // [n,64]  bf16
        const unsigned short* __restrict__ W1T,     // [64][128]
        const float* __restrict__ b1,
        const unsigned short* __restrict__ W2T,     // [64][64]
        const float* __restrict__ b2,
        const unsigned short* __restrict__ gcnWT,   // [64][64]
        const float* __restrict__ gcnb,
        unsigned short* __restrict__ xcb_nxt, int n)
{
    __shared__ unsigned short hsh[64 * 72];
    int tid = threadIdx.x;
    int w = tid >> 6, l = tid & 63;
    int m = l & 15, q = l >> 4;
    int rbase = blockIdx.x * 64 + w * 16;
    int arow  = rbase + m;
    bool valid = arow < n;
    v8s z = {0,0,0,0,0,0,0,0};
    // GEMM3: s_new = tanh(ub @ gcnW + b)
    {
        v8s a3[2];
#pragma unroll
        for (int ko = 0; ko < 2; ko++)
            a3[ko] = valid ? *(const v8s*)(ub + (size_t)arow * 64 + ko*32 + q*8) : z;
#pragma unroll
        for (int ct = 0; ct < 4; ct++){
            v4f acc = {0.f, 0.f, 0.f, 0.f};
#pragma unroll
            for (int ko = 0; ko < 2; ko++){
                v8s b = *(const v8s*)(gcnWT + (size_t)(ct*16 + m) * 64 + ko*32 + q*8);
                acc = __builtin_amdgcn_mfma_f32_16x16x32_bf16(a3[ko], b, acc, 0, 0, 0);
            }
            int col = ct*16 + m;
            float bv = gcnb[col];
#pragma unroll
            for (int r = 0; r < 4; r++){
                int orow = rbase + q*4 + r;
                if (orow < n)
                    xcb_nxt[(size_t)orow * 128 + 64 + col] = f2bf(tanhf(acc[r] + bv));
            }
        }
    }
    // GEMM1: h = relu(hpreb @ W1 + b1) -> LDS (bf16)
    {
        v8s a[4];
#pragma unroll
        for (int ko = 0; ko < 4; ko++)
            a[ko] = valid ? *(const v8s*)(hpreb + (size_t)arow * 128 + ko*32 + q*8) : z;
#pragma unroll
        for (int ct = 0; ct < 4; ct++){
            v4f acc = {0.f, 0.f, 0.f, 0.f};
#pragma unroll
            for (int ko = 0; ko < 4; ko++){
                v8s b = *(const v8s*)(W1T + (size_t)(ct*16 + m) * 128 + ko*32 + q*8);
                acc = __builtin_amdgcn_mfma_f32_16x16x32_bf16(a[ko], b, acc, 0, 0, 0);
            }
            int col = ct*16 + m;
            float bv = b1[col];
#pragma unroll
            for (int r = 0; r < 4; r++){
                int lrow = w*16 + q*4 + r;
                hsh[lrow*72 + col] = f2bf(fmaxf(acc[r] + bv, 0.f));
            }
        }
    }
    __syncthreads();
    // GEMM2: x_new = relu(h @ W2 + b2)
    v8s a2[2];
#pragma unroll
    for (int ko = 0; ko < 2; ko++)
        a2[ko] = *(const v8s*)(&hsh[(w*16 + m)*72 + ko*32 + q*8]);
#pragma unroll
    for (int ct = 0; ct < 4; ct++){
        v4f acc = {0.f, 0.f, 0.f, 0.f};
#pragma unroll
        for (int ko = 0; ko < 2; ko++){
            v8s b = *(const v8s*)(W2T + (size_t)(ct*16 + m) * 64 + ko*32 + q*8);
            acc = __builtin_amdgcn_mfma_f32_16x16x32_bf16(a2[ko], b, acc, 0, 0, 0);
        }
        int col = ct*16 + m;
        float bv = b2[col];
#pragma unroll
        for (int r = 0; r < 4; r++){
            int orow = rbase + q*4 + r;
            if (orow < n)
                xcb_nxt[(size_t)orow * 128 + col] = f2bf(fmaxf(acc[r] + bv, 0.f));
        }
    }
}

// ---------------- global_add_pool: 16 rows per wave (latency-parallel) -----
#define PROWS 16
__global__ __launch_bounds__(64) void pool_kernel(
        const float* __restrict__ xw, const int* __restrict__ batch,
        float* __restrict__ g, int n)
{
    int lane = threadIdx.x;
    int r0 = blockIdx.x * PROWS;
    if (r0 >= n) return;
    int r1 = r0 + PROWS; if (r1 > n) r1 = n;
    float acc = 0.f;
    int cb = batch[r0];
    for (int r = r0; r < r1; r++){
        int b = batch[r];
        if (b != cb){
            atomicAdd(&g[(size_t)cb*64 + lane], acc);
            acc = 0.f; cb = b;
        }
        acc += xw[(size_t)r*64 + lane];
    }
    atomicAdd(&g[(size_t)cb*64 + lane], acc);
}

// ---------------- head ----------------------------------------------------
__global__ __launch_bounds__(256) void head_kernel(
        const float* __restrict__ g, const float* __restrict__ postW,
        const float* __restrict__ postb, const float* __restrict__ roW,
        const float* __restrict__ rob, float* __restrict__ out, int ngraph)
{
    int gr = __builtin_amdgcn_readfirstlane(blockIdx.x * 4 + (threadIdx.x >> 6));
    int lane = threadIdx.x & 63;
    if (gr >= ngraph) return;
    float gv = g[(size_t)gr*64 + lane];
    float t = postb[lane];
    for (int k = 0; k < 64; k++){
        float a = __shfl(gv, k);
        t = fmaf(a, postW[k*64 + lane], t);
    }
    t = fmaxf(t, 0.f);
    float lg = (lane < NCLS) ? rob[lane] : 0.f;
    for (int k = 0; k < 64; k++){
        float a = __shfl(t, k);
        float w = (lane < NCLS) ? roW[k*NCLS + lane] : 0.f;
        lg = fmaf(a, w, lg);
    }
    float m = (lane < NCLS) ? lg : -INFINITY;
#pragma unroll
    for (int d = 1; d < 16; d <<= 1) m = fmaxf(m, __shfl_xor(m, d, 16));
    float ex = (lane < NCLS) ? expf(lg - m) : 0.f;
    float ssum = ex;
#pragma unroll
    for (int d = 1; d < 16; d <<= 1) ssum += __shfl_xor(ssum, d, 16);
    if (lane < NCLS) out[(size_t)gr*NCLS + lane] = lg - m - logf(ssum);
}

// ---------------- launch --------------------------------------------------
extern "C" void kernel_launch(void* const* d_in, const int* in_sizes, int n_in,
                              void* d_out, int out_size, void* d_ws, size_t ws_size,
                              hipStream_t stream) {
    const float* x      = (const float*)d_in[0];
    const float* s      = (const float*)d_in[1];
    const int*   ei     = (const int*)d_in[2];    // int32
    const int*   batch  = (const int*)d_in[3];    // int32
    const float* pre_W  = (const float*)d_in[4];
    const float* pre_b  = (const float*)d_in[5];
    const float* emb_W  = (const float*)d_in[6];
    const float* emb_b  = (const float*)d_in[7];
    const float* gin_W1 = (const float*)d_in[8];
    const float* gin_b1 = (const float*)d_in[9];
    const float* gin_W2 = (const float*)d_in[10];
    const float* gin_b2 = (const float*)d_in[11];
    const float* gcn_W  = (const float*)d_in[12];
    const float* gcn_b  = (const float*)d_in[13];
    const float* whp_W  = (const float*)d_in[14];
    const float* whp_b  = (const float*)d_in[15];
    const float* post_W = (const float*)d_in[16];
    const float* post_b = (const float*)d_in[17];
    const float* ro_W   = (const float*)d_in[18];
    const float* ro_b   = (const float*)d_in[19];
    float* out = (float*)d_out;

    char* w = (char*)d_ws;
    auto alloc = [&](size_t bytes) -> void* {
        void* p = (void*)w;
        w += (bytes + 255) & ~(size_t)255;
        return p;
    };
    int*   off   = (int*)  alloc((size_t)(NN+1) * 4);
    int*   csr   = (int*)  alloc((size_t)NE * 4);
    int*   ghist = (int*)  alloc((size_t)NCH * CB * 4);
    unsigned int* ebuf = (unsigned int*)alloc((size_t)NE * 4);
    float* dinv = (float*)alloc((size_t)NN * 4);
    unsigned short* xcb0 = (unsigned short*)alloc((size_t)NN * 128 * 2);
    unsigned short* xcb1 = (unsigned short*)alloc((size_t)NN * 128 * 2);
    unsigned int*   hpreb = (unsigned int*)alloc((size_t)NN * 64 * 4);  // bf16 [n,128]
    unsigned int*   ub    = (unsigned int*)alloc((size_t)NN * 32 * 4);  // bf16 [n,64]
    float* xw   = (float*)alloc((size_t)NN * 64 * 4);
    float* gbuf = (float*)alloc((size_t)NG * 64 * 4);
    unsigned short* gcnWT = (unsigned short*)alloc((size_t)3 * 4096 * 2);
    unsigned short* W1T   = (unsigned short*)alloc((size_t)3 * 8192 * 2);
    unsigned short* W2T   = (unsigned short*)alloc((size_t)3 * 4096 * 2);
    unsigned short* whpWT = (unsigned short*)alloc((size_t)8192 * 2);

    const int B  = 256;
    const int GL = (NN + 63) / 64;   // 782
    const int GA = (NN + 3) / 4;     // 12500

    // weight prep + CSR build (196-block hist/bin)
    wprep<<<224, 256, 0, stream>>>(gcn_W, gin_W1, gin_W2, whp_W, gcnWT, W1T, W2T, whpWT);
    coarse_hist<<<NCH, 256, 0, stream>>>(ei + NE, ghist);
    coarse_scan<<<1,   256, 0, stream>>>(ghist);
    bin_lds    <<<NCH, 256, 0, stream>>>(ei, ei + NE, ghist, ebuf);
    scatter_all<<<CB,  256, 0, stream>>>(ebuf, ghist, off, dinv, csr, NN);

    // fused pre+emb -> xcb0
    pre_emb<<<GL, B, 0, stream>>>(x, pre_W, pre_b, s, emb_W, emb_b, xcb0, NN);

    for (int i = 0; i < NLAY; i++){
        unsigned short* cur = (i & 1) ? xcb1 : xcb0;
        unsigned short* nxt = (i & 1) ? xcb0 : xcb1;
        merged_agg<<<GA, B, 0, stream>>>((const unsigned int*)cur, dinv, off, csr,
                                         hpreb, ub, NN);
        ginmlp3<<<GL, B, 0, stream>>>((const unsigned short*)hpreb,
                                      (const unsigned short*)ub,
                                      W1T + (size_t)i*8192, gin_b1 + i*64,
                                      W2T + (size_t)i*4096, gin_b2 + i*64,
                                      gcnWT + (size_t)i*4096, gcn_b + i*64,
                                      nxt, NN);
    }

    // whp (final state in xcb1 after 3 layers) -- R12-proven pool path
    mfma_linear<128><<<GL, B, 0, stream>>>(xcb1, 128, whpWT, whp_b, xw, 64, NN);

    // pool (memset + 16 rows/wave) + head, exactly as R12
    hipMemsetAsync(gbuf, 0, (size_t)NG * 64 * 4, stream);
    pool_kernel<<<(NN + PROWS - 1)/PROWS, 64, 0, stream>>>(xw, batch, gbuf, NN);
    head_kernel<<<(NG + 3)/4, B, 0, stream>>>(gbuf, post_W, post_b, ro_W, ro_b, out, NG);
}